// Round 10
// baseline (522.359 us; speedup 1.0000x reference)
//
#include <hip/hip_runtime.h>
#include <math.h>

#define ED 2700     // basis_dim
#define NC 1024     // num_codes
#define DM 256      // d_model
#define BKROWS 32768

#define IDX_OFF 88473600
#define VQ_OFF  88506368
#define ENT_OFF 88506369

#define KPAD 2720     // padded K for P/M small GEMMs (5 x 544)
#define NTZ 4         // zsq n-tile partials

typedef float  f32x4  __attribute__((ext_vector_type(4)));
typedef short  bf16x8 __attribute__((ext_vector_type(8)));

__device__ inline unsigned short f2bf(float x) {
    unsigned int u = __float_as_uint(x);
    unsigned int r = (u + 0x7FFFu + ((u >> 16) & 1u)) >> 16;
    return (unsigned short)r;
}
__device__ inline float bf2f(unsigned short h) {
    return __uint_as_float(((unsigned int)h) << 16);
}

// =====================================================================
// ============================ MFMA PATH ==============================
// =====================================================================

// ---- S -> Sh/Sm bf16 planes ----
__global__ __launch_bounds__(256)
void k_packS(const float* __restrict__ S, unsigned short* __restrict__ Sh,
             unsigned short* __restrict__ Sm) {
    const size_t i4 = (size_t)blockIdx.x * 256 + threadIdx.x;
    const float4 v = *(const float4*)(S + i4 * 4);
    ushort4 hv, mv;
    unsigned short* hp = (unsigned short*)&hv;
    unsigned short* mp = (unsigned short*)&mv;
    const float xs[4] = {v.x, v.y, v.z, v.w};
    #pragma unroll
    for (int j = 0; j < 4; ++j) {
        const unsigned short h = f2bf(xs[j]);
        hp[j] = h;
        mp[j] = f2bf(xs[j] - bf2f(h));
    }
    *(ushort4*)(Sh + i4 * 4) = hv;
    *(ushort4*)(Sm + i4 * 4) = mv;
}

// ---- bsq'[c] = sum basis^2 - 2*basis.bproj (f64) ----
__global__ void k_bsq2(const float* __restrict__ basis, const float* __restrict__ bproj,
                       float* __restrict__ bsq) {
    const int c = blockIdx.x;
    const int t = threadIdx.x;
    const float* row = basis + (size_t)c * ED;
    double s2 = 0.0, sp = 0.0;
    for (int j = t; j < ED; j += 256) {
        const float x = row[j];
        s2 += (double)x * (double)x;
        sp += (double)x * (double)bproj[j];
    }
    __shared__ double sd[512];
    sd[t] = s2; sd[256 + t] = sp;
    __syncthreads();
    for (int off = 128; off > 0; off >>= 1) {
        if (t < off) { sd[t] += sd[t + off]; sd[256 + t] += sd[256 + t + off]; }
        __syncthreads();
    }
    if (t == 0) bsq[c] = (float)(sd[0] - 2.0 * sd[256]);
}

// ---- basisP = basis zero-padded to [1024][2720] ----
__global__ __launch_bounds__(256)
void k_padB(const float* __restrict__ basis, float* __restrict__ bP) {
    const int c = blockIdx.x;
    const float4* src = (const float4*)(basis + (size_t)c * ED);
    float4* dst = (float4*)(bP + (size_t)c * KPAD);
    for (int q = threadIdx.x; q < KPAD / 4; q += 256)
        dst[q] = (q < ED / 4) ? src[q] : make_float4(0.f, 0.f, 0.f, 0.f);
}

// ---- WT = W^T zero-padded to [256][2720] ----
__global__ __launch_bounds__(256)
void k_padWT(const float* __restrict__ W, float* __restrict__ WT) {
    const int e0 = blockIdx.x * 64;
    const int d0 = blockIdx.y * 64;
    __shared__ float tbuf[64][65];
    const int t  = threadIdx.x;
    const int r  = t >> 2;
    const int q4 = t & 3;
    #pragma unroll
    for (int j = 0; j < 4; ++j) {
        const int col = q4 * 16 + j * 4;
        const int e = e0 + r;
        float4 v = make_float4(0.f, 0.f, 0.f, 0.f);
        if (e < ED) v = *(const float4*)(W + (size_t)e * DM + d0 + col);
        tbuf[r][col + 0] = v.x; tbuf[r][col + 1] = v.y;
        tbuf[r][col + 2] = v.z; tbuf[r][col + 3] = v.w;
    }
    __syncthreads();
    #pragma unroll
    for (int j = 0; j < 4; ++j) {
        const int col = q4 * 16 + j * 4;
        if (e0 + col < KPAD) {
            float4 o;
            o.x = tbuf[col + 0][r]; o.y = tbuf[col + 1][r];
            o.z = tbuf[col + 2][r]; o.w = tbuf[col + 3][r];
            *(float4*)(WT + (size_t)(d0 + r) * KPAD + e0 + col) = o;
        }
    }
}

// ---- k_uv2: u[d] = WT[d].bproj (blocks 0..255); v = ||bproj||^2 (block 256) ----
__global__ __launch_bounds__(256)
void k_uv2(const float* __restrict__ WT, const float* __restrict__ bproj,
           float* __restrict__ uv) {
    const int b = blockIdx.x;
    const int t = threadIdx.x;
    double s = 0.0;
    if (b < 256) {
        const float* row = WT + (size_t)b * KPAD;
        for (int j = t; j < ED; j += 256) s += (double)row[j] * (double)bproj[j];
    } else {
        for (int j = t; j < ED; j += 256) { const double x = bproj[j]; s += x * x; }
    }
    __shared__ double sd[256];
    sd[t] = s;
    __syncthreads();
    for (int off = 128; off > 0; off >>= 1) {
        if (t < off) sd[t] += sd[t + off];
        __syncthreads();
    }
    if (t == 0) uv[b] = (float)sd[0];
}

// ---- generic 64x64-tile f32 GEMM partial over K-slab of 544 ----
__global__ __launch_bounds__(256)
void k_gsplit(const float* __restrict__ A, const float* __restrict__ B,
              float* __restrict__ Cp, int nld) {
    const int n0  = blockIdx.x * 64;
    const int m0  = blockIdx.y * 64;
    const int k00 = blockIdx.z * 544;
    float* Cout = Cp + (size_t)blockIdx.z * (size_t)gridDim.y * 64 * nld;
    const int t  = threadIdx.x;
    const int tx = t & 15, ty = t >> 4;

    __shared__ float alds[32 * 68];
    __shared__ float blds[32 * 68];

    float acc[4][4] = {};

    for (int k0 = k00; k0 < k00 + 544; k0 += 32) {
        #pragma unroll
        for (int rep = 0; rep < 2; ++rep) {
            const int id  = t + rep * 256;
            const int row = id >> 3, kq = id & 7;
            const float4 va = *(const float4*)(A + (size_t)(m0 + row) * KPAD + k0 + 4 * kq);
            alds[(4*kq+0)*68 + row] = va.x;
            alds[(4*kq+1)*68 + row] = va.y;
            alds[(4*kq+2)*68 + row] = va.z;
            alds[(4*kq+3)*68 + row] = va.w;
            const float4 vb = *(const float4*)(B + (size_t)(n0 + row) * KPAD + k0 + 4 * kq);
            blds[(4*kq+0)*68 + row] = vb.x;
            blds[(4*kq+1)*68 + row] = vb.y;
            blds[(4*kq+2)*68 + row] = vb.z;
            blds[(4*kq+3)*68 + row] = vb.w;
        }
        __syncthreads();
        #pragma unroll 8
        for (int k = 0; k < 32; ++k) {
            const float4 a = *(const float4*)&alds[k*68 + 4*ty];
            const float4 b = *(const float4*)&blds[k*68 + 4*tx];
            const float av[4] = {a.x, a.y, a.z, a.w};
            const float bv[4] = {b.x, b.y, b.z, b.w};
            #pragma unroll
            for (int i = 0; i < 4; ++i)
                #pragma unroll
                for (int j = 0; j < 4; ++j)
                    acc[i][j] = fmaf(av[i], bv[j], acc[i][j]);
        }
        __syncthreads();
    }
    #pragma unroll
    for (int i = 0; i < 4; ++i) {
        float4 o; o.x = acc[i][0]; o.y = acc[i][1]; o.z = acc[i][2]; o.w = acc[i][3];
        *(float4*)(Cout + (size_t)(m0 + 4*ty + i) * nld + n0 + 4*tx) = o;
    }
}

// ---- reduce 5 P-partials -> Ph/Pm planes ----
__global__ __launch_bounds__(256)
void k_redP(const float* __restrict__ Pp, unsigned short* __restrict__ Ph,
            unsigned short* __restrict__ Pm) {
    const size_t idx = (size_t)blockIdx.x * 256 + threadIdx.x;
    float s = 0.f;
    #pragma unroll
    for (int k = 0; k < 5; ++k) s += Pp[(size_t)k * 262144 + idx];
    const unsigned short h = f2bf(s);
    Ph[idx] = h;
    Pm[idx] = f2bf(s - bf2f(h));
}

// ---- reduce 5 M-partials -> M f32 ----
__global__ __launch_bounds__(256)
void k_redM(const float* __restrict__ Mp, float* __restrict__ M) {
    const size_t idx = (size_t)blockIdx.x * 256 + threadIdx.x;
    float s = 0.f;
    #pragma unroll
    for (int k = 0; k < 5; ++k) s += Mp[(size_t)k * 65536 + idx];
    M[idx] = s;
}

// ---- zsq partials: zsq_r = S_r M S_r^T + 2 S_r.u + v ----
__global__ __launch_bounds__(256)
void k_zsqS(const float* __restrict__ S, const float* __restrict__ M,
            const float* __restrict__ uv, float* __restrict__ zsqpart) {
    const int e0 = blockIdx.x * 64;
    const int m0 = blockIdx.y * 64;
    const int t  = threadIdx.x;
    const int tx = t & 15, ty = t >> 4;

    __shared__ float alds[32 * 68];
    __shared__ float blds[32 * 68];

    float acc[4][4] = {};

    for (int k0 = 0; k0 < DM; k0 += 32) {
        #pragma unroll
        for (int rep = 0; rep < 2; ++rep) {
            const int id  = t + rep * 256;
            const int row = id >> 3, kq = id & 7;
            const float4 va = *(const float4*)(S + (size_t)(m0 + row) * DM + k0 + 4 * kq);
            alds[(4*kq+0)*68 + row] = va.x;
            alds[(4*kq+1)*68 + row] = va.y;
            alds[(4*kq+2)*68 + row] = va.z;
            alds[(4*kq+3)*68 + row] = va.w;
            const float4 vb = *(const float4*)(M + (size_t)(e0 + row) * DM + k0 + 4 * kq);
            blds[(4*kq+0)*68 + row] = vb.x;
            blds[(4*kq+1)*68 + row] = vb.y;
            blds[(4*kq+2)*68 + row] = vb.z;
            blds[(4*kq+3)*68 + row] = vb.w;
        }
        __syncthreads();
        #pragma unroll 8
        for (int k = 0; k < 32; ++k) {
            const float4 a = *(const float4*)&alds[k*68 + 4*ty];
            const float4 b = *(const float4*)&blds[k*68 + 4*tx];
            const float av[4] = {a.x, a.y, a.z, a.w};
            const float bv[4] = {b.x, b.y, b.z, b.w};
            #pragma unroll
            for (int i = 0; i < 4; ++i)
                #pragma unroll
                for (int j = 0; j < 4; ++j)
                    acc[i][j] = fmaf(av[i], bv[j], acc[i][j]);
        }
        __syncthreads();
    }

    const int col0 = e0 + 4 * tx;
    const float4 uu = *(const float4*)(uv + col0);
    const float vq4 = uv[256] * 0.25f;
    float psum[4];
    #pragma unroll
    for (int i = 0; i < 4; ++i) {
        const int row = m0 + 4 * ty + i;
        const float4 sv = *(const float4*)(S + (size_t)row * DM + col0);
        psum[i] = (acc[i][0] + 2.f * uu.x) * sv.x
                + (acc[i][1] + 2.f * uu.y) * sv.y
                + (acc[i][2] + 2.f * uu.z) * sv.z
                + (acc[i][3] + 2.f * uu.w) * sv.w + vq4;
    }
    float* red = alds;
    #pragma unroll
    for (int i = 0; i < 4; ++i) red[(4*ty + i) * 16 + tx] = psum[i];
    __syncthreads();
    if (t < 64) {
        float s = 0.f;
        #pragma unroll
        for (int x = 0; x < 16; ++x) s += red[t * 16 + x];
        zsqpart[(size_t)blockIdx.x * BKROWS + m0 + t] = s;
    }
}

// ---- zsq[r] = sum over NTZ partials (f64, deterministic) ----
__global__ void k_zsqred(const float* __restrict__ part, float* __restrict__ zsq) {
    const int r = blockIdx.x * 256 + threadIdx.x;
    double s = 0.0;
    #pragma unroll
    for (int b = 0; b < NTZ; ++b) s += (double)part[(size_t)b * BKROWS + r];
    zsq[r] = (float)s;
}

// ---- k_fdist2: fused dist GEMM (K=256, direct-global MFMA) + LDS G-tile
//      roundtrip + PROVEN k_post epilogue verbatim. Block = 32 rows x 1024 codes.
__global__ __launch_bounds__(512, 2)
void k_fdist2(const unsigned short* __restrict__ Sh, const unsigned short* __restrict__ Sm,
              const unsigned short* __restrict__ Ph, const unsigned short* __restrict__ Pm,
              const float* __restrict__ bsq, const float* __restrict__ zsq,
              float* __restrict__ A, float* __restrict__ wgpart,
              int* __restrict__ idxws, float* __restrict__ out) {
    __shared__ float gtile[32 * 1024];   // 128 KB; re-used by epilogue after reads

    const int bid  = blockIdx.x;
    const int wr0  = bid * 32;
    const int t    = threadIdx.x;
    const int w    = t >> 6, l = t & 63;
    const int lrow = l & 15;
    const int lu   = l >> 4;
    const int wc0  = w * 128;            // wave's 128-code slice

    // ---- phase 1: MFMA, fragments loaded directly from global (L2-hot) ----
    // Fragment k-window identical to verified k_gemm2 LDS path: k = c*32 + lu*8.
    f32x4 acc2[2][8];
    #pragma unroll
    for (int rf = 0; rf < 2; ++rf)
        #pragma unroll
        for (int f = 0; f < 8; ++f) acc2[rf][f] = (f32x4){0.f, 0.f, 0.f, 0.f};

    for (int c = 0; c < 8; ++c) {
        bf16x8 ah[2], am[2];
        #pragma unroll
        for (int rf = 0; rf < 2; ++rf) {
            const size_t off = (size_t)(wr0 + rf * 16 + lrow) * DM + c * 32 + lu * 8;
            ah[rf] = *(const bf16x8*)(Sh + off);
            am[rf] = *(const bf16x8*)(Sm + off);
        }
        #pragma unroll
        for (int f = 0; f < 8; ++f) {
            const size_t off = (size_t)(wc0 + f * 16 + lrow) * DM + c * 32 + lu * 8;
            const bf16x8 bh = *(const bf16x8*)(Ph + off);
            const bf16x8 bm = *(const bf16x8*)(Pm + off);
            #pragma unroll
            for (int rf = 0; rf < 2; ++rf) {
                f32x4 cc = acc2[rf][f];
                cc = __builtin_amdgcn_mfma_f32_16x16x32_bf16(ah[rf], bh, cc, 0, 0, 0);
                cc = __builtin_amdgcn_mfma_f32_16x16x32_bf16(ah[rf], bm, cc, 0, 0, 0);
                cc = __builtin_amdgcn_mfma_f32_16x16x32_bf16(am[rf], bh, cc, 0, 0, 0);
                acc2[rf][f] = cc;
            }
        }
    }

    // ---- store G-tile to LDS with the verified C-layout mapping (k_gemm2's store) ----
    #pragma unroll
    for (int rf = 0; rf < 2; ++rf)
        #pragma unroll
        for (int f = 0; f < 8; ++f) {
            const int col = wc0 + f * 16 + lrow;
            #pragma unroll
            for (int r = 0; r < 4; ++r) {
                const int row = rf * 16 + lu * 4 + r;
                gtile[row * 1024 + col] = acc2[rf][f][r];
            }
        }
    __syncthreads();

    // ==== phase 2: k_post epilogue VERBATIM, G reads -> gtile ====
    const int cg = t & 127;
    const int rq = t >> 7;
    const int r0 = rq * 8;
    const int c0 = cg * 4;
    const int c1 = 512 + cg * 4;

    float acc[8][8];
    #pragma unroll
    for (int i = 0; i < 8; ++i) {
        const float4 g0 = *(const float4*)&gtile[(r0 + i) * 1024 + c0];
        const float4 g1 = *(const float4*)&gtile[(r0 + i) * 1024 + c1];
        acc[i][0] = g0.x; acc[i][1] = g0.y; acc[i][2] = g0.z; acc[i][3] = g0.w;
        acc[i][4] = g1.x; acc[i][5] = g1.y; acc[i][6] = g1.z; acc[i][7] = g1.w;
    }
    __syncthreads();   // all reads done before overlaying red arrays on gtile

    float* red_v    = gtile;                 // [32][128]
    int*   red_i    = (int*)(gtile + 4096);  // [32][128]
    float* row_dmin = gtile + 8192;          // [32]
    float* row_s    = gtile + 8224;          // [32]
    float* pc       = gtile + 8256;          // [1024]

    float bsqv[8], zsqv[8];
    #pragma unroll
    for (int j = 0; j < 4; ++j) { bsqv[j] = bsq[c0 + j]; bsqv[4 + j] = bsq[c1 + j]; }
    #pragma unroll
    for (int i = 0; i < 8; ++i) zsqv[i] = zsq[wr0 + r0 + i];

    #pragma unroll
    for (int i = 0; i < 8; ++i)
        #pragma unroll
        for (int j = 0; j < 8; ++j) {
            const float tv = zsqv[i] - 2.f * acc[i][j];
            acc[i][j] = tv + bsqv[j];
        }

    #pragma unroll
    for (int i = 0; i < 8; ++i) {
        float bv = acc[i][0]; int bi = c0;
        #pragma unroll
        for (int j = 1; j < 8; ++j) {
            const int c = (j < 4) ? (c0 + j) : (c1 + (j - 4));
            if (acc[i][j] < bv || (acc[i][j] == bv && c < bi)) { bv = acc[i][j]; bi = c; }
        }
        red_v[(r0 + i) * 128 + cg] = bv;
        red_i[(r0 + i) * 128 + cg] = bi;
    }
    __syncthreads();
    if (t < 32) {
        float bv = red_v[t * 128]; int bi = red_i[t * 128];
        for (int x = 1; x < 128; ++x) {
            const float v = red_v[t * 128 + x];
            const int  iv = red_i[t * 128 + x];
            if (v < bv || (v == bv && iv < bi)) { bv = v; bi = iv; }
        }
        row_dmin[t] = bv;
        idxws[wr0 + t] = bi;
        out[IDX_OFF + wr0 + t] = (float)bi;
    }
    __syncthreads();

    float su[8];
    #pragma unroll
    for (int i = 0; i < 8; ++i) {
        const float dm = row_dmin[r0 + i];
        float s = 0.f;
        #pragma unroll
        for (int j = 0; j < 8; ++j) {
            const float u = expf(dm - acc[i][j]);
            acc[i][j] = u;
            s += u;
        }
        su[i] = s;
    }
    #pragma unroll
    for (int i = 0; i < 8; ++i) red_v[(r0 + i) * 128 + cg] = su[i];
    __syncthreads();
    if (t < 32) {
        float s = 0.f;
        for (int x = 0; x < 128; ++x) s += red_v[t * 128 + x];
        row_s[t] = s;
    }
    __syncthreads();

    float rcp[8];
    #pragma unroll
    for (int i = 0; i < 8; ++i) rcp[i] = 1.f / row_s[r0 + i];

    pc[t] = 0.f; pc[t + 512] = 0.f;
    __syncthreads();
    #pragma unroll
    for (int j = 0; j < 8; ++j) {
        const int c = (j < 4) ? (c0 + j) : (c1 + (j - 4));
        float s = 0.f;
        #pragma unroll
        for (int i = 0; i < 8; ++i) s += acc[i][j] * rcp[i];
        atomicAdd(&pc[c], s);
    }
    __syncthreads();
    atomicAdd(&A[t],       pc[t]);
    atomicAdd(&A[t + 512], pc[t + 512]);

    if (t == 0) {
        float s = 0.f;
        for (int r = 0; r < 32; ++r) s += row_dmin[r];
        wgpart[bid] = s;
    }
}

// ---- finalize scalars ----
__global__ void k_final(const float* __restrict__ wgpart, const float* __restrict__ A,
                        float* __restrict__ out) {
    __shared__ double sd[1024];
    const int t = threadIdx.x;
    sd[t] = (double)wgpart[t];
    __syncthreads();
    for (int off = 512; off > 0; off >>= 1) {
        if (t < off) sd[t] += sd[t + off];
        __syncthreads();
    }
    if (t == 0) out[VQ_OFF] = (float)(0.25 * sd[0] / 88473600.0);
    __syncthreads();
    const double p = (double)A[t] * (1.0 / 32768.0);
    sd[t] = -p * log(p + 1e-8);
    __syncthreads();
    for (int off = 512; off > 0; off >>= 1) {
        if (t < off) sd[t] += sd[t + off];
        __syncthreads();
    }
    if (t == 0) out[ENT_OFF] = (float)sd[0];
}

// ---- q_st = basis[indices] ----
__global__ void k_gather(const float* __restrict__ basis, const int* __restrict__ idxws,
                         float* __restrict__ out) {
    const int r = blockIdx.x;
    const int idx = idxws[r];
    const float4* src = (const float4*)(basis + (size_t)idx * ED);
    float4* dst = (float4*)(out + (size_t)r * ED);
    for (int j = threadIdx.x; j < ED / 4; j += 256) dst[j] = src[j];
}

// =====================================================================
// ===================== FALLBACK (round-2, f32 VALU) ==================
// =====================================================================

__global__ void k_bsq(const float* __restrict__ basis, float* __restrict__ bsq) {
    int c = blockIdx.x;
    const float* row = basis + (size_t)c * ED;
    double s = 0.0;
    for (int j = threadIdx.x; j < ED; j += 256) { float v = row[j]; s += (double)v * (double)v; }
    __shared__ double sd[256];
    sd[threadIdx.x] = s;
    __syncthreads();
    for (int off = 128; off > 0; off >>= 1) {
        if (threadIdx.x < off) sd[threadIdx.x] += sd[threadIdx.x + off];
        __syncthreads();
    }
    if (threadIdx.x == 0) bsq[c] = (float)sd[0];
}

__global__ __launch_bounds__(256, 4)
void k_gemm1(const float* __restrict__ S, const float* __restrict__ W,
             const float* __restrict__ bproj, float* __restrict__ Z) {
    const int e0 = blockIdx.x * 64;
    const int m0 = blockIdx.y * 64;
    const int t  = threadIdx.x;
    const int tx = t & 15, ty = t >> 4;
    __shared__ float alds[32 * 68];
    __shared__ float blds[32 * 68];
    float acc[4][4] = {};
    for (int k0 = 0; k0 < DM; k0 += 32) {
        #pragma unroll
        for (int rep = 0; rep < 2; ++rep) {
            const int id  = t + rep * 256;
            const int row = id >> 3, kq = id & 7;
            const float4 va = *(const float4*)(S + (size_t)(m0 + row) * DM + k0 + 4 * kq);
            alds[(4*kq+0)*68 + row] = va.x;
            alds[(4*kq+1)*68 + row] = va.y;
            alds[(4*kq+2)*68 + row] = va.z;
            alds[(4*kq+3)*68 + row] = va.w;
            float4 vb = make_float4(0.f, 0.f, 0.f, 0.f);
            if (e0 + row < ED)
                vb = *(const float4*)(W + (size_t)(e0 + row) * DM + k0 + 4 * kq);
            blds[(4*kq+0)*68 + row] = vb.x;
            blds[(4*kq+1)*68 + row] = vb.y;
            blds[(4*kq+2)*68 + row] = vb.z;
            blds[(4*kq+3)*68 + row] = vb.w;
        }
        __syncthreads();
        #pragma unroll 8
        for (int k = 0; k < 32; ++k) {
            const float4 a = *(const float4*)&alds[k*68 + 4*ty];
            const float4 b = *(const float4*)&blds[k*68 + 4*tx];
            const float av[4] = {a.x, a.y, a.z, a.w};
            const float bv[4] = {b.x, b.y, b.z, b.w};
            #pragma unroll
            for (int i = 0; i < 4; ++i)
                #pragma unroll
                for (int j = 0; j < 4; ++j)
                    acc[i][j] = fmaf(av[i], bv[j], acc[i][j]);
        }
        __syncthreads();
    }
    const bool valid = (e0 + 4*tx + 4) <= ED;
    float4 bias = make_float4(0.f, 0.f, 0.f, 0.f);
    if (valid) bias = *(const float4*)(bproj + e0 + 4*tx);
    #pragma unroll
    for (int i = 0; i < 4; ++i) {
        if (valid) {
            float4 o;
            o.x = acc[i][0] + bias.x;
            o.y = acc[i][1] + bias.y;
            o.z = acc[i][2] + bias.z;
            o.w = acc[i][3] + bias.w;
            *(float4*)(Z + (size_t)(m0 + 4*ty + i) * ED + e0 + 4*tx) = o;
        }
    }
}

__global__ __launch_bounds__(64)
void k_zsq(const float* __restrict__ Z, float* __restrict__ zsq) {
    const int r = blockIdx.x;
    const float4* row4 = (const float4*)(Z + (size_t)r * ED);
    double s = 0.0;
    for (int q = threadIdx.x; q < ED / 4; q += 64) {
        const float4 v = row4[q];
        s += (double)v.x * v.x + (double)v.y * v.y + (double)v.z * v.z + (double)v.w * v.w;
    }
    #pragma unroll
    for (int off = 32; off > 0; off >>= 1) s += __shfl_down(s, off);
    if (threadIdx.x == 0) zsq[r] = (float)s;
}

__global__ __launch_bounds__(512, 2)
void k_dist(const float* __restrict__ Z, const float* __restrict__ basis,
            const float* __restrict__ bsq, const float* __restrict__ zsq,
            float* __restrict__ A, float* __restrict__ wgpart,
            int* __restrict__ idxws, float* __restrict__ out) {
    const int bid = blockIdx.x;
    const int wr0 = bid * 32;
    const int t   = threadIdx.x;
    const int cg  = t & 127;
    const int rq  = t >> 7;
    const int r0  = rq * 8;
    const int c0  = cg * 4;
    const int c1  = 512 + cg * 4;
    __shared__ float blds[16 * 1024];
    __shared__ float zlds[16 * 36];
    float acc[8][8];
    #pragma unroll
    for (int i = 0; i < 8; ++i)
        #pragma unroll
        for (int j = 0; j < 8; ++j) acc[i][j] = 0.f;
    for (int k0 = 0; k0 < ED; k0 += 16) {
        const bool full = (k0 + 16) <= ED;
        #pragma unroll
        for (int rep = 0; rep < 2; ++rep) {
            const int c = t + rep * 512;
            const float* bp = basis + (size_t)c * ED + k0;
            if (full) {
                const float4 v0 = *(const float4*)(bp + 0);
                const float4 v1 = *(const float4*)(bp + 4);
                const float4 v2 = *(const float4*)(bp + 8);
                const float4 v3 = *(const float4*)(bp + 12);
                blds[ 0*1024+c]=v0.x; blds[ 1*1024+c]=v0.y; blds[ 2*1024+c]=v0.z; blds[ 3*1024+c]=v0.w;
                blds[ 4*1024+c]=v1.x; blds[ 5*1024+c]=v1.y; blds[ 6*1024+c]=v1.z; blds[ 7*1024+c]=v1.w;
                blds[ 8*1024+c]=v2.x; blds[ 9*1024+c]=v2.y; blds[10*1024+c]=v2.z; blds[11*1024+c]=v2.w;
                blds[12*1024+c]=v3.x; blds[13*1024+c]=v3.y; blds[14*1024+c]=v3.z; blds[15*1024+c]=v3.w;
            } else {
                for (int kk = 0; kk < 16; ++kk)
                    blds[kk*1024 + c] = (k0 + kk < ED) ? bp[kk] : 0.f;
            }
        }
        if (t < 128) {
            const int row = t >> 2, kq = t & 3;
            const float* zp = Z + (size_t)(wr0 + row) * ED + k0 + 4 * kq;
            if (full) {
                const float4 v = *(const float4*)zp;
                zlds[(4*kq+0)*36 + row] = v.x;
                zlds[(4*kq+1)*36 + row] = v.y;
                zlds[(4*kq+2)*36 + row] = v.z;
                zlds[(4*kq+3)*36 + row] = v.w;
            } else {
                for (int j = 0; j < 4; ++j) {
                    const int k = k0 + 4*kq + j;
                    zlds[(4*kq+j)*36 + row] = (k < ED) ? zp[j] : 0.f;
                }
            }
        }
        __syncthreads();
        #pragma unroll
        for (int k = 0; k < 16; ++k) {
            const float4 z0 = *(const float4*)&zlds[k*36 + r0];
            const float4 z1 = *(const float4*)&zlds[k*36 + r0 + 4];
            const float4 b0 = *(const float4*)&blds[k*1024 + c0];
            const float4 b1 = *(const float4*)&blds[k*1024 + c1];
            const float zz[8] = {z0.x, z0.y, z0.z, z0.w, z1.x, z1.y, z1.z, z1.w};
            const float bb[8] = {b0.x, b0.y, b0.z, b0.w, b1.x, b1.y, b1.z, b1.w};
            #pragma unroll
            for (int i = 0; i < 8; ++i)
                #pragma unroll
                for (int j = 0; j < 8; ++j)
                    acc[i][j] = fmaf(zz[i], bb[j], acc[i][j]);
        }
        __syncthreads();
    }
    float* red_v    = blds;
    int*   red_i    = (int*)(blds + 4096);
    float* row_dmin = blds + 8192;
    float* row_s    = blds + 8224;
    float* pc       = blds + 8256;
    float bsqv[8], zsqv[8];
    #pragma unroll
    for (int j = 0; j < 4; ++j) { bsqv[j] = bsq[c0 + j]; bsqv[4 + j] = bsq[c1 + j]; }
    #pragma unroll
    for (int i = 0; i < 8; ++i) zsqv[i] = zsq[wr0 + r0 + i];
    #pragma unroll
    for (int i = 0; i < 8; ++i)
        #pragma unroll
        for (int j = 0; j < 8; ++j) {
            const float tv = zsqv[i] - 2.f * acc[i][j];
            acc[i][j] = tv + bsqv[j];
        }
    #pragma unroll
    for (int i = 0; i < 8; ++i) {
        float bv = acc[i][0]; int bi = c0;
        #pragma unroll
        for (int j = 1; j < 8; ++j) {
            const int c = (j < 4) ? (c0 + j) : (c1 + (j - 4));
            if (acc[i][j] < bv || (acc[i][j] == bv && c < bi)) { bv = acc[i][j]; bi = c; }
        }
        red_v[(r0 + i) * 128 + cg] = bv;
        red_i[(r0 + i) * 128 + cg] = bi;
    }
    __syncthreads();
    if (t < 32) {
        float bv = red_v[t * 128]; int bi = red_i[t * 128];
        for (int x = 1; x < 128; ++x) {
            const float v = red_v[t * 128 + x];
            const int  iv = red_i[t * 128 + x];
            if (v < bv || (v == bv && iv < bi)) { bv = v; bi = iv; }
        }
        row_dmin[t] = bv;
        idxws[wr0 + t] = bi;
        out[IDX_OFF + wr0 + t] = (float)bi;
    }
    __syncthreads();
    float su[8];
    #pragma unroll
    for (int i = 0; i < 8; ++i) {
        const float dm = row_dmin[r0 + i];
        float s = 0.f;
        #pragma unroll
        for (int j = 0; j < 8; ++j) {
            const float u = expf(dm - acc[i][j]);
            acc[i][j] = u;
            s += u;
        }
        su[i] = s;
    }
    #pragma unroll
    for (int i = 0; i < 8; ++i) red_v[(r0 + i) * 128 + cg] = su[i];
    __syncthreads();
    if (t < 32) {
        float s = 0.f;
        for (int x = 0; x < 128; ++x) s += red_v[t * 128 + x];
        row_s[t] = s;
    }
    __syncthreads();
    float rcp[8];
    #pragma unroll
    for (int i = 0; i < 8; ++i) rcp[i] = 1.f / row_s[r0 + i];
    pc[t] = 0.f; pc[t + 512] = 0.f;
    __syncthreads();
    #pragma unroll
    for (int j = 0; j < 8; ++j) {
        const int c = (j < 4) ? (c0 + j) : (c1 + (j - 4));
        float s = 0.f;
        #pragma unroll
        for (int i = 0; i < 8; ++i) s += acc[i][j] * rcp[i];
        atomicAdd(&pc[c], s);
    }
    __syncthreads();
    atomicAdd(&A[t],       pc[t]);
    atomicAdd(&A[t + 512], pc[t + 512]);
    if (t == 0) {
        float s = 0.f;
        for (int r = 0; r < 32; ++r) s += row_dmin[r];
        wgpart[bid] = s;
    }
}

// =====================================================================

extern "C" void kernel_launch(void* const* d_in, const int* in_sizes, int n_in,
                              void* d_out, int out_size, void* d_ws, size_t ws_size,
                              hipStream_t stream) {
    const float* S     = (const float*)d_in[0];  // [32768, 256]
    const float* W     = (const float*)d_in[1];  // [2700, 256]
    const float* bproj = (const float*)d_in[2];  // [2700]
    const float* basis = (const float*)d_in[3];  // [1024, 2700]
    float* out = (float*)d_out;
    float* ws  = (float*)d_ws;

    // common small regions
    float* zsq    = ws;                  // 32768
    float* A      = ws + 32768;          // 1024
    float* bsq    = ws + 33792;          // 1024
    float* wgpart = ws + 34816;          // 1024
    int*   idxws  = (int*)(ws + 35840);  // 32768

    // ws floats: 68608 small + Ph/Pm 262144 + transients 5316992 = 5,647,744 (~22.6 MB)
    const size_t NEED = (size_t)5647744 * sizeof(float);
    if (ws_size >= NEED) {
        // -------- MFMA path (reassociated: G = S.(basis.W)^T, fused dist) --------
        unsigned short* Ph = (unsigned short*)(ws + 68608);            // 1024*256 ush
        unsigned short* Pm = (unsigned short*)(ws + 68608 + 131072);
        float* basisP  = ws + 330752;        // 1024*2720 = 2785280
        float* WT      = ws + 3116032;       // 256*2720  = 696320
        float* uv      = ws + 3812352;       // 257 (u[256], v)
        float* Pp      = ws + 3812736;       // 5*262144 = 1310720
        float* Mp      = ws + 5123456;       // 5*65536  = 327680
        float* Mm      = ws + 5451136;       // 65536
        float* zsqpart = ws + 5516672;       // 4*32768  = 131072 -> ends 5647744
        // S planes live in q_st output region (dead before k_gather writes q_st)
        unsigned short* Sh = (unsigned short*)out;                     // 32768*256 ush
        unsigned short* Sm = Sh + (size_t)BKROWS * DM;

        hipMemsetAsync(A, 0, (size_t)NC * sizeof(float), stream);
        k_packS <<<BKROWS * DM / 1024, 256, 0, stream>>>(S, Sh, Sm);
        k_bsq2  <<<NC, 256, 0, stream>>>(basis, bproj, bsq);
        k_padB  <<<NC, 256, 0, stream>>>(basis, basisP);
        k_padWT <<<dim3(43, 4), 256, 0, stream>>>(W, WT);
        k_uv2   <<<257, 256, 0, stream>>>(WT, bproj, uv);
        k_gsplit<<<dim3(4, 16, 5), 256, 0, stream>>>(basisP, WT, Pp, 256);  // P partials
        k_gsplit<<<dim3(4, 4, 5),  256, 0, stream>>>(WT, WT, Mp, 256);      // M partials
        k_redP  <<<1024, 256, 0, stream>>>(Pp, Ph, Pm);
        k_redM  <<<256, 256, 0, stream>>>(Mp, Mm);
        k_zsqS  <<<dim3(NTZ, 512), 256, 0, stream>>>(S, Mm, uv, zsqpart);
        k_zsqred<<<BKROWS / 256, 256, 0, stream>>>(zsqpart, zsq);
        k_fdist2<<<BKROWS / 32, 512, 0, stream>>>(Sh, Sm, Ph, Pm, bsq, zsq, A, wgpart, idxws, out);
        k_final <<<1, 1024, 0, stream>>>(wgpart, A, out);
        k_gather<<<BKROWS, 256, 0, stream>>>(basis, idxws, out);
    } else {
        // -------- fallback: round-2 f32 path --------
        float* Z = out;
        hipMemsetAsync(A, 0, (size_t)NC * sizeof(float), stream);
        k_bsq   <<<NC, 256, 0, stream>>>(basis, bsq);
        k_gemm1 <<<dim3(43, 512), 256, 0, stream>>>(S, W, bproj, Z);
        k_zsq   <<<BKROWS, 64, 0, stream>>>(Z, zsq);
        k_dist  <<<BKROWS / 32, 512, 0, stream>>>(Z, basis, bsq, zsq, A, wgpart, idxws, out);
        k_final <<<1, 1024, 0, stream>>>(wgpart, A, out);
        k_gather<<<BKROWS, 256, 0, stream>>>(basis, idxws, out);
    }
}

// Round 11
// 519.274 us; speedup vs baseline: 1.0059x; 1.0059x over previous
//
#include <hip/hip_runtime.h>
#include <math.h>

#define ED 2700     // basis_dim
#define NC 1024     // num_codes
#define DM 256      // d_model
#define BKROWS 32768

#define IDX_OFF 88473600
#define VQ_OFF  88506368
#define ENT_OFF 88506369

#define KPAD 2720     // padded K for P/M small GEMMs (5 x 544)
#define NTZ 4         // zsq n-tile partials
#define GSTR 1028     // gtile row stride (floats): 2-way-bank-free, 16B-aligned

typedef float  f32x4  __attribute__((ext_vector_type(4)));
typedef short  bf16x8 __attribute__((ext_vector_type(8)));

__device__ inline unsigned short f2bf(float x) {
    unsigned int u = __float_as_uint(x);
    unsigned int r = (u + 0x7FFFu + ((u >> 16) & 1u)) >> 16;
    return (unsigned short)r;
}
__device__ inline float bf2f(unsigned short h) {
    return __uint_as_float(((unsigned int)h) << 16);
}

// =====================================================================
// ============================ MFMA PATH ==============================
// =====================================================================

// ---- S -> Sh/Sm bf16 planes ----
__global__ __launch_bounds__(256)
void k_packS(const float* __restrict__ S, unsigned short* __restrict__ Sh,
             unsigned short* __restrict__ Sm) {
    const size_t i4 = (size_t)blockIdx.x * 256 + threadIdx.x;
    const float4 v = *(const float4*)(S + i4 * 4);
    ushort4 hv, mv;
    unsigned short* hp = (unsigned short*)&hv;
    unsigned short* mp = (unsigned short*)&mv;
    const float xs[4] = {v.x, v.y, v.z, v.w};
    #pragma unroll
    for (int j = 0; j < 4; ++j) {
        const unsigned short h = f2bf(xs[j]);
        hp[j] = h;
        mp[j] = f2bf(xs[j] - bf2f(h));
    }
    *(ushort4*)(Sh + i4 * 4) = hv;
    *(ushort4*)(Sm + i4 * 4) = mv;
}

// ---- bsq'[c] = sum basis^2 - 2*basis.bproj (f64) ----
__global__ void k_bsq2(const float* __restrict__ basis, const float* __restrict__ bproj,
                       float* __restrict__ bsq) {
    const int c = blockIdx.x;
    const int t = threadIdx.x;
    const float* row = basis + (size_t)c * ED;
    double s2 = 0.0, sp = 0.0;
    for (int j = t; j < ED; j += 256) {
        const float x = row[j];
        s2 += (double)x * (double)x;
        sp += (double)x * (double)bproj[j];
    }
    __shared__ double sd[512];
    sd[t] = s2; sd[256 + t] = sp;
    __syncthreads();
    for (int off = 128; off > 0; off >>= 1) {
        if (t < off) { sd[t] += sd[t + off]; sd[256 + t] += sd[256 + t + off]; }
        __syncthreads();
    }
    if (t == 0) bsq[c] = (float)(sd[0] - 2.0 * sd[256]);
}

// ---- basisP = basis zero-padded to [1024][2720] ----
__global__ __launch_bounds__(256)
void k_padB(const float* __restrict__ basis, float* __restrict__ bP) {
    const int c = blockIdx.x;
    const float4* src = (const float4*)(basis + (size_t)c * ED);
    float4* dst = (float4*)(bP + (size_t)c * KPAD);
    for (int q = threadIdx.x; q < KPAD / 4; q += 256)
        dst[q] = (q < ED / 4) ? src[q] : make_float4(0.f, 0.f, 0.f, 0.f);
}

// ---- WT = W^T zero-padded to [256][2720] ----
__global__ __launch_bounds__(256)
void k_padWT(const float* __restrict__ W, float* __restrict__ WT) {
    const int e0 = blockIdx.x * 64;
    const int d0 = blockIdx.y * 64;
    __shared__ float tbuf[64][65];
    const int t  = threadIdx.x;
    const int r  = t >> 2;
    const int q4 = t & 3;
    #pragma unroll
    for (int j = 0; j < 4; ++j) {
        const int col = q4 * 16 + j * 4;
        const int e = e0 + r;
        float4 v = make_float4(0.f, 0.f, 0.f, 0.f);
        if (e < ED) v = *(const float4*)(W + (size_t)e * DM + d0 + col);
        tbuf[r][col + 0] = v.x; tbuf[r][col + 1] = v.y;
        tbuf[r][col + 2] = v.z; tbuf[r][col + 3] = v.w;
    }
    __syncthreads();
    #pragma unroll
    for (int j = 0; j < 4; ++j) {
        const int col = q4 * 16 + j * 4;
        if (e0 + col < KPAD) {
            float4 o;
            o.x = tbuf[col + 0][r]; o.y = tbuf[col + 1][r];
            o.z = tbuf[col + 2][r]; o.w = tbuf[col + 3][r];
            *(float4*)(WT + (size_t)(d0 + r) * KPAD + e0 + col) = o;
        }
    }
}

// ---- k_uv2: u[d] = WT[d].bproj (blocks 0..255); v = ||bproj||^2 (block 256) ----
__global__ __launch_bounds__(256)
void k_uv2(const float* __restrict__ WT, const float* __restrict__ bproj,
           float* __restrict__ uv) {
    const int b = blockIdx.x;
    const int t = threadIdx.x;
    double s = 0.0;
    if (b < 256) {
        const float* row = WT + (size_t)b * KPAD;
        for (int j = t; j < ED; j += 256) s += (double)row[j] * (double)bproj[j];
    } else {
        for (int j = t; j < ED; j += 256) { const double x = bproj[j]; s += x * x; }
    }
    __shared__ double sd[256];
    sd[t] = s;
    __syncthreads();
    for (int off = 128; off > 0; off >>= 1) {
        if (t < off) sd[t] += sd[t + off];
        __syncthreads();
    }
    if (t == 0) uv[b] = (float)sd[0];
}

// ---- generic 64x64-tile f32 GEMM partial over K-slab of 544 ----
__global__ __launch_bounds__(256)
void k_gsplit(const float* __restrict__ A, const float* __restrict__ B,
              float* __restrict__ Cp, int nld) {
    const int n0  = blockIdx.x * 64;
    const int m0  = blockIdx.y * 64;
    const int k00 = blockIdx.z * 544;
    float* Cout = Cp + (size_t)blockIdx.z * (size_t)gridDim.y * 64 * nld;
    const int t  = threadIdx.x;
    const int tx = t & 15, ty = t >> 4;

    __shared__ float alds[32 * 68];
    __shared__ float blds[32 * 68];

    float acc[4][4] = {};

    for (int k0 = k00; k0 < k00 + 544; k0 += 32) {
        #pragma unroll
        for (int rep = 0; rep < 2; ++rep) {
            const int id  = t + rep * 256;
            const int row = id >> 3, kq = id & 7;
            const float4 va = *(const float4*)(A + (size_t)(m0 + row) * KPAD + k0 + 4 * kq);
            alds[(4*kq+0)*68 + row] = va.x;
            alds[(4*kq+1)*68 + row] = va.y;
            alds[(4*kq+2)*68 + row] = va.z;
            alds[(4*kq+3)*68 + row] = va.w;
            const float4 vb = *(const float4*)(B + (size_t)(n0 + row) * KPAD + k0 + 4 * kq);
            blds[(4*kq+0)*68 + row] = vb.x;
            blds[(4*kq+1)*68 + row] = vb.y;
            blds[(4*kq+2)*68 + row] = vb.z;
            blds[(4*kq+3)*68 + row] = vb.w;
        }
        __syncthreads();
        #pragma unroll 8
        for (int k = 0; k < 32; ++k) {
            const float4 a = *(const float4*)&alds[k*68 + 4*ty];
            const float4 b = *(const float4*)&blds[k*68 + 4*tx];
            const float av[4] = {a.x, a.y, a.z, a.w};
            const float bv[4] = {b.x, b.y, b.z, b.w};
            #pragma unroll
            for (int i = 0; i < 4; ++i)
                #pragma unroll
                for (int j = 0; j < 4; ++j)
                    acc[i][j] = fmaf(av[i], bv[j], acc[i][j]);
        }
        __syncthreads();
    }
    #pragma unroll
    for (int i = 0; i < 4; ++i) {
        float4 o; o.x = acc[i][0]; o.y = acc[i][1]; o.z = acc[i][2]; o.w = acc[i][3];
        *(float4*)(Cout + (size_t)(m0 + 4*ty + i) * nld + n0 + 4*tx) = o;
    }
}

// ---- reduce 5 P-partials -> Ph/Pm planes ----
__global__ __launch_bounds__(256)
void k_redP(const float* __restrict__ Pp, unsigned short* __restrict__ Ph,
            unsigned short* __restrict__ Pm) {
    const size_t idx = (size_t)blockIdx.x * 256 + threadIdx.x;
    float s = 0.f;
    #pragma unroll
    for (int k = 0; k < 5; ++k) s += Pp[(size_t)k * 262144 + idx];
    const unsigned short h = f2bf(s);
    Ph[idx] = h;
    Pm[idx] = f2bf(s - bf2f(h));
}

// ---- reduce 5 M-partials -> M f32 ----
__global__ __launch_bounds__(256)
void k_redM(const float* __restrict__ Mp, float* __restrict__ M) {
    const size_t idx = (size_t)blockIdx.x * 256 + threadIdx.x;
    float s = 0.f;
    #pragma unroll
    for (int k = 0; k < 5; ++k) s += Mp[(size_t)k * 65536 + idx];
    M[idx] = s;
}

// ---- zsq partials: zsq_r = S_r M S_r^T + 2 S_r.u + v ----
__global__ __launch_bounds__(256)
void k_zsqS(const float* __restrict__ S, const float* __restrict__ M,
            const float* __restrict__ uv, float* __restrict__ zsqpart) {
    const int e0 = blockIdx.x * 64;
    const int m0 = blockIdx.y * 64;
    const int t  = threadIdx.x;
    const int tx = t & 15, ty = t >> 4;

    __shared__ float alds[32 * 68];
    __shared__ float blds[32 * 68];

    float acc[4][4] = {};

    for (int k0 = 0; k0 < DM; k0 += 32) {
        #pragma unroll
        for (int rep = 0; rep < 2; ++rep) {
            const int id  = t + rep * 256;
            const int row = id >> 3, kq = id & 7;
            const float4 va = *(const float4*)(S + (size_t)(m0 + row) * DM + k0 + 4 * kq);
            alds[(4*kq+0)*68 + row] = va.x;
            alds[(4*kq+1)*68 + row] = va.y;
            alds[(4*kq+2)*68 + row] = va.z;
            alds[(4*kq+3)*68 + row] = va.w;
            const float4 vb = *(const float4*)(M + (size_t)(e0 + row) * DM + k0 + 4 * kq);
            blds[(4*kq+0)*68 + row] = vb.x;
            blds[(4*kq+1)*68 + row] = vb.y;
            blds[(4*kq+2)*68 + row] = vb.z;
            blds[(4*kq+3)*68 + row] = vb.w;
        }
        __syncthreads();
        #pragma unroll 8
        for (int k = 0; k < 32; ++k) {
            const float4 a = *(const float4*)&alds[k*68 + 4*ty];
            const float4 b = *(const float4*)&blds[k*68 + 4*tx];
            const float av[4] = {a.x, a.y, a.z, a.w};
            const float bv[4] = {b.x, b.y, b.z, b.w};
            #pragma unroll
            for (int i = 0; i < 4; ++i)
                #pragma unroll
                for (int j = 0; j < 4; ++j)
                    acc[i][j] = fmaf(av[i], bv[j], acc[i][j]);
        }
        __syncthreads();
    }

    const int col0 = e0 + 4 * tx;
    const float4 uu = *(const float4*)(uv + col0);
    const float vq4 = uv[256] * 0.25f;
    float psum[4];
    #pragma unroll
    for (int i = 0; i < 4; ++i) {
        const int row = m0 + 4 * ty + i;
        const float4 sv = *(const float4*)(S + (size_t)row * DM + col0);
        psum[i] = (acc[i][0] + 2.f * uu.x) * sv.x
                + (acc[i][1] + 2.f * uu.y) * sv.y
                + (acc[i][2] + 2.f * uu.z) * sv.z
                + (acc[i][3] + 2.f * uu.w) * sv.w + vq4;
    }
    float* red = alds;
    #pragma unroll
    for (int i = 0; i < 4; ++i) red[(4*ty + i) * 16 + tx] = psum[i];
    __syncthreads();
    if (t < 64) {
        float s = 0.f;
        #pragma unroll
        for (int x = 0; x < 16; ++x) s += red[t * 16 + x];
        zsqpart[(size_t)blockIdx.x * BKROWS + m0 + t] = s;
    }
}

// ---- zsq[r] = sum over NTZ partials (f64, deterministic) ----
__global__ void k_zsqred(const float* __restrict__ part, float* __restrict__ zsq) {
    const int r = blockIdx.x * 256 + threadIdx.x;
    double s = 0.0;
    #pragma unroll
    for (int b = 0; b < NTZ; ++b) s += (double)part[(size_t)b * BKROWS + r];
    zsq[r] = (float)s;
}

// ---- k_fdist2: fused dist GEMM (K=256, direct-global MFMA, 2-deep register
//      pipeline) + padded-LDS G-tile roundtrip + PROVEN k_post epilogue.
__global__ __launch_bounds__(512, 2)
void k_fdist2(const unsigned short* __restrict__ Sh, const unsigned short* __restrict__ Sm,
              const unsigned short* __restrict__ Ph, const unsigned short* __restrict__ Pm,
              const float* __restrict__ bsq, const float* __restrict__ zsq,
              float* __restrict__ A, float* __restrict__ wgpart,
              int* __restrict__ idxws, float* __restrict__ out) {
    __shared__ float gtile[32 * GSTR];   // ~131.6 KB; reused by epilogue

    const int bid  = blockIdx.x;
    const int wr0  = bid * 32;
    const int t    = threadIdx.x;
    const int w    = t >> 6, l = t & 63;
    const int lrow = l & 15;
    const int lu   = l >> 4;
    const int wc0  = w * 128;            // wave's 128-code slice

    f32x4 acc2[2][8];
    #pragma unroll
    for (int rf = 0; rf < 2; ++rf)
        #pragma unroll
        for (int f = 0; f < 8; ++f) acc2[rf][f] = (f32x4){0.f, 0.f, 0.f, 0.f};

    // 2-deep chunk pipeline: named buffer sets (static indexing, no scratch).
    #define LOADC(c, AH, AM, BH, BM) { \
        _Pragma("unroll") \
        for (int f = 0; f < 8; ++f) { \
            const size_t off = (size_t)(wc0 + f * 16 + lrow) * DM + (c) * 32 + lu * 8; \
            BH[f] = *(const bf16x8*)(Ph + off); \
            BM[f] = *(const bf16x8*)(Pm + off); \
        } \
        _Pragma("unroll") \
        for (int rf = 0; rf < 2; ++rf) { \
            const size_t off = (size_t)(wr0 + rf * 16 + lrow) * DM + (c) * 32 + lu * 8; \
            AH[rf] = *(const bf16x8*)(Sh + off); \
            AM[rf] = *(const bf16x8*)(Sm + off); \
        } }
    #define MFMAC(AH, AM, BH, BM) { \
        _Pragma("unroll") \
        for (int f = 0; f < 8; ++f) \
            _Pragma("unroll") \
            for (int rf = 0; rf < 2; ++rf) { \
                f32x4 cc = acc2[rf][f]; \
                cc = __builtin_amdgcn_mfma_f32_16x16x32_bf16(AH[rf], BH[f], cc, 0, 0, 0); \
                cc = __builtin_amdgcn_mfma_f32_16x16x32_bf16(AH[rf], BM[f], cc, 0, 0, 0); \
                cc = __builtin_amdgcn_mfma_f32_16x16x32_bf16(AM[rf], BH[f], cc, 0, 0, 0); \
                acc2[rf][f] = cc; \
            } }

    {
        bf16x8 ah0[2], am0[2], bh0[8], bm0[8];
        bf16x8 ah1[2], am1[2], bh1[8], bm1[8];
        LOADC(0, ah0, am0, bh0, bm0)
        LOADC(1, ah1, am1, bh1, bm1)
        #pragma unroll
        for (int cc = 0; cc < 4; ++cc) {
            MFMAC(ah0, am0, bh0, bm0)
            if (cc < 3) LOADC(2 * cc + 2, ah0, am0, bh0, bm0)
            MFMAC(ah1, am1, bh1, bm1)
            if (cc < 3) LOADC(2 * cc + 3, ah1, am1, bh1, bm1)
        }
    }
    #undef LOADC
    #undef MFMAC

    // ---- store G-tile to LDS with the verified C-layout mapping ----
    #pragma unroll
    for (int rf = 0; rf < 2; ++rf)
        #pragma unroll
        for (int f = 0; f < 8; ++f) {
            const int col = wc0 + f * 16 + lrow;
            #pragma unroll
            for (int r = 0; r < 4; ++r) {
                const int row = rf * 16 + lu * 4 + r;
                gtile[row * GSTR + col] = acc2[rf][f][r];
            }
        }
    __syncthreads();

    // ==== phase 2: k_post epilogue VERBATIM, G reads -> gtile ====
    const int cg = t & 127;
    const int rq = t >> 7;
    const int r0 = rq * 8;
    const int c0 = cg * 4;
    const int c1 = 512 + cg * 4;

    float acc[8][8];
    #pragma unroll
    for (int i = 0; i < 8; ++i) {
        const float4 g0 = *(const float4*)&gtile[(r0 + i) * GSTR + c0];
        const float4 g1 = *(const float4*)&gtile[(r0 + i) * GSTR + c1];
        acc[i][0] = g0.x; acc[i][1] = g0.y; acc[i][2] = g0.z; acc[i][3] = g0.w;
        acc[i][4] = g1.x; acc[i][5] = g1.y; acc[i][6] = g1.z; acc[i][7] = g1.w;
    }
    __syncthreads();   // all reads done before overlaying red arrays on gtile

    float* red_v    = gtile;                 // [32][128]
    int*   red_i    = (int*)(gtile + 4096);  // [32][128]
    float* row_dmin = gtile + 8192;          // [32]
    float* row_s    = gtile + 8224;          // [32]
    float* pc       = gtile + 8256;          // [1024]

    float bsqv[8], zsqv[8];
    #pragma unroll
    for (int j = 0; j < 4; ++j) { bsqv[j] = bsq[c0 + j]; bsqv[4 + j] = bsq[c1 + j]; }
    #pragma unroll
    for (int i = 0; i < 8; ++i) zsqv[i] = zsq[wr0 + r0 + i];

    #pragma unroll
    for (int i = 0; i < 8; ++i)
        #pragma unroll
        for (int j = 0; j < 8; ++j) {
            const float tv = zsqv[i] - 2.f * acc[i][j];
            acc[i][j] = tv + bsqv[j];
        }

    #pragma unroll
    for (int i = 0; i < 8; ++i) {
        float bv = acc[i][0]; int bi = c0;
        #pragma unroll
        for (int j = 1; j < 8; ++j) {
            const int c = (j < 4) ? (c0 + j) : (c1 + (j - 4));
            if (acc[i][j] < bv || (acc[i][j] == bv && c < bi)) { bv = acc[i][j]; bi = c; }
        }
        red_v[(r0 + i) * 128 + cg] = bv;
        red_i[(r0 + i) * 128 + cg] = bi;
    }
    __syncthreads();
    if (t < 32) {
        float bv = red_v[t * 128]; int bi = red_i[t * 128];
        for (int x = 1; x < 128; ++x) {
            const float v = red_v[t * 128 + x];
            const int  iv = red_i[t * 128 + x];
            if (v < bv || (v == bv && iv < bi)) { bv = v; bi = iv; }
        }
        row_dmin[t] = bv;
        idxws[wr0 + t] = bi;
        out[IDX_OFF + wr0 + t] = (float)bi;
    }
    __syncthreads();

    float su[8];
    #pragma unroll
    for (int i = 0; i < 8; ++i) {
        const float dm = row_dmin[r0 + i];
        float s = 0.f;
        #pragma unroll
        for (int j = 0; j < 8; ++j) {
            const float u = expf(dm - acc[i][j]);
            acc[i][j] = u;
            s += u;
        }
        su[i] = s;
    }
    #pragma unroll
    for (int i = 0; i < 8; ++i) red_v[(r0 + i) * 128 + cg] = su[i];
    __syncthreads();
    if (t < 32) {
        float s = 0.f;
        for (int x = 0; x < 128; ++x) s += red_v[t * 128 + x];
        row_s[t] = s;
    }
    __syncthreads();

    float rcp[8];
    #pragma unroll
    for (int i = 0; i < 8; ++i) rcp[i] = 1.f / row_s[r0 + i];

    pc[t] = 0.f; pc[t + 512] = 0.f;
    __syncthreads();
    #pragma unroll
    for (int j = 0; j < 8; ++j) {
        const int c = (j < 4) ? (c0 + j) : (c1 + (j - 4));
        float s = 0.f;
        #pragma unroll
        for (int i = 0; i < 8; ++i) s += acc[i][j] * rcp[i];
        atomicAdd(&pc[c], s);
    }
    __syncthreads();
    atomicAdd(&A[t],       pc[t]);
    atomicAdd(&A[t + 512], pc[t + 512]);

    if (t == 0) {
        float s = 0.f;
        for (int r = 0; r < 32; ++r) s += row_dmin[r];
        wgpart[bid] = s;
    }
}

// ---- finalize scalars ----
__global__ void k_final(const float* __restrict__ wgpart, const float* __restrict__ A,
                        float* __restrict__ out) {
    __shared__ double sd[1024];
    const int t = threadIdx.x;
    sd[t] = (double)wgpart[t];
    __syncthreads();
    for (int off = 512; off > 0; off >>= 1) {
        if (t < off) sd[t] += sd[t + off];
        __syncthreads();
    }
    if (t == 0) out[VQ_OFF] = (float)(0.25 * sd[0] / 88473600.0);
    __syncthreads();
    const double p = (double)A[t] * (1.0 / 32768.0);
    sd[t] = -p * log(p + 1e-8);
    __syncthreads();
    for (int off = 512; off > 0; off >>= 1) {
        if (t < off) sd[t] += sd[t + off];
        __syncthreads();
    }
    if (t == 0) out[ENT_OFF] = (float)sd[0];
}

// ---- q_st = basis[indices] ----
__global__ void k_gather(const float* __restrict__ basis, const int* __restrict__ idxws,
                         float* __restrict__ out) {
    const int r = blockIdx.x;
    const int idx = idxws[r];
    const float4* src = (const float4*)(basis + (size_t)idx * ED);
    float4* dst = (float4*)(out + (size_t)r * ED);
    for (int j = threadIdx.x; j < ED / 4; j += 256) dst[j] = src[j];
}

// =====================================================================
// ===================== FALLBACK (round-2, f32 VALU) ==================
// =====================================================================

__global__ void k_bsq(const float* __restrict__ basis, float* __restrict__ bsq) {
    int c = blockIdx.x;
    const float* row = basis + (size_t)c * ED;
    double s = 0.0;
    for (int j = threadIdx.x; j < ED; j += 256) { float v = row[j]; s += (double)v * (double)v; }
    __shared__ double sd[256];
    sd[threadIdx.x] = s;
    __syncthreads();
    for (int off = 128; off > 0; off >>= 1) {
        if (threadIdx.x < off) sd[threadIdx.x] += sd[threadIdx.x + off];
        __syncthreads();
    }
    if (threadIdx.x == 0) bsq[c] = (float)sd[0];
}

__global__ __launch_bounds__(256, 4)
void k_gemm1(const float* __restrict__ S, const float* __restrict__ W,
             const float* __restrict__ bproj, float* __restrict__ Z) {
    const int e0 = blockIdx.x * 64;
    const int m0 = blockIdx.y * 64;
    const int t  = threadIdx.x;
    const int tx = t & 15, ty = t >> 4;
    __shared__ float alds[32 * 68];
    __shared__ float blds[32 * 68];
    float acc[4][4] = {};
    for (int k0 = 0; k0 < DM; k0 += 32) {
        #pragma unroll
        for (int rep = 0; rep < 2; ++rep) {
            const int id  = t + rep * 256;
            const int row = id >> 3, kq = id & 7;
            const float4 va = *(const float4*)(S + (size_t)(m0 + row) * DM + k0 + 4 * kq);
            alds[(4*kq+0)*68 + row] = va.x;
            alds[(4*kq+1)*68 + row] = va.y;
            alds[(4*kq+2)*68 + row] = va.z;
            alds[(4*kq+3)*68 + row] = va.w;
            float4 vb = make_float4(0.f, 0.f, 0.f, 0.f);
            if (e0 + row < ED)
                vb = *(const float4*)(W + (size_t)(e0 + row) * DM + k0 + 4 * kq);
            blds[(4*kq+0)*68 + row] = vb.x;
            blds[(4*kq+1)*68 + row] = vb.y;
            blds[(4*kq+2)*68 + row] = vb.z;
            blds[(4*kq+3)*68 + row] = vb.w;
        }
        __syncthreads();
        #pragma unroll 8
        for (int k = 0; k < 32; ++k) {
            const float4 a = *(const float4*)&alds[k*68 + 4*ty];
            const float4 b = *(const float4*)&blds[k*68 + 4*tx];
            const float av[4] = {a.x, a.y, a.z, a.w};
            const float bv[4] = {b.x, b.y, b.z, b.w};
            #pragma unroll
            for (int i = 0; i < 4; ++i)
                #pragma unroll
                for (int j = 0; j < 4; ++j)
                    acc[i][j] = fmaf(av[i], bv[j], acc[i][j]);
        }
        __syncthreads();
    }
    const bool valid = (e0 + 4*tx + 4) <= ED;
    float4 bias = make_float4(0.f, 0.f, 0.f, 0.f);
    if (valid) bias = *(const float4*)(bproj + e0 + 4*tx);
    #pragma unroll
    for (int i = 0; i < 4; ++i) {
        if (valid) {
            float4 o;
            o.x = acc[i][0] + bias.x;
            o.y = acc[i][1] + bias.y;
            o.z = acc[i][2] + bias.z;
            o.w = acc[i][3] + bias.w;
            *(float4*)(Z + (size_t)(m0 + 4*ty + i) * ED + e0 + 4*tx) = o;
        }
    }
}

__global__ __launch_bounds__(64)
void k_zsq(const float* __restrict__ Z, float* __restrict__ zsq) {
    const int r = blockIdx.x;
    const float4* row4 = (const float4*)(Z + (size_t)r * ED);
    double s = 0.0;
    for (int q = threadIdx.x; q < ED / 4; q += 64) {
        const float4 v = row4[q];
        s += (double)v.x * v.x + (double)v.y * v.y + (double)v.z * v.z + (double)v.w * v.w;
    }
    #pragma unroll
    for (int off = 32; off > 0; off >>= 1) s += __shfl_down(s, off);
    if (threadIdx.x == 0) zsq[r] = (float)s;
}

__global__ __launch_bounds__(512, 2)
void k_dist(const float* __restrict__ Z, const float* __restrict__ basis,
            const float* __restrict__ bsq, const float* __restrict__ zsq,
            float* __restrict__ A, float* __restrict__ wgpart,
            int* __restrict__ idxws, float* __restrict__ out) {
    const int bid = blockIdx.x;
    const int wr0 = bid * 32;
    const int t   = threadIdx.x;
    const int cg  = t & 127;
    const int rq  = t >> 7;
    const int r0  = rq * 8;
    const int c0  = cg * 4;
    const int c1  = 512 + cg * 4;
    __shared__ float blds[16 * 1024];
    __shared__ float zlds[16 * 36];
    float acc[8][8];
    #pragma unroll
    for (int i = 0; i < 8; ++i)
        #pragma unroll
        for (int j = 0; j < 8; ++j) acc[i][j] = 0.f;
    for (int k0 = 0; k0 < ED; k0 += 16) {
        const bool full = (k0 + 16) <= ED;
        #pragma unroll
        for (int rep = 0; rep < 2; ++rep) {
            const int c = t + rep * 512;
            const float* bp = basis + (size_t)c * ED + k0;
            if (full) {
                const float4 v0 = *(const float4*)(bp + 0);
                const float4 v1 = *(const float4*)(bp + 4);
                const float4 v2 = *(const float4*)(bp + 8);
                const float4 v3 = *(const float4*)(bp + 12);
                blds[ 0*1024+c]=v0.x; blds[ 1*1024+c]=v0.y; blds[ 2*1024+c]=v0.z; blds[ 3*1024+c]=v0.w;
                blds[ 4*1024+c]=v1.x; blds[ 5*1024+c]=v1.y; blds[ 6*1024+c]=v1.z; blds[ 7*1024+c]=v1.w;
                blds[ 8*1024+c]=v2.x; blds[ 9*1024+c]=v2.y; blds[10*1024+c]=v2.z; blds[11*1024+c]=v2.w;
                blds[12*1024+c]=v3.x; blds[13*1024+c]=v3.y; blds[14*1024+c]=v3.z; blds[15*1024+c]=v3.w;
            } else {
                for (int kk = 0; kk < 16; ++kk)
                    blds[kk*1024 + c] = (k0 + kk < ED) ? bp[kk] : 0.f;
            }
        }
        if (t < 128) {
            const int row = t >> 2, kq = t & 3;
            const float* zp = Z + (size_t)(wr0 + row) * ED + k0 + 4 * kq;
            if (full) {
                const float4 v = *(const float4*)zp;
                zlds[(4*kq+0)*36 + row] = v.x;
                zlds[(4*kq+1)*36 + row] = v.y;
                zlds[(4*kq+2)*36 + row] = v.z;
                zlds[(4*kq+3)*36 + row] = v.w;
            } else {
                for (int j = 0; j < 4; ++j) {
                    const int k = k0 + 4*kq + j;
                    zlds[(4*kq+j)*36 + row] = (k < ED) ? zp[j] : 0.f;
                }
            }
        }
        __syncthreads();
        #pragma unroll
        for (int k = 0; k < 16; ++k) {
            const float4 z0 = *(const float4*)&zlds[k*36 + r0];
            const float4 z1 = *(const float4*)&zlds[k*36 + r0 + 4];
            const float4 b0 = *(const float4*)&blds[k*1024 + c0];
            const float4 b1 = *(const float4*)&blds[k*1024 + c1];
            const float zz[8] = {z0.x, z0.y, z0.z, z0.w, z1.x, z1.y, z1.z, z1.w};
            const float bb[8] = {b0.x, b0.y, b0.z, b0.w, b1.x, b1.y, b1.z, b1.w};
            #pragma unroll
            for (int i = 0; i < 8; ++i)
                #pragma unroll
                for (int j = 0; j < 8; ++j)
                    acc[i][j] = fmaf(zz[i], bb[j], acc[i][j]);
        }
        __syncthreads();
    }
    float* red_v    = blds;
    int*   red_i    = (int*)(blds + 4096);
    float* row_dmin = blds + 8192;
    float* row_s    = blds + 8224;
    float* pc       = blds + 8256;
    float bsqv[8], zsqv[8];
    #pragma unroll
    for (int j = 0; j < 4; ++j) { bsqv[j] = bsq[c0 + j]; bsqv[4 + j] = bsq[c1 + j]; }
    #pragma unroll
    for (int i = 0; i < 8; ++i) zsqv[i] = zsq[wr0 + r0 + i];
    #pragma unroll
    for (int i = 0; i < 8; ++i)
        #pragma unroll
        for (int j = 0; j < 8; ++j) {
            const float tv = zsqv[i] - 2.f * acc[i][j];
            acc[i][j] = tv + bsqv[j];
        }
    #pragma unroll
    for (int i = 0; i < 8; ++i) {
        float bv = acc[i][0]; int bi = c0;
        #pragma unroll
        for (int j = 1; j < 8; ++j) {
            const int c = (j < 4) ? (c0 + j) : (c1 + (j - 4));
            if (acc[i][j] < bv || (acc[i][j] == bv && c < bi)) { bv = acc[i][j]; bi = c; }
        }
        red_v[(r0 + i) * 128 + cg] = bv;
        red_i[(r0 + i) * 128 + cg] = bi;
    }
    __syncthreads();
    if (t < 32) {
        float bv = red_v[t * 128]; int bi = red_i[t * 128];
        for (int x = 1; x < 128; ++x) {
            const float v = red_v[t * 128 + x];
            const int  iv = red_i[t * 128 + x];
            if (v < bv || (v == bv && iv < bi)) { bv = v; bi = iv; }
        }
        row_dmin[t] = bv;
        idxws[wr0 + t] = bi;
        out[IDX_OFF + wr0 + t] = (float)bi;
    }
    __syncthreads();
    float su[8];
    #pragma unroll
    for (int i = 0; i < 8; ++i) {
        const float dm = row_dmin[r0 + i];
        float s = 0.f;
        #pragma unroll
        for (int j = 0; j < 8; ++j) {
            const float u = expf(dm - acc[i][j]);
            acc[i][j] = u;
            s += u;
        }
        su[i] = s;
    }
    #pragma unroll
    for (int i = 0; i < 8; ++i) red_v[(r0 + i) * 128 + cg] = su[i];
    __syncthreads();
    if (t < 32) {
        float s = 0.f;
        for (int x = 0; x < 128; ++x) s += red_v[t * 128 + x];
        row_s[t] = s;
    }
    __syncthreads();
    float rcp[8];
    #pragma unroll
    for (int i = 0; i < 8; ++i) rcp[i] = 1.f / row_s[r0 + i];
    pc[t] = 0.f; pc[t + 512] = 0.f;
    __syncthreads();
    #pragma unroll
    for (int j = 0; j < 8; ++j) {
        const int c = (j < 4) ? (c0 + j) : (c1 + (j - 4));
        float s = 0.f;
        #pragma unroll
        for (int i = 0; i < 8; ++i) s += acc[i][j] * rcp[i];
        atomicAdd(&pc[c], s);
    }
    __syncthreads();
    atomicAdd(&A[t],       pc[t]);
    atomicAdd(&A[t + 512], pc[t + 512]);
    if (t == 0) {
        float s = 0.f;
        for (int r = 0; r < 32; ++r) s += row_dmin[r];
        wgpart[bid] = s;
    }
}

// =====================================================================

extern "C" void kernel_launch(void* const* d_in, const int* in_sizes, int n_in,
                              void* d_out, int out_size, void* d_ws, size_t ws_size,
                              hipStream_t stream) {
    const float* S     = (const float*)d_in[0];  // [32768, 256]
    const float* W     = (const float*)d_in[1];  // [2700, 256]
    const float* bproj = (const float*)d_in[2];  // [2700]
    const float* basis = (const float*)d_in[3];  // [1024, 2700]
    float* out = (float*)d_out;
    float* ws  = (float*)d_ws;

    // common small regions
    float* zsq    = ws;                  // 32768
    float* A      = ws + 32768;          // 1024
    float* bsq    = ws + 33792;          // 1024
    float* wgpart = ws + 34816;          // 1024
    int*   idxws  = (int*)(ws + 35840);  // 32768

    // ws floats: 68608 small + Ph/Pm 262144 + transients 5316992 = 5,647,744 (~22.6 MB)
    const size_t NEED = (size_t)5647744 * sizeof(float);
    if (ws_size >= NEED) {
        // -------- MFMA path (reassociated: G = S.(basis.W)^T, fused dist) --------
        unsigned short* Ph = (unsigned short*)(ws + 68608);            // 1024*256 ush
        unsigned short* Pm = (unsigned short*)(ws + 68608 + 131072);
        float* basisP  = ws + 330752;        // 1024*2720 = 2785280
        float* WT      = ws + 3116032;       // 256*2720  = 696320
        float* uv      = ws + 3812352;       // 257 (u[256], v)
        float* Pp      = ws + 3812736;       // 5*262144 = 1310720
        float* Mp      = ws + 5123456;       // 5*65536  = 327680
        float* Mm      = ws + 5451136;       // 65536
        float* zsqpart = ws + 5516672;       // 4*32768  = 131072 -> ends 5647744
        // S planes live in q_st output region (dead before k_gather writes q_st)
        unsigned short* Sh = (unsigned short*)out;                     // 32768*256 ush
        unsigned short* Sm = Sh + (size_t)BKROWS * DM;

        hipMemsetAsync(A, 0, (size_t)NC * sizeof(float), stream);
        k_packS <<<BKROWS * DM / 1024, 256, 0, stream>>>(S, Sh, Sm);
        k_bsq2  <<<NC, 256, 0, stream>>>(basis, bproj, bsq);
        k_padB  <<<NC, 256, 0, stream>>>(basis, basisP);
        k_padWT <<<dim3(43, 4), 256, 0, stream>>>(W, WT);
        k_uv2   <<<257, 256, 0, stream>>>(WT, bproj, uv);
        k_gsplit<<<dim3(4, 16, 5), 256, 0, stream>>>(basisP, WT, Pp, 256);  // P partials
        k_gsplit<<<dim3(4, 4, 5),  256, 0, stream>>>(WT, WT, Mp, 256);      // M partials
        k_redP  <<<1024, 256, 0, stream>>>(Pp, Ph, Pm);
        k_redM  <<<256, 256, 0, stream>>>(Mp, Mm);
        k_zsqS  <<<dim3(NTZ, 512), 256, 0, stream>>>(S, Mm, uv, zsqpart);
        k_zsqred<<<BKROWS / 256, 256, 0, stream>>>(zsqpart, zsq);
        k_fdist2<<<BKROWS / 32, 512, 0, stream>>>(Sh, Sm, Ph, Pm, bsq, zsq, A, wgpart, idxws, out);
        k_final <<<1, 1024, 0, stream>>>(wgpart, A, out);
        k_gather<<<BKROWS, 256, 0, stream>>>(basis, idxws, out);
    } else {
        // -------- fallback: round-2 f32 path --------
        float* Z = out;
        hipMemsetAsync(A, 0, (size_t)NC * sizeof(float), stream);
        k_bsq   <<<NC, 256, 0, stream>>>(basis, bsq);
        k_gemm1 <<<dim3(43, 512), 256, 0, stream>>>(S, W, bproj, Z);
        k_zsq   <<<BKROWS, 64, 0, stream>>>(Z, zsq);
        k_dist  <<<BKROWS / 32, 512, 0, stream>>>(Z, basis, bsq, zsq, A, wgpart, idxws, out);
        k_final <<<1, 1024, 0, stream>>>(wgpart, A, out);
        k_gather<<<BKROWS, 256, 0, stream>>>(basis, idxws, out);
    }
}

// Round 12
// 479.481 us; speedup vs baseline: 1.0894x; 1.0830x over previous
//
#include <hip/hip_runtime.h>
#include <math.h>

#define ED 2700     // basis_dim
#define NC 1024     // num_codes
#define DM 256      // d_model
#define BKROWS 32768

#define IDX_OFF 88473600
#define VQ_OFF  88506368
#define ENT_OFF 88506369

#define KPAD 2720     // padded K for P/M small GEMMs (5 x 544)
#define NTZ 4         // zsq n-tile partials
#define GSTR 1028     // gtile row stride (floats): 2-way-bank-free, 16B-aligned

typedef float  f32x4  __attribute__((ext_vector_type(4)));
typedef short  bf16x8 __attribute__((ext_vector_type(8)));

__device__ inline unsigned short f2bf(float x) {
    unsigned int u = __float_as_uint(x);
    unsigned int r = (u + 0x7FFFu + ((u >> 16) & 1u)) >> 16;
    return (unsigned short)r;
}
__device__ inline float bf2f(unsigned short h) {
    return __uint_as_float(((unsigned int)h) << 16);
}

// =====================================================================
// ============================ MFMA PATH ==============================
// =====================================================================

// ---- S -> Sh/Sm bf16 planes ----
__global__ __launch_bounds__(256)
void k_packS(const float* __restrict__ S, unsigned short* __restrict__ Sh,
             unsigned short* __restrict__ Sm) {
    const size_t i4 = (size_t)blockIdx.x * 256 + threadIdx.x;
    const float4 v = *(const float4*)(S + i4 * 4);
    ushort4 hv, mv;
    unsigned short* hp = (unsigned short*)&hv;
    unsigned short* mp = (unsigned short*)&mv;
    const float xs[4] = {v.x, v.y, v.z, v.w};
    #pragma unroll
    for (int j = 0; j < 4; ++j) {
        const unsigned short h = f2bf(xs[j]);
        hp[j] = h;
        mp[j] = f2bf(xs[j] - bf2f(h));
    }
    *(ushort4*)(Sh + i4 * 4) = hv;
    *(ushort4*)(Sm + i4 * 4) = mv;
}

// ---- bsq'[c] = sum basis^2 - 2*basis.bproj (f64) ----
__global__ void k_bsq2(const float* __restrict__ basis, const float* __restrict__ bproj,
                       float* __restrict__ bsq) {
    const int c = blockIdx.x;
    const int t = threadIdx.x;
    const float* row = basis + (size_t)c * ED;
    double s2 = 0.0, sp = 0.0;
    for (int j = t; j < ED; j += 256) {
        const float x = row[j];
        s2 += (double)x * (double)x;
        sp += (double)x * (double)bproj[j];
    }
    __shared__ double sd[512];
    sd[t] = s2; sd[256 + t] = sp;
    __syncthreads();
    for (int off = 128; off > 0; off >>= 1) {
        if (t < off) { sd[t] += sd[t + off]; sd[256 + t] += sd[256 + t + off]; }
        __syncthreads();
    }
    if (t == 0) bsq[c] = (float)(sd[0] - 2.0 * sd[256]);
}

// ---- basisP = basis zero-padded to [1024][2720] ----
__global__ __launch_bounds__(256)
void k_padB(const float* __restrict__ basis, float* __restrict__ bP) {
    const int c = blockIdx.x;
    const float4* src = (const float4*)(basis + (size_t)c * ED);
    float4* dst = (float4*)(bP + (size_t)c * KPAD);
    for (int q = threadIdx.x; q < KPAD / 4; q += 256)
        dst[q] = (q < ED / 4) ? src[q] : make_float4(0.f, 0.f, 0.f, 0.f);
}

// ---- WT = W^T zero-padded to [256][2720] ----
__global__ __launch_bounds__(256)
void k_padWT(const float* __restrict__ W, float* __restrict__ WT) {
    const int e0 = blockIdx.x * 64;
    const int d0 = blockIdx.y * 64;
    __shared__ float tbuf[64][65];
    const int t  = threadIdx.x;
    const int r  = t >> 2;
    const int q4 = t & 3;
    #pragma unroll
    for (int j = 0; j < 4; ++j) {
        const int col = q4 * 16 + j * 4;
        const int e = e0 + r;
        float4 v = make_float4(0.f, 0.f, 0.f, 0.f);
        if (e < ED) v = *(const float4*)(W + (size_t)e * DM + d0 + col);
        tbuf[r][col + 0] = v.x; tbuf[r][col + 1] = v.y;
        tbuf[r][col + 2] = v.z; tbuf[r][col + 3] = v.w;
    }
    __syncthreads();
    #pragma unroll
    for (int j = 0; j < 4; ++j) {
        const int col = q4 * 16 + j * 4;
        if (e0 + col < KPAD) {
            float4 o;
            o.x = tbuf[col + 0][r]; o.y = tbuf[col + 1][r];
            o.z = tbuf[col + 2][r]; o.w = tbuf[col + 3][r];
            *(float4*)(WT + (size_t)(d0 + r) * KPAD + e0 + col) = o;
        }
    }
}

// ---- k_uv2: u[d] = WT[d].bproj (blocks 0..255); v = ||bproj||^2 (block 256) ----
__global__ __launch_bounds__(256)
void k_uv2(const float* __restrict__ WT, const float* __restrict__ bproj,
           float* __restrict__ uv) {
    const int b = blockIdx.x;
    const int t = threadIdx.x;
    double s = 0.0;
    if (b < 256) {
        const float* row = WT + (size_t)b * KPAD;
        for (int j = t; j < ED; j += 256) s += (double)row[j] * (double)bproj[j];
    } else {
        for (int j = t; j < ED; j += 256) { const double x = bproj[j]; s += x * x; }
    }
    __shared__ double sd[256];
    sd[t] = s;
    __syncthreads();
    for (int off = 128; off > 0; off >>= 1) {
        if (t < off) sd[t] += sd[t + off];
        __syncthreads();
    }
    if (t == 0) uv[b] = (float)sd[0];
}

// ---- generic 64x64-tile f32 GEMM partial over K-slab of 544 ----
__global__ __launch_bounds__(256)
void k_gsplit(const float* __restrict__ A, const float* __restrict__ B,
              float* __restrict__ Cp, int nld) {
    const int n0  = blockIdx.x * 64;
    const int m0  = blockIdx.y * 64;
    const int k00 = blockIdx.z * 544;
    float* Cout = Cp + (size_t)blockIdx.z * (size_t)gridDim.y * 64 * nld;
    const int t  = threadIdx.x;
    const int tx = t & 15, ty = t >> 4;

    __shared__ float alds[32 * 68];
    __shared__ float blds[32 * 68];

    float acc[4][4] = {};

    for (int k0 = k00; k0 < k00 + 544; k0 += 32) {
        #pragma unroll
        for (int rep = 0; rep < 2; ++rep) {
            const int id  = t + rep * 256;
            const int row = id >> 3, kq = id & 7;
            const float4 va = *(const float4*)(A + (size_t)(m0 + row) * KPAD + k0 + 4 * kq);
            alds[(4*kq+0)*68 + row] = va.x;
            alds[(4*kq+1)*68 + row] = va.y;
            alds[(4*kq+2)*68 + row] = va.z;
            alds[(4*kq+3)*68 + row] = va.w;
            const float4 vb = *(const float4*)(B + (size_t)(n0 + row) * KPAD + k0 + 4 * kq);
            blds[(4*kq+0)*68 + row] = vb.x;
            blds[(4*kq+1)*68 + row] = vb.y;
            blds[(4*kq+2)*68 + row] = vb.z;
            blds[(4*kq+3)*68 + row] = vb.w;
        }
        __syncthreads();
        #pragma unroll 8
        for (int k = 0; k < 32; ++k) {
            const float4 a = *(const float4*)&alds[k*68 + 4*ty];
            const float4 b = *(const float4*)&blds[k*68 + 4*tx];
            const float av[4] = {a.x, a.y, a.z, a.w};
            const float bv[4] = {b.x, b.y, b.z, b.w};
            #pragma unroll
            for (int i = 0; i < 4; ++i)
                #pragma unroll
                for (int j = 0; j < 4; ++j)
                    acc[i][j] = fmaf(av[i], bv[j], acc[i][j]);
        }
        __syncthreads();
    }
    #pragma unroll
    for (int i = 0; i < 4; ++i) {
        float4 o; o.x = acc[i][0]; o.y = acc[i][1]; o.z = acc[i][2]; o.w = acc[i][3];
        *(float4*)(Cout + (size_t)(m0 + 4*ty + i) * nld + n0 + 4*tx) = o;
    }
}

// ---- reduce 5 P-partials -> Ph/Pm planes ----
__global__ __launch_bounds__(256)
void k_redP(const float* __restrict__ Pp, unsigned short* __restrict__ Ph,
            unsigned short* __restrict__ Pm) {
    const size_t idx = (size_t)blockIdx.x * 256 + threadIdx.x;
    float s = 0.f;
    #pragma unroll
    for (int k = 0; k < 5; ++k) s += Pp[(size_t)k * 262144 + idx];
    const unsigned short h = f2bf(s);
    Ph[idx] = h;
    Pm[idx] = f2bf(s - bf2f(h));
}

// ---- reduce 5 M-partials -> M f32 ----
__global__ __launch_bounds__(256)
void k_redM(const float* __restrict__ Mp, float* __restrict__ M) {
    const size_t idx = (size_t)blockIdx.x * 256 + threadIdx.x;
    float s = 0.f;
    #pragma unroll
    for (int k = 0; k < 5; ++k) s += Mp[(size_t)k * 65536 + idx];
    M[idx] = s;
}

// ---- zsq partials: zsq_r = S_r M S_r^T + 2 S_r.u + v ----
__global__ __launch_bounds__(256)
void k_zsqS(const float* __restrict__ S, const float* __restrict__ M,
            const float* __restrict__ uv, float* __restrict__ zsqpart) {
    const int e0 = blockIdx.x * 64;
    const int m0 = blockIdx.y * 64;
    const int t  = threadIdx.x;
    const int tx = t & 15, ty = t >> 4;

    __shared__ float alds[32 * 68];
    __shared__ float blds[32 * 68];

    float acc[4][4] = {};

    for (int k0 = 0; k0 < DM; k0 += 32) {
        #pragma unroll
        for (int rep = 0; rep < 2; ++rep) {
            const int id  = t + rep * 256;
            const int row = id >> 3, kq = id & 7;
            const float4 va = *(const float4*)(S + (size_t)(m0 + row) * DM + k0 + 4 * kq);
            alds[(4*kq+0)*68 + row] = va.x;
            alds[(4*kq+1)*68 + row] = va.y;
            alds[(4*kq+2)*68 + row] = va.z;
            alds[(4*kq+3)*68 + row] = va.w;
            const float4 vb = *(const float4*)(M + (size_t)(e0 + row) * DM + k0 + 4 * kq);
            blds[(4*kq+0)*68 + row] = vb.x;
            blds[(4*kq+1)*68 + row] = vb.y;
            blds[(4*kq+2)*68 + row] = vb.z;
            blds[(4*kq+3)*68 + row] = vb.w;
        }
        __syncthreads();
        #pragma unroll 8
        for (int k = 0; k < 32; ++k) {
            const float4 a = *(const float4*)&alds[k*68 + 4*ty];
            const float4 b = *(const float4*)&blds[k*68 + 4*tx];
            const float av[4] = {a.x, a.y, a.z, a.w};
            const float bv[4] = {b.x, b.y, b.z, b.w};
            #pragma unroll
            for (int i = 0; i < 4; ++i)
                #pragma unroll
                for (int j = 0; j < 4; ++j)
                    acc[i][j] = fmaf(av[i], bv[j], acc[i][j]);
        }
        __syncthreads();
    }

    const int col0 = e0 + 4 * tx;
    const float4 uu = *(const float4*)(uv + col0);
    const float vq4 = uv[256] * 0.25f;
    float psum[4];
    #pragma unroll
    for (int i = 0; i < 4; ++i) {
        const int row = m0 + 4 * ty + i;
        const float4 sv = *(const float4*)(S + (size_t)row * DM + col0);
        psum[i] = (acc[i][0] + 2.f * uu.x) * sv.x
                + (acc[i][1] + 2.f * uu.y) * sv.y
                + (acc[i][2] + 2.f * uu.z) * sv.z
                + (acc[i][3] + 2.f * uu.w) * sv.w + vq4;
    }
    float* red = alds;
    #pragma unroll
    for (int i = 0; i < 4; ++i) red[(4*ty + i) * 16 + tx] = psum[i];
    __syncthreads();
    if (t < 64) {
        float s = 0.f;
        #pragma unroll
        for (int x = 0; x < 16; ++x) s += red[t * 16 + x];
        zsqpart[(size_t)blockIdx.x * BKROWS + m0 + t] = s;
    }
}

// ---- zsq[r] = sum over NTZ partials (f64, deterministic) ----
__global__ void k_zsqred(const float* __restrict__ part, float* __restrict__ zsq) {
    const int r = blockIdx.x * 256 + threadIdx.x;
    double s = 0.0;
    #pragma unroll
    for (int b = 0; b < NTZ; ++b) s += (double)part[(size_t)b * BKROWS + r];
    zsq[r] = (float)s;
}

// ---- k_fdist3: fused dist GEMM with global_load_lds-staged B chunks (k_gemm2's
//      proven staging/swizzle), S frags from global, + proven gtile epilogue.
//      Block = 32 rows x all 1024 codes; LDS buffer shared by B-stage and gtile.
__global__ __launch_bounds__(512, 2)
void k_fdist3(const unsigned short* __restrict__ Sh, const unsigned short* __restrict__ Sm,
              const unsigned short* __restrict__ Ph, const unsigned short* __restrict__ Pm,
              const float* __restrict__ bsq, const float* __restrict__ zsq,
              float* __restrict__ A, float* __restrict__ wgpart,
              int* __restrict__ idxws, float* __restrict__ out) {
    __shared__ float shbuf[32 * GSTR];   // 131584 B: B-stage (131072 B) then gtile

    const int bid  = blockIdx.x;
    const int wr0  = bid * 32;
    const int t    = threadIdx.x;
    const int w    = t >> 6, l = t & 63;
    const int lrow = l & 15;
    const int lu   = l >> 4;
    const int wc0  = w * 128;            // wave's 128-code slice

    unsigned short* Bst = (unsigned short*)shbuf;

    // staging descriptors (k_gemm2 pattern, 1024 rows): 16 slots/thread
    const unsigned short* gsrc[16];
    int ldsoff[16];
    #pragma unroll
    for (int i = 0; i < 16; ++i) {
        const int slot = i * 512 + t;
        const int row  = slot >> 3;
        const int unit = slot & 7;
        const int sg   = unit ^ (row & 7);
        const int pl   = sg >> 2;
        const int koff = (sg & 3) * 8;
        gsrc[i]   = (pl ? Pm : Ph) + (size_t)row * DM + koff;
        ldsoff[i] = slot * 8;            // ushort index = 16B per slot
    }

    #define STAGE3(ck) { \
        _Pragma("unroll") \
        for (int i = 0; i < 16; ++i) \
            __builtin_amdgcn_global_load_lds( \
                (const __attribute__((address_space(1))) unsigned int*)(const void*)(gsrc[i] + (ck) * 32), \
                (__attribute__((address_space(3))) unsigned int*)(void*)&Bst[ldsoff[i]], \
                16, 0, 0); \
    }

    f32x4 acc2[2][8];
    #pragma unroll
    for (int rf = 0; rf < 2; ++rf)
        #pragma unroll
        for (int f = 0; f < 8; ++f) acc2[rf][f] = (f32x4){0.f, 0.f, 0.f, 0.f};

    STAGE3(0)
    __syncthreads();

    #pragma unroll
    for (int c = 0; c < 8; ++c) {
        // S fragments for this chunk (global, L2-hot; overlap with LDS reads)
        bf16x8 ah[2], am[2];
        #pragma unroll
        for (int rf = 0; rf < 2; ++rf) {
            const size_t off = (size_t)(wr0 + rf * 16 + lrow) * DM + c * 32 + lu * 8;
            ah[rf] = *(const bf16x8*)(Sh + off);
            am[rf] = *(const bf16x8*)(Sm + off);
        }
        // B fragments from LDS (k_gemm2's verified swizzled read)
        bf16x8 bh[8], bm[8];
        #pragma unroll
        for (int f = 0; f < 8; ++f) {
            const int col = wc0 + f * 16 + lrow;
            bh[f] = *(const bf16x8*)(Bst + col * 64 + (((0 + lu) ^ (col & 7))) * 8);
            bm[f] = *(const bf16x8*)(Bst + col * 64 + (((4 + lu) ^ (col & 7))) * 8);
        }
        __syncthreads();                 // all lanes done reading chunk c
        if (c < 7) STAGE3(c + 1)         // overwrite; loads fly under MFMAs
        #pragma unroll
        for (int f = 0; f < 8; ++f)
            #pragma unroll
            for (int rf = 0; rf < 2; ++rf) {
                f32x4 cc = acc2[rf][f];
                cc = __builtin_amdgcn_mfma_f32_16x16x32_bf16(ah[rf], bh[f], cc, 0, 0, 0);
                cc = __builtin_amdgcn_mfma_f32_16x16x32_bf16(ah[rf], bm[f], cc, 0, 0, 0);
                cc = __builtin_amdgcn_mfma_f32_16x16x32_bf16(am[rf], bh[f], cc, 0, 0, 0);
                acc2[rf][f] = cc;
            }
        if (c < 7) __syncthreads();      // drains vmcnt: chunk c+1 staged
    }
    #undef STAGE3

    // ---- store G-tile to LDS with the verified C-layout mapping ----
    // (safe: last LDS reads completed at the post-LOAD barrier of chunk 7)
    float* gtile = shbuf;
    #pragma unroll
    for (int rf = 0; rf < 2; ++rf)
        #pragma unroll
        for (int f = 0; f < 8; ++f) {
            const int col = wc0 + f * 16 + lrow;
            #pragma unroll
            for (int r = 0; r < 4; ++r) {
                const int row = rf * 16 + lu * 4 + r;
                gtile[row * GSTR + col] = acc2[rf][f][r];
            }
        }
    __syncthreads();

    // ==== phase 2: k_post epilogue VERBATIM (proven round 10) ====
    const int cg = t & 127;
    const int rq = t >> 7;
    const int r0 = rq * 8;
    const int c0 = cg * 4;
    const int c1 = 512 + cg * 4;

    float acc[8][8];
    #pragma unroll
    for (int i = 0; i < 8; ++i) {
        const float4 g0 = *(const float4*)&gtile[(r0 + i) * GSTR + c0];
        const float4 g1 = *(const float4*)&gtile[(r0 + i) * GSTR + c1];
        acc[i][0] = g0.x; acc[i][1] = g0.y; acc[i][2] = g0.z; acc[i][3] = g0.w;
        acc[i][4] = g1.x; acc[i][5] = g1.y; acc[i][6] = g1.z; acc[i][7] = g1.w;
    }
    __syncthreads();   // all reads done before overlaying red arrays

    float* red_v    = gtile;                 // [32][128]
    int*   red_i    = (int*)(gtile + 4096);  // [32][128]
    float* row_dmin = gtile + 8192;          // [32]
    float* row_s    = gtile + 8224;          // [32]
    float* pc       = gtile + 8256;          // [1024]

    float bsqv[8], zsqv[8];
    #pragma unroll
    for (int j = 0; j < 4; ++j) { bsqv[j] = bsq[c0 + j]; bsqv[4 + j] = bsq[c1 + j]; }
    #pragma unroll
    for (int i = 0; i < 8; ++i) zsqv[i] = zsq[wr0 + r0 + i];

    #pragma unroll
    for (int i = 0; i < 8; ++i)
        #pragma unroll
        for (int j = 0; j < 8; ++j) {
            const float tv = zsqv[i] - 2.f * acc[i][j];
            acc[i][j] = tv + bsqv[j];
        }

    #pragma unroll
    for (int i = 0; i < 8; ++i) {
        float bv = acc[i][0]; int bi = c0;
        #pragma unroll
        for (int j = 1; j < 8; ++j) {
            const int c = (j < 4) ? (c0 + j) : (c1 + (j - 4));
            if (acc[i][j] < bv || (acc[i][j] == bv && c < bi)) { bv = acc[i][j]; bi = c; }
        }
        red_v[(r0 + i) * 128 + cg] = bv;
        red_i[(r0 + i) * 128 + cg] = bi;
    }
    __syncthreads();
    if (t < 32) {
        float bv = red_v[t * 128]; int bi = red_i[t * 128];
        for (int x = 1; x < 128; ++x) {
            const float v = red_v[t * 128 + x];
            const int  iv = red_i[t * 128 + x];
            if (v < bv || (v == bv && iv < bi)) { bv = v; bi = iv; }
        }
        row_dmin[t] = bv;
        idxws[wr0 + t] = bi;
        out[IDX_OFF + wr0 + t] = (float)bi;
    }
    __syncthreads();

    float su[8];
    #pragma unroll
    for (int i = 0; i < 8; ++i) {
        const float dm = row_dmin[r0 + i];
        float s = 0.f;
        #pragma unroll
        for (int j = 0; j < 8; ++j) {
            const float u = expf(dm - acc[i][j]);
            acc[i][j] = u;
            s += u;
        }
        su[i] = s;
    }
    #pragma unroll
    for (int i = 0; i < 8; ++i) red_v[(r0 + i) * 128 + cg] = su[i];
    __syncthreads();
    if (t < 32) {
        float s = 0.f;
        for (int x = 0; x < 128; ++x) s += red_v[t * 128 + x];
        row_s[t] = s;
    }
    __syncthreads();

    float rcp[8];
    #pragma unroll
    for (int i = 0; i < 8; ++i) rcp[i] = 1.f / row_s[r0 + i];

    pc[t] = 0.f; pc[t + 512] = 0.f;
    __syncthreads();
    #pragma unroll
    for (int j = 0; j < 8; ++j) {
        const int c = (j < 4) ? (c0 + j) : (c1 + (j - 4));
        float s = 0.f;
        #pragma unroll
        for (int i = 0; i < 8; ++i) s += acc[i][j] * rcp[i];
        atomicAdd(&pc[c], s);
    }
    __syncthreads();
    atomicAdd(&A[t],       pc[t]);
    atomicAdd(&A[t + 512], pc[t + 512]);

    if (t == 0) {
        float s = 0.f;
        for (int r = 0; r < 32; ++r) s += row_dmin[r];
        wgpart[bid] = s;
    }
}

// ---- finalize scalars ----
__global__ void k_final(const float* __restrict__ wgpart, const float* __restrict__ A,
                        float* __restrict__ out) {
    __shared__ double sd[1024];
    const int t = threadIdx.x;
    sd[t] = (double)wgpart[t];
    __syncthreads();
    for (int off = 512; off > 0; off >>= 1) {
        if (t < off) sd[t] += sd[t + off];
        __syncthreads();
    }
    if (t == 0) out[VQ_OFF] = (float)(0.25 * sd[0] / 88473600.0);
    __syncthreads();
    const double p = (double)A[t] * (1.0 / 32768.0);
    sd[t] = -p * log(p + 1e-8);
    __syncthreads();
    for (int off = 512; off > 0; off >>= 1) {
        if (t < off) sd[t] += sd[t + off];
        __syncthreads();
    }
    if (t == 0) out[ENT_OFF] = (float)sd[0];
}

// ---- q_st = basis[indices] ----
__global__ void k_gather(const float* __restrict__ basis, const int* __restrict__ idxws,
                         float* __restrict__ out) {
    const int r = blockIdx.x;
    const int idx = idxws[r];
    const float4* src = (const float4*)(basis + (size_t)idx * ED);
    float4* dst = (float4*)(out + (size_t)r * ED);
    for (int j = threadIdx.x; j < ED / 4; j += 256) dst[j] = src[j];
}

// =====================================================================
// ===================== FALLBACK (round-2, f32 VALU) ==================
// =====================================================================

__global__ void k_bsq(const float* __restrict__ basis, float* __restrict__ bsq) {
    int c = blockIdx.x;
    const float* row = basis + (size_t)c * ED;
    double s = 0.0;
    for (int j = threadIdx.x; j < ED; j += 256) { float v = row[j]; s += (double)v * (double)v; }
    __shared__ double sd[256];
    sd[threadIdx.x] = s;
    __syncthreads();
    for (int off = 128; off > 0; off >>= 1) {
        if (threadIdx.x < off) sd[threadIdx.x] += sd[threadIdx.x + off];
        __syncthreads();
    }
    if (threadIdx.x == 0) bsq[c] = (float)sd[0];
}

__global__ __launch_bounds__(256, 4)
void k_gemm1(const float* __restrict__ S, const float* __restrict__ W,
             const float* __restrict__ bproj, float* __restrict__ Z) {
    const int e0 = blockIdx.x * 64;
    const int m0 = blockIdx.y * 64;
    const int t  = threadIdx.x;
    const int tx = t & 15, ty = t >> 4;
    __shared__ float alds[32 * 68];
    __shared__ float blds[32 * 68];
    float acc[4][4] = {};
    for (int k0 = 0; k0 < DM; k0 += 32) {
        #pragma unroll
        for (int rep = 0; rep < 2; ++rep) {
            const int id  = t + rep * 256;
            const int row = id >> 3, kq = id & 7;
            const float4 va = *(const float4*)(S + (size_t)(m0 + row) * DM + k0 + 4 * kq);
            alds[(4*kq+0)*68 + row] = va.x;
            alds[(4*kq+1)*68 + row] = va.y;
            alds[(4*kq+2)*68 + row] = va.z;
            alds[(4*kq+3)*68 + row] = va.w;
            float4 vb = make_float4(0.f, 0.f, 0.f, 0.f);
            if (e0 + row < ED)
                vb = *(const float4*)(W + (size_t)(e0 + row) * DM + k0 + 4 * kq);
            blds[(4*kq+0)*68 + row] = vb.x;
            blds[(4*kq+1)*68 + row] = vb.y;
            blds[(4*kq+2)*68 + row] = vb.z;
            blds[(4*kq+3)*68 + row] = vb.w;
        }
        __syncthreads();
        #pragma unroll 8
        for (int k = 0; k < 32; ++k) {
            const float4 a = *(const float4*)&alds[k*68 + 4*ty];
            const float4 b = *(const float4*)&blds[k*68 + 4*tx];
            const float av[4] = {a.x, a.y, a.z, a.w};
            const float bv[4] = {b.x, b.y, b.z, b.w};
            #pragma unroll
            for (int i = 0; i < 4; ++i)
                #pragma unroll
                for (int j = 0; j < 4; ++j)
                    acc[i][j] = fmaf(av[i], bv[j], acc[i][j]);
        }
        __syncthreads();
    }
    const bool valid = (e0 + 4*tx + 4) <= ED;
    float4 bias = make_float4(0.f, 0.f, 0.f, 0.f);
    if (valid) bias = *(const float4*)(bproj + e0 + 4*tx);
    #pragma unroll
    for (int i = 0; i < 4; ++i) {
        if (valid) {
            float4 o;
            o.x = acc[i][0] + bias.x;
            o.y = acc[i][1] + bias.y;
            o.z = acc[i][2] + bias.z;
            o.w = acc[i][3] + bias.w;
            *(float4*)(Z + (size_t)(m0 + 4*ty + i) * ED + e0 + 4*tx) = o;
        }
    }
}

__global__ __launch_bounds__(64)
void k_zsq(const float* __restrict__ Z, float* __restrict__ zsq) {
    const int r = blockIdx.x;
    const float4* row4 = (const float4*)(Z + (size_t)r * ED);
    double s = 0.0;
    for (int q = threadIdx.x; q < ED / 4; q += 64) {
        const float4 v = row4[q];
        s += (double)v.x * v.x + (double)v.y * v.y + (double)v.z * v.z + (double)v.w * v.w;
    }
    #pragma unroll
    for (int off = 32; off > 0; off >>= 1) s += __shfl_down(s, off);
    if (threadIdx.x == 0) zsq[r] = (float)s;
}

__global__ __launch_bounds__(512, 2)
void k_dist(const float* __restrict__ Z, const float* __restrict__ basis,
            const float* __restrict__ bsq, const float* __restrict__ zsq,
            float* __restrict__ A, float* __restrict__ wgpart,
            int* __restrict__ idxws, float* __restrict__ out) {
    const int bid = blockIdx.x;
    const int wr0 = bid * 32;
    const int t   = threadIdx.x;
    const int cg  = t & 127;
    const int rq  = t >> 7;
    const int r0  = rq * 8;
    const int c0  = cg * 4;
    const int c1  = 512 + cg * 4;
    __shared__ float blds[16 * 1024];
    __shared__ float zlds[16 * 36];
    float acc[8][8];
    #pragma unroll
    for (int i = 0; i < 8; ++i)
        #pragma unroll
        for (int j = 0; j < 8; ++j) acc[i][j] = 0.f;
    for (int k0 = 0; k0 < ED; k0 += 16) {
        const bool full = (k0 + 16) <= ED;
        #pragma unroll
        for (int rep = 0; rep < 2; ++rep) {
            const int c = t + rep * 512;
            const float* bp = basis + (size_t)c * ED + k0;
            if (full) {
                const float4 v0 = *(const float4*)(bp + 0);
                const float4 v1 = *(const float4*)(bp + 4);
                const float4 v2 = *(const float4*)(bp + 8);
                const float4 v3 = *(const float4*)(bp + 12);
                blds[ 0*1024+c]=v0.x; blds[ 1*1024+c]=v0.y; blds[ 2*1024+c]=v0.z; blds[ 3*1024+c]=v0.w;
                blds[ 4*1024+c]=v1.x; blds[ 5*1024+c]=v1.y; blds[ 6*1024+c]=v1.z; blds[ 7*1024+c]=v1.w;
                blds[ 8*1024+c]=v2.x; blds[ 9*1024+c]=v2.y; blds[10*1024+c]=v2.z; blds[11*1024+c]=v2.w;
                blds[12*1024+c]=v3.x; blds[13*1024+c]=v3.y; blds[14*1024+c]=v3.z; blds[15*1024+c]=v3.w;
            } else {
                for (int kk = 0; kk < 16; ++kk)
                    blds[kk*1024 + c] = (k0 + kk < ED) ? bp[kk] : 0.f;
            }
        }
        if (t < 128) {
            const int row = t >> 2, kq = t & 3;
            const float* zp = Z + (size_t)(wr0 + row) * ED + k0 + 4 * kq;
            if (full) {
                const float4 v = *(const float4*)zp;
                zlds[(4*kq+0)*36 + row] = v.x;
                zlds[(4*kq+1)*36 + row] = v.y;
                zlds[(4*kq+2)*36 + row] = v.z;
                zlds[(4*kq+3)*36 + row] = v.w;
            } else {
                for (int j = 0; j < 4; ++j) {
                    const int k = k0 + 4*kq + j;
                    zlds[(4*kq+j)*36 + row] = (k < ED) ? zp[j] : 0.f;
                }
            }
        }
        __syncthreads();
        #pragma unroll
        for (int k = 0; k < 16; ++k) {
            const float4 z0 = *(const float4*)&zlds[k*36 + r0];
            const float4 z1 = *(const float4*)&zlds[k*36 + r0 + 4];
            const float4 b0 = *(const float4*)&blds[k*1024 + c0];
            const float4 b1 = *(const float4*)&blds[k*1024 + c1];
            const float zz[8] = {z0.x, z0.y, z0.z, z0.w, z1.x, z1.y, z1.z, z1.w};
            const float bb[8] = {b0.x, b0.y, b0.z, b0.w, b1.x, b1.y, b1.z, b1.w};
            #pragma unroll
            for (int i = 0; i < 8; ++i)
                #pragma unroll
                for (int j = 0; j < 8; ++j)
                    acc[i][j] = fmaf(zz[i], bb[j], acc[i][j]);
        }
        __syncthreads();
    }
    float* red_v    = blds;
    int*   red_i    = (int*)(blds + 4096);
    float* row_dmin = blds + 8192;
    float* row_s    = blds + 8224;
    float* pc       = blds + 8256;
    float bsqv[8], zsqv[8];
    #pragma unroll
    for (int j = 0; j < 4; ++j) { bsqv[j] = bsq[c0 + j]; bsqv[4 + j] = bsq[c1 + j]; }
    #pragma unroll
    for (int i = 0; i < 8; ++i) zsqv[i] = zsq[wr0 + r0 + i];
    #pragma unroll
    for (int i = 0; i < 8; ++i)
        #pragma unroll
        for (int j = 0; j < 8; ++j) {
            const float tv = zsqv[i] - 2.f * acc[i][j];
            acc[i][j] = tv + bsqv[j];
        }
    #pragma unroll
    for (int i = 0; i < 8; ++i) {
        float bv = acc[i][0]; int bi = c0;
        #pragma unroll
        for (int j = 1; j < 8; ++j) {
            const int c = (j < 4) ? (c0 + j) : (c1 + (j - 4));
            if (acc[i][j] < bv || (acc[i][j] == bv && c < bi)) { bv = acc[i][j]; bi = c; }
        }
        red_v[(r0 + i) * 128 + cg] = bv;
        red_i[(r0 + i) * 128 + cg] = bi;
    }
    __syncthreads();
    if (t < 32) {
        float bv = red_v[t * 128]; int bi = red_i[t * 128];
        for (int x = 1; x < 128; ++x) {
            const float v = red_v[t * 128 + x];
            const int  iv = red_i[t * 128 + x];
            if (v < bv || (v == bv && iv < bi)) { bv = v; bi = iv; }
        }
        row_dmin[t] = bv;
        idxws[wr0 + t] = bi;
        out[IDX_OFF + wr0 + t] = (float)bi;
    }
    __syncthreads();
    float su[8];
    #pragma unroll
    for (int i = 0; i < 8; ++i) {
        const float dm = row_dmin[r0 + i];
        float s = 0.f;
        #pragma unroll
        for (int j = 0; j < 8; ++j) {
            const float u = expf(dm - acc[i][j]);
            acc[i][j] = u;
            s += u;
        }
        su[i] = s;
    }
    #pragma unroll
    for (int i = 0; i < 8; ++i) red_v[(r0 + i) * 128 + cg] = su[i];
    __syncthreads();
    if (t < 32) {
        float s = 0.f;
        for (int x = 0; x < 128; ++x) s += red_v[t * 128 + x];
        row_s[t] = s;
    }
    __syncthreads();
    float rcp[8];
    #pragma unroll
    for (int i = 0; i < 8; ++i) rcp[i] = 1.f / row_s[r0 + i];
    pc[t] = 0.f; pc[t + 512] = 0.f;
    __syncthreads();
    #pragma unroll
    for (int j = 0; j < 8; ++j) {
        const int c = (j < 4) ? (c0 + j) : (c1 + (j - 4));
        float s = 0.f;
        #pragma unroll
        for (int i = 0; i < 8; ++i) s += acc[i][j] * rcp[i];
        atomicAdd(&pc[c], s);
    }
    __syncthreads();
    atomicAdd(&A[t],       pc[t]);
    atomicAdd(&A[t + 512], pc[t + 512]);
    if (t == 0) {
        float s = 0.f;
        for (int r = 0; r < 32; ++r) s += row_dmin[r];
        wgpart[bid] = s;
    }
}

// =====================================================================

extern "C" void kernel_launch(void* const* d_in, const int* in_sizes, int n_in,
                              void* d_out, int out_size, void* d_ws, size_t ws_size,
                              hipStream_t stream) {
    const float* S     = (const float*)d_in[0];  // [32768, 256]
    const float* W     = (const float*)d_in[1];  // [2700, 256]
    const float* bproj = (const float*)d_in[2];  // [2700]
    const float* basis = (const float*)d_in[3];  // [1024, 2700]
    float* out = (float*)d_out;
    float* ws  = (float*)d_ws;

    // common small regions
    float* zsq    = ws;                  // 32768
    float* A      = ws + 32768;          // 1024
    float* bsq    = ws + 33792;          // 1024
    float* wgpart = ws + 34816;          // 1024
    int*   idxws  = (int*)(ws + 35840);  // 32768

    // ws floats: 68608 small + Ph/Pm 262144 + transients 5316992 = 5,647,744 (~22.6 MB)
    const size_t NEED = (size_t)5647744 * sizeof(float);
    if (ws_size >= NEED) {
        // -------- MFMA path (reassociated: G = S.(basis.W)^T, fused dist) --------
        unsigned short* Ph = (unsigned short*)(ws + 68608);            // 1024*256 ush
        unsigned short* Pm = (unsigned short*)(ws + 68608 + 131072);
        float* basisP  = ws + 330752;        // 1024*2720 = 2785280
        float* WT      = ws + 3116032;       // 256*2720  = 696320
        float* uv      = ws + 3812352;       // 257 (u[256], v)
        float* Pp      = ws + 3812736;       // 5*262144 = 1310720
        float* Mp      = ws + 5123456;       // 5*65536  = 327680
        float* Mm      = ws + 5451136;       // 65536
        float* zsqpart = ws + 5516672;       // 4*32768  = 131072 -> ends 5647744
        // S planes live in q_st output region (dead before k_gather writes q_st)
        unsigned short* Sh = (unsigned short*)out;                     // 32768*256 ush
        unsigned short* Sm = Sh + (size_t)BKROWS * DM;

        hipMemsetAsync(A, 0, (size_t)NC * sizeof(float), stream);
        k_packS <<<BKROWS * DM / 1024, 256, 0, stream>>>(S, Sh, Sm);
        k_bsq2  <<<NC, 256, 0, stream>>>(basis, bproj, bsq);
        k_padB  <<<NC, 256, 0, stream>>>(basis, basisP);
        k_padWT <<<dim3(43, 4), 256, 0, stream>>>(W, WT);
        k_uv2   <<<257, 256, 0, stream>>>(WT, bproj, uv);
        k_gsplit<<<dim3(4, 16, 5), 256, 0, stream>>>(basisP, WT, Pp, 256);  // P partials
        k_gsplit<<<dim3(4, 4, 5),  256, 0, stream>>>(WT, WT, Mp, 256);      // M partials
        k_redP  <<<1024, 256, 0, stream>>>(Pp, Ph, Pm);
        k_redM  <<<256, 256, 0, stream>>>(Mp, Mm);
        k_zsqS  <<<dim3(NTZ, 512), 256, 0, stream>>>(S, Mm, uv, zsqpart);
        k_zsqred<<<BKROWS / 256, 256, 0, stream>>>(zsqpart, zsq);
        k_fdist3<<<BKROWS / 32, 512, 0, stream>>>(Sh, Sm, Ph, Pm, bsq, zsq, A, wgpart, idxws, out);
        k_final <<<1, 1024, 0, stream>>>(wgpart, A, out);
        k_gather<<<BKROWS, 256, 0, stream>>>(basis, idxws, out);
    } else {
        // -------- fallback: round-2 f32 path --------
        float* Z = out;
        hipMemsetAsync(A, 0, (size_t)NC * sizeof(float), stream);
        k_bsq   <<<NC, 256, 0, stream>>>(basis, bsq);
        k_gemm1 <<<dim3(43, 512), 256, 0, stream>>>(S, W, bproj, Z);
        k_zsq   <<<BKROWS, 64, 0, stream>>>(Z, zsq);
        k_dist  <<<BKROWS / 32, 512, 0, stream>>>(Z, basis, bsq, zsq, A, wgpart, idxws, out);
        k_final <<<1, 1024, 0, stream>>>(wgpart, A, out);
        k_gather<<<BKROWS, 256, 0, stream>>>(basis, idxws, out);
    }
}

// Round 13
// 367.643 us; speedup vs baseline: 1.4208x; 1.3042x over previous
//
#include <hip/hip_runtime.h>
#include <math.h>

#define ED 2700     // basis_dim
#define NC 1024     // num_codes
#define DM 256      // d_model
#define BKROWS 32768

#define IDX_OFF 88473600
#define VQ_OFF  88506368
#define ENT_OFF 88506369

#define KPAD 2720     // padded K for P/M small GEMMs (5 x 544)
#define K2CH 8        // gemm chunks (K=256 / 32)

typedef float  f32x4  __attribute__((ext_vector_type(4)));
typedef short  bf16x8 __attribute__((ext_vector_type(8)));

__device__ inline unsigned short f2bf(float x) {
    unsigned int u = __float_as_uint(x);
    unsigned int r = (u + 0x7FFFu + ((u >> 16) & 1u)) >> 16;
    return (unsigned short)r;
}
__device__ inline float bf2f(unsigned short h) {
    return __uint_as_float(((unsigned int)h) << 16);
}

// =====================================================================
// ============================ MFMA PATH ==============================
// =====================================================================

// ---- S -> Sh/Sm bf16 planes ----
__global__ __launch_bounds__(256)
void k_packS(const float* __restrict__ S, unsigned short* __restrict__ Sh,
             unsigned short* __restrict__ Sm) {
    const size_t i4 = (size_t)blockIdx.x * 256 + threadIdx.x;
    const float4 v = *(const float4*)(S + i4 * 4);
    ushort4 hv, mv;
    unsigned short* hp = (unsigned short*)&hv;
    unsigned short* mp = (unsigned short*)&mv;
    const float xs[4] = {v.x, v.y, v.z, v.w};
    #pragma unroll
    for (int j = 0; j < 4; ++j) {
        const unsigned short h = f2bf(xs[j]);
        hp[j] = h;
        mp[j] = f2bf(xs[j] - bf2f(h));
    }
    *(ushort4*)(Sh + i4 * 4) = hv;
    *(ushort4*)(Sm + i4 * 4) = mv;
}

// ---- merged: basisP (zero-padded copy) + bsq'[c] = sum b^2 - 2 b.bproj ----
__global__ void k_prepB(const float* __restrict__ basis, const float* __restrict__ bproj,
                        float* __restrict__ bP, float* __restrict__ bsq) {
    const int c = blockIdx.x;
    const int t = threadIdx.x;
    const float* row = basis + (size_t)c * ED;
    float* dst = bP + (size_t)c * KPAD;
    double s2 = 0.0, sp = 0.0;
    for (int j = t; j < ED; j += 256) {
        const float x = row[j];
        dst[j] = x;
        s2 += (double)x * (double)x;
        sp += (double)x * (double)bproj[j];
    }
    if (t < KPAD - ED) dst[ED + t] = 0.f;
    __shared__ double sd[512];
    sd[t] = s2; sd[256 + t] = sp;
    __syncthreads();
    for (int off = 128; off > 0; off >>= 1) {
        if (t < off) { sd[t] += sd[t + off]; sd[256 + t] += sd[256 + t + off]; }
        __syncthreads();
    }
    if (t == 0) bsq[c] = (float)(sd[0] - 2.0 * sd[256]);
}

// ---- WT = W^T zero-padded to [256][2720] ----
__global__ __launch_bounds__(256)
void k_padWT(const float* __restrict__ W, float* __restrict__ WT) {
    const int e0 = blockIdx.x * 64;
    const int d0 = blockIdx.y * 64;
    __shared__ float tbuf[64][65];
    const int t  = threadIdx.x;
    const int r  = t >> 2;
    const int q4 = t & 3;
    #pragma unroll
    for (int j = 0; j < 4; ++j) {
        const int col = q4 * 16 + j * 4;
        const int e = e0 + r;
        float4 v = make_float4(0.f, 0.f, 0.f, 0.f);
        if (e < ED) v = *(const float4*)(W + (size_t)e * DM + d0 + col);
        tbuf[r][col + 0] = v.x; tbuf[r][col + 1] = v.y;
        tbuf[r][col + 2] = v.z; tbuf[r][col + 3] = v.w;
    }
    __syncthreads();
    #pragma unroll
    for (int j = 0; j < 4; ++j) {
        const int col = q4 * 16 + j * 4;
        if (e0 + col < KPAD) {
            float4 o;
            o.x = tbuf[col + 0][r]; o.y = tbuf[col + 1][r];
            o.z = tbuf[col + 2][r]; o.w = tbuf[col + 3][r];
            *(float4*)(WT + (size_t)(d0 + r) * KPAD + e0 + col) = o;
        }
    }
}

// ---- k_uv2: u[d] = WT[d].bproj (blocks 0..255); v = ||bproj||^2 (block 256) ----
__global__ __launch_bounds__(256)
void k_uv2(const float* __restrict__ WT, const float* __restrict__ bproj,
           float* __restrict__ uv) {
    const int b = blockIdx.x;
    const int t = threadIdx.x;
    double s = 0.0;
    if (b < 256) {
        const float* row = WT + (size_t)b * KPAD;
        for (int j = t; j < ED; j += 256) s += (double)row[j] * (double)bproj[j];
    } else {
        for (int j = t; j < ED; j += 256) { const double x = bproj[j]; s += x * x; }
    }
    __shared__ double sd[256];
    sd[t] = s;
    __syncthreads();
    for (int off = 128; off > 0; off >>= 1) {
        if (t < off) sd[t] += sd[t + off];
        __syncthreads();
    }
    if (t == 0) uv[b] = (float)sd[0];
}

// ---- column sums of S (coalesced, deterministic): cspart[blk][d] ----
__global__ __launch_bounds__(256)
void k_colsum(const float* __restrict__ S, float* __restrict__ cspart) {
    const int m0 = blockIdx.x * 256;
    const int t  = threadIdx.x;
    double s = 0.0;
    for (int r = 0; r < 256; ++r) s += (double)S[(size_t)(m0 + r) * DM + t];
    cspart[blockIdx.x * 256 + t] = (float)s;
}

// ---- generic 64x64-tile f32 GEMM partial over K-slab of 544 ----
__global__ __launch_bounds__(256)
void k_gsplit(const float* __restrict__ A, const float* __restrict__ B,
              float* __restrict__ Cp, int nld) {
    const int n0  = blockIdx.x * 64;
    const int m0  = blockIdx.y * 64;
    const int k00 = blockIdx.z * 544;
    float* Cout = Cp + (size_t)blockIdx.z * (size_t)gridDim.y * 64 * nld;
    const int t  = threadIdx.x;
    const int tx = t & 15, ty = t >> 4;

    __shared__ float alds[32 * 68];
    __shared__ float blds[32 * 68];

    float acc[4][4] = {};

    for (int k0 = k00; k0 < k00 + 544; k0 += 32) {
        #pragma unroll
        for (int rep = 0; rep < 2; ++rep) {
            const int id  = t + rep * 256;
            const int row = id >> 3, kq = id & 7;
            const float4 va = *(const float4*)(A + (size_t)(m0 + row) * KPAD + k0 + 4 * kq);
            alds[(4*kq+0)*68 + row] = va.x;
            alds[(4*kq+1)*68 + row] = va.y;
            alds[(4*kq+2)*68 + row] = va.z;
            alds[(4*kq+3)*68 + row] = va.w;
            const float4 vb = *(const float4*)(B + (size_t)(n0 + row) * KPAD + k0 + 4 * kq);
            blds[(4*kq+0)*68 + row] = vb.x;
            blds[(4*kq+1)*68 + row] = vb.y;
            blds[(4*kq+2)*68 + row] = vb.z;
            blds[(4*kq+3)*68 + row] = vb.w;
        }
        __syncthreads();
        #pragma unroll 8
        for (int k = 0; k < 32; ++k) {
            const float4 a = *(const float4*)&alds[k*68 + 4*ty];
            const float4 b = *(const float4*)&blds[k*68 + 4*tx];
            const float av[4] = {a.x, a.y, a.z, a.w};
            const float bv[4] = {b.x, b.y, b.z, b.w};
            #pragma unroll
            for (int i = 0; i < 4; ++i)
                #pragma unroll
                for (int j = 0; j < 4; ++j)
                    acc[i][j] = fmaf(av[i], bv[j], acc[i][j]);
        }
        __syncthreads();
    }
    #pragma unroll
    for (int i = 0; i < 4; ++i) {
        float4 o; o.x = acc[i][0]; o.y = acc[i][1]; o.z = acc[i][2]; o.w = acc[i][3];
        *(float4*)(Cout + (size_t)(m0 + 4*ty + i) * nld + n0 + 4*tx) = o;
    }
}

// ---- reduce 5 P-partials -> Ph/Pm planes ----
__global__ __launch_bounds__(256)
void k_redP(const float* __restrict__ Pp, unsigned short* __restrict__ Ph,
            unsigned short* __restrict__ Pm) {
    const size_t idx = (size_t)blockIdx.x * 256 + threadIdx.x;
    float s = 0.f;
    #pragma unroll
    for (int k = 0; k < 5; ++k) s += Pp[(size_t)k * 262144 + idx];
    const unsigned short h = f2bf(s);
    Ph[idx] = h;
    Pm[idx] = f2bf(s - bf2f(h));
}

// ---- reduce 5 M-partials -> Mh/Mm bf16 planes ----
__global__ __launch_bounds__(256)
void k_redM2(const float* __restrict__ Mp, unsigned short* __restrict__ Mh,
             unsigned short* __restrict__ Mm) {
    const size_t idx = (size_t)blockIdx.x * 256 + threadIdx.x;   // 65536
    float s = 0.f;
    #pragma unroll
    for (int k = 0; k < 5; ++k) s += Mp[(size_t)k * 65536 + idx];
    const unsigned short h = f2bf(s);
    Mh[idx] = h;
    Mm[idx] = f2bf(s - bf2f(h));
}

// ---- K2m: G = S.P^T, 256x256 tile, 8 waves, 4-phase counted-vmcnt, K=256 ----
// (byte-identical to the round-9 proven kernel)
__global__ __launch_bounds__(512, 2)
void k_gemm2(const unsigned short* __restrict__ Zh, const unsigned short* __restrict__ Zm,
             const unsigned short* __restrict__ Bh, const unsigned short* __restrict__ Bm,
             float* __restrict__ G) {
    __shared__ unsigned short lds[2 * 32768];

    const int bid  = blockIdx.x;
    const int xcd  = bid & 7, local = bid >> 3;
    const int mt   = xcd * 16 + (local >> 2);
    const int nt   = local & 3;
    const int m0   = mt * 256, n0 = nt * 256;
    const int tid  = threadIdx.x;
    const int w    = tid >> 6, l = tid & 63;
    const int wr   = (w >> 2) * 128;
    const int wc   = (w & 3) * 64;
    const int lrow = l & 15;
    const int lu   = l >> 4;

    const unsigned short* hsrc[4][2];
    int hlds[4][2];
    #pragma unroll
    for (int ht = 0; ht < 4; ++ht) {
        #pragma unroll
        for (int j = 0; j < 2; ++j) {
            const int slot = j * 512 + tid;
            const int rwh  = slot >> 3;
            const int unit = slot & 7;
            int row; bool isB;
            if (ht == 0)      { row = (rwh & 63) + (rwh >> 6) * 128;       isB = false; }
            else if (ht == 1) { row = 64 + (rwh & 63) + (rwh >> 6) * 128;  isB = false; }
            else if (ht == 2) { row = (rwh & 31) + (rwh >> 5) * 64;        isB = true;  }
            else              { row = 32 + (rwh & 31) + (rwh >> 5) * 64;   isB = true;  }
            const int sg   = unit ^ (row & 7);
            const int pl   = sg >> 2;
            const int koff = (sg & 3) * 8;
            if (!isB) hsrc[ht][j] = (pl ? Zm : Zh) + (size_t)(m0 + row) * DM + koff;
            else      hsrc[ht][j] = (pl ? Bm : Bh) + (size_t)(n0 + row) * DM + koff;
            hlds[ht][j] = (isB ? 16384 : 0) + row * 64 + unit * 8;
        }
    }

    f32x4 acc[8][4];
    #pragma unroll
    for (int i = 0; i < 8; ++i)
        #pragma unroll
        for (int j = 0; j < 4; ++j) acc[i][j] = (f32x4){0.f, 0.f, 0.f, 0.f};

    #define STAGE_HALF(ht, ck, db) { \
        _Pragma("unroll") \
        for (int j = 0; j < 2; ++j) \
            __builtin_amdgcn_global_load_lds( \
                (const __attribute__((address_space(1))) unsigned int*)(const void*)(hsrc[ht][j] + (ck) * 32), \
                (__attribute__((address_space(3))) unsigned int*)(void*)&lds[(db) * 32768 + hlds[ht][j]], \
                16, 0, 0); \
    }

    #define LOAD_A(db, qm) { \
        const unsigned short* At = &lds[(db) * 32768]; \
        _Pragma("unroll") \
        for (int f = 0; f < 4; ++f) { \
            const int row = wr + ((qm) * 4 + f) * 16 + lrow; \
            ah[f] = *(const bf16x8*)(At + row * 64 + (((0 + lu) ^ (row & 7))) * 8); \
            am[f] = *(const bf16x8*)(At + row * 64 + (((4 + lu) ^ (row & 7))) * 8); \
        } \
    }
    #define LOAD_B(db, qn) { \
        const unsigned short* Bt = &lds[(db) * 32768 + 16384]; \
        _Pragma("unroll") \
        for (int f = 0; f < 2; ++f) { \
            const int col = wc + ((qn) * 2 + f) * 16 + lrow; \
            bh[f] = *(const bf16x8*)(Bt + col * 64 + (((0 + lu) ^ (col & 7))) * 8); \
            bm[f] = *(const bf16x8*)(Bt + col * 64 + (((4 + lu) ^ (col & 7))) * 8); \
        } \
    }
    #define MFMA_Q(qm, qn) { \
        __builtin_amdgcn_s_setprio(1); \
        _Pragma("unroll") \
        for (int i = 0; i < 4; ++i) \
            _Pragma("unroll") \
            for (int j = 0; j < 2; ++j) { \
                f32x4 cc = acc[(qm) * 4 + i][(qn) * 2 + j]; \
                cc = __builtin_amdgcn_mfma_f32_16x16x32_bf16(ah[i], bh[j], cc, 0, 0, 0); \
                cc = __builtin_amdgcn_mfma_f32_16x16x32_bf16(ah[i], bm[j], cc, 0, 0, 0); \
                cc = __builtin_amdgcn_mfma_f32_16x16x32_bf16(am[i], bh[j], cc, 0, 0, 0); \
                acc[(qm) * 4 + i][(qn) * 2 + j] = cc; \
            } \
        __builtin_amdgcn_s_setprio(0); \
    }
    #define VM8  asm volatile("s_waitcnt vmcnt(8)" ::: "memory");
    #define BAR  __builtin_amdgcn_s_barrier();

    STAGE_HALF(0, 0, 0) STAGE_HALF(2, 0, 0) STAGE_HALF(3, 0, 0) STAGE_HALF(1, 0, 0)
    STAGE_HALF(0, 1, 1) STAGE_HALF(2, 1, 1)
    VM8
    BAR

    for (int c = 0; c < K2CH - 2; ++c) {
        const int cb = c & 1, ob = cb ^ 1;
        bf16x8 ah[4], am[4], bh[2], bm[2];
        LOAD_A(cb, 0) LOAD_B(cb, 0)
        STAGE_HALF(3, c + 1, ob)
        BAR
        MFMA_Q(0, 0)
        VM8
        BAR
        LOAD_B(cb, 1)
        STAGE_HALF(1, c + 1, ob)
        BAR
        MFMA_Q(0, 1)
        VM8
        BAR
        LOAD_A(cb, 1) LOAD_B(cb, 0)
        STAGE_HALF(0, c + 2, cb)
        BAR
        MFMA_Q(1, 0)
        BAR
        LOAD_B(cb, 1)
        STAGE_HALF(2, c + 2, cb)
        BAR
        MFMA_Q(1, 1)
        VM8
        BAR
    }

    STAGE_HALF(3, K2CH - 1, (K2CH - 1) & 1) STAGE_HALF(1, K2CH - 1, (K2CH - 1) & 1)
    asm volatile("s_waitcnt vmcnt(0)" ::: "memory");
    BAR
    #pragma unroll
    for (int e = 0; e < 2; ++e) {
        const int cb = (K2CH - 2 + e) & 1;
        bf16x8 ah[4], am[4], bh[2], bm[2];
        LOAD_A(cb, 0) LOAD_B(cb, 0)
        MFMA_Q(0, 0)
        LOAD_B(cb, 1)
        MFMA_Q(0, 1)
        LOAD_A(cb, 1) LOAD_B(cb, 0)
        MFMA_Q(1, 0)
        LOAD_B(cb, 1)
        MFMA_Q(1, 1)
    }

    // C layout: col = lane&15, row = (lane>>4)*4 + reg
    #pragma unroll
    for (int fm = 0; fm < 8; ++fm)
        #pragma unroll
        for (int fn = 0; fn < 4; ++fn) {
            const int col = n0 + wc + fn * 16 + lrow;
            #pragma unroll
            for (int r = 0; r < 4; ++r) {
                const int row = m0 + wr + fm * 16 + lu * 4 + r;
                G[(size_t)row * NC + col] = acc[fm][fn][r];
            }
        }
}

// ---- k_ydot: ydotpart[b] = <(S.M^T)_tile, S_tile> using the same proven core.
//      Grid 128: m0 = mt*256, n0 = 0 (M is 256x256).
__global__ __launch_bounds__(512, 2)
void k_ydot(const unsigned short* __restrict__ Zh, const unsigned short* __restrict__ Zm,
            const unsigned short* __restrict__ Bh, const unsigned short* __restrict__ Bm,
            const float* __restrict__ S, float* __restrict__ ydotpart) {
    __shared__ unsigned short lds[2 * 32768];

    const int bid  = blockIdx.x;
    const int xcd  = bid & 7, local = bid >> 3;
    const int mt   = xcd * 16 + local;
    const int m0   = mt * 256, n0 = 0;
    const int tid  = threadIdx.x;
    const int w    = tid >> 6, l = tid & 63;
    const int wr   = (w >> 2) * 128;
    const int wc   = (w & 3) * 64;
    const int lrow = l & 15;
    const int lu   = l >> 4;

    const unsigned short* hsrc[4][2];
    int hlds[4][2];
    #pragma unroll
    for (int ht = 0; ht < 4; ++ht) {
        #pragma unroll
        for (int j = 0; j < 2; ++j) {
            const int slot = j * 512 + tid;
            const int rwh  = slot >> 3;
            const int unit = slot & 7;
            int row; bool isB;
            if (ht == 0)      { row = (rwh & 63) + (rwh >> 6) * 128;       isB = false; }
            else if (ht == 1) { row = 64 + (rwh & 63) + (rwh >> 6) * 128;  isB = false; }
            else if (ht == 2) { row = (rwh & 31) + (rwh >> 5) * 64;        isB = true;  }
            else              { row = 32 + (rwh & 31) + (rwh >> 5) * 64;   isB = true;  }
            const int sg   = unit ^ (row & 7);
            const int pl   = sg >> 2;
            const int koff = (sg & 3) * 8;
            if (!isB) hsrc[ht][j] = (pl ? Zm : Zh) + (size_t)(m0 + row) * DM + koff;
            else      hsrc[ht][j] = (pl ? Bm : Bh) + (size_t)(n0 + row) * DM + koff;
            hlds[ht][j] = (isB ? 16384 : 0) + row * 64 + unit * 8;
        }
    }

    f32x4 acc[8][4];
    #pragma unroll
    for (int i = 0; i < 8; ++i)
        #pragma unroll
        for (int j = 0; j < 4; ++j) acc[i][j] = (f32x4){0.f, 0.f, 0.f, 0.f};

    STAGE_HALF(0, 0, 0) STAGE_HALF(2, 0, 0) STAGE_HALF(3, 0, 0) STAGE_HALF(1, 0, 0)
    STAGE_HALF(0, 1, 1) STAGE_HALF(2, 1, 1)
    VM8
    BAR

    for (int c = 0; c < K2CH - 2; ++c) {
        const int cb = c & 1, ob = cb ^ 1;
        bf16x8 ah[4], am[4], bh[2], bm[2];
        LOAD_A(cb, 0) LOAD_B(cb, 0)
        STAGE_HALF(3, c + 1, ob)
        BAR
        MFMA_Q(0, 0)
        VM8
        BAR
        LOAD_B(cb, 1)
        STAGE_HALF(1, c + 1, ob)
        BAR
        MFMA_Q(0, 1)
        VM8
        BAR
        LOAD_A(cb, 1) LOAD_B(cb, 0)
        STAGE_HALF(0, c + 2, cb)
        BAR
        MFMA_Q(1, 0)
        BAR
        LOAD_B(cb, 1)
        STAGE_HALF(2, c + 2, cb)
        BAR
        MFMA_Q(1, 1)
        VM8
        BAR
    }

    STAGE_HALF(3, K2CH - 1, (K2CH - 1) & 1) STAGE_HALF(1, K2CH - 1, (K2CH - 1) & 1)
    asm volatile("s_waitcnt vmcnt(0)" ::: "memory");
    BAR
    #pragma unroll
    for (int e = 0; e < 2; ++e) {
        const int cb = (K2CH - 2 + e) & 1;
        bf16x8 ah[4], am[4], bh[2], bm[2];
        LOAD_A(cb, 0) LOAD_B(cb, 0)
        MFMA_Q(0, 0)
        LOAD_B(cb, 1)
        MFMA_Q(0, 1)
        LOAD_A(cb, 1) LOAD_B(cb, 0)
        MFMA_Q(1, 0)
        LOAD_B(cb, 1)
        MFMA_Q(1, 1)
    }
    #undef STAGE_HALF
    #undef LOAD_A
    #undef LOAD_B
    #undef MFMA_Q
    #undef VM8
    #undef BAR

    // epilogue: part = sum acc .* S (same C layout), block-reduce (deterministic)
    float part = 0.f;
    #pragma unroll
    for (int fm = 0; fm < 8; ++fm)
        #pragma unroll
        for (int fn = 0; fn < 4; ++fn) {
            const int col = wc + fn * 16 + lrow;
            #pragma unroll
            for (int r = 0; r < 4; ++r) {
                const int row = m0 + wr + fm * 16 + lu * 4 + r;
                part += acc[fm][fn][r] * S[(size_t)row * DM + col];
            }
        }
    __syncthreads();   // all waves done with lds reads
    float* red = (float*)lds;
    red[tid] = part;
    __syncthreads();
    for (int off = 256; off > 0; off >>= 1) {
        if (tid < off) red[tid] += red[tid + off];
        __syncthreads();
    }
    if (tid == 0) ydotpart[bid] = red[0];
}

// ---- K-post: dist' = bsq' - 2G (zsq dropped; argmin/softmax invariant) ----
__global__ __launch_bounds__(512)
void k_post(const float* __restrict__ G, const float* __restrict__ bsq,
            float* __restrict__ A, float* __restrict__ wgpart,
            int* __restrict__ idxws, float* __restrict__ out) {
    const int bid = blockIdx.x;
    const int wr0 = bid * 32;
    const int t   = threadIdx.x;
    const int cg  = t & 127;
    const int rq  = t >> 7;
    const int r0  = rq * 8;
    const int c0  = cg * 4;
    const int c1  = 512 + cg * 4;

    __shared__ float sm[9280];
    float* red_v    = sm;
    int*   red_i    = (int*)(sm + 4096);
    float* row_dmin = sm + 8192;
    float* row_s    = sm + 8224;
    float* pc       = sm + 8256;

    float acc[8][8];
    #pragma unroll
    for (int i = 0; i < 8; ++i) {
        const float4 g0 = *(const float4*)&G[(size_t)(wr0 + r0 + i) * NC + c0];
        const float4 g1 = *(const float4*)&G[(size_t)(wr0 + r0 + i) * NC + c1];
        acc[i][0] = g0.x; acc[i][1] = g0.y; acc[i][2] = g0.z; acc[i][3] = g0.w;
        acc[i][4] = g1.x; acc[i][5] = g1.y; acc[i][6] = g1.z; acc[i][7] = g1.w;
    }

    float bsqv[8];
    #pragma unroll
    for (int j = 0; j < 4; ++j) { bsqv[j] = bsq[c0 + j]; bsqv[4 + j] = bsq[c1 + j]; }

    #pragma unroll
    for (int i = 0; i < 8; ++i)
        #pragma unroll
        for (int j = 0; j < 8; ++j)
            acc[i][j] = bsqv[j] - 2.f * acc[i][j];

    #pragma unroll
    for (int i = 0; i < 8; ++i) {
        float bv = acc[i][0]; int bi = c0;
        #pragma unroll
        for (int j = 1; j < 8; ++j) {
            const int c = (j < 4) ? (c0 + j) : (c1 + (j - 4));
            if (acc[i][j] < bv || (acc[i][j] == bv && c < bi)) { bv = acc[i][j]; bi = c; }
        }
        red_v[(r0 + i) * 128 + cg] = bv;
        red_i[(r0 + i) * 128 + cg] = bi;
    }
    __syncthreads();
    if (t < 32) {
        float bv = red_v[t * 128]; int bi = red_i[t * 128];
        for (int x = 1; x < 128; ++x) {
            const float v = red_v[t * 128 + x];
            const int  iv = red_i[t * 128 + x];
            if (v < bv || (v == bv && iv < bi)) { bv = v; bi = iv; }
        }
        row_dmin[t] = bv;
        idxws[wr0 + t] = bi;
        out[IDX_OFF + wr0 + t] = (float)bi;
    }
    __syncthreads();

    float su[8];
    #pragma unroll
    for (int i = 0; i < 8; ++i) {
        const float dm = row_dmin[r0 + i];
        float s = 0.f;
        #pragma unroll
        for (int j = 0; j < 8; ++j) {
            const float u = expf(dm - acc[i][j]);
            acc[i][j] = u;
            s += u;
        }
        su[i] = s;
    }
    #pragma unroll
    for (int i = 0; i < 8; ++i) red_v[(r0 + i) * 128 + cg] = su[i];
    __syncthreads();
    if (t < 32) {
        float s = 0.f;
        for (int x = 0; x < 128; ++x) s += red_v[t * 128 + x];
        row_s[t] = s;
    }
    __syncthreads();

    float rcp[8];
    #pragma unroll
    for (int i = 0; i < 8; ++i) rcp[i] = 1.f / row_s[r0 + i];

    pc[t] = 0.f; pc[t + 512] = 0.f;
    __syncthreads();
    #pragma unroll
    for (int j = 0; j < 8; ++j) {
        const int c = (j < 4) ? (c0 + j) : (c1 + (j - 4));
        float s = 0.f;
        #pragma unroll
        for (int i = 0; i < 8; ++i) s += acc[i][j] * rcp[i];
        atomicAdd(&pc[c], s);
    }
    __syncthreads();
    atomicAdd(&A[t],       pc[t]);
    atomicAdd(&A[t + 512], pc[t + 512]);

    if (t == 0) {
        float s = 0.f;
        for (int r = 0; r < 32; ++r) s += row_dmin[r];
        wgpart[bid] = s;
    }
}

// ---- finalize scalars: vq = 0.25*(Σminval' + Σzsq)/N; Σzsq = ydot + 2 cs·u + 32768 v ----
__global__ void k_final2(const float* __restrict__ wgpart, const float* __restrict__ Aq,
                         const float* __restrict__ ydotpart, const float* __restrict__ cspart,
                         const float* __restrict__ uv, float* __restrict__ out) {
    __shared__ double sd[1024];
    const int t = threadIdx.x;
    sd[t] = (double)wgpart[t];
    __syncthreads();
    for (int off = 512; off > 0; off >>= 1) {
        if (t < off) sd[t] += sd[t + off];
        __syncthreads();
    }
    const double smin = sd[0];
    __syncthreads();
    sd[t] = (t < 128) ? (double)ydotpart[t] : 0.0;
    __syncthreads();
    for (int off = 512; off > 0; off >>= 1) {
        if (t < off) sd[t] += sd[t + off];
        __syncthreads();
    }
    const double sy = sd[0];
    __syncthreads();
    double cu = 0.0;
    if (t < 256) {
        double cs = 0.0;
        for (int b = 0; b < 128; ++b) cs += (double)cspart[b * 256 + t];
        cu = cs * (double)uv[t];
    }
    sd[t] = cu;
    __syncthreads();
    for (int off = 512; off > 0; off >>= 1) {
        if (t < off) sd[t] += sd[t + off];
        __syncthreads();
    }
    if (t == 0) {
        const double szsq = sy + 2.0 * sd[0] + 32768.0 * (double)uv[256];
        out[VQ_OFF] = (float)(0.25 * (smin + szsq) / 88473600.0);
    }
    __syncthreads();
    const double p = (double)Aq[t] * (1.0 / 32768.0);
    sd[t] = -p * log(p + 1e-8);
    __syncthreads();
    for (int off = 512; off > 0; off >>= 1) {
        if (t < off) sd[t] += sd[t + off];
        __syncthreads();
    }
    if (t == 0) out[ENT_OFF] = (float)sd[0];
}

// ---- q_st = basis[indices] ----
__global__ void k_gather(const float* __restrict__ basis, const int* __restrict__ idxws,
                         float* __restrict__ out) {
    const int r = blockIdx.x;
    const int idx = idxws[r];
    const float4* src = (const float4*)(basis + (size_t)idx * ED);
    float4* dst = (float4*)(out + (size_t)r * ED);
    for (int j = threadIdx.x; j < ED / 4; j += 256) dst[j] = src[j];
}

// =====================================================================
// ===================== FALLBACK (round-2, f32 VALU) ==================
// =====================================================================

__global__ void k_bsq(const float* __restrict__ basis, float* __restrict__ bsq) {
    int c = blockIdx.x;
    const float* row = basis + (size_t)c * ED;
    double s = 0.0;
    for (int j = threadIdx.x; j < ED; j += 256) { float v = row[j]; s += (double)v * (double)v; }
    __shared__ double sd[256];
    sd[threadIdx.x] = s;
    __syncthreads();
    for (int off = 128; off > 0; off >>= 1) {
        if (threadIdx.x < off) sd[threadIdx.x] += sd[threadIdx.x + off];
        __syncthreads();
    }
    if (threadIdx.x == 0) bsq[c] = (float)sd[0];
}

__global__ __launch_bounds__(256, 4)
void k_gemm1(const float* __restrict__ S, const float* __restrict__ W,
             const float* __restrict__ bproj, float* __restrict__ Z) {
    const int e0 = blockIdx.x * 64;
    const int m0 = blockIdx.y * 64;
    const int t  = threadIdx.x;
    const int tx = t & 15, ty = t >> 4;
    __shared__ float alds[32 * 68];
    __shared__ float blds[32 * 68];
    float acc[4][4] = {};
    for (int k0 = 0; k0 < DM; k0 += 32) {
        #pragma unroll
        for (int rep = 0; rep < 2; ++rep) {
            const int id  = t + rep * 256;
            const int row = id >> 3, kq = id & 7;
            const float4 va = *(const float4*)(S + (size_t)(m0 + row) * DM + k0 + 4 * kq);
            alds[(4*kq+0)*68 + row] = va.x;
            alds[(4*kq+1)*68 + row] = va.y;
            alds[(4*kq+2)*68 + row] = va.z;
            alds[(4*kq+3)*68 + row] = va.w;
            float4 vb = make_float4(0.f, 0.f, 0.f, 0.f);
            if (e0 + row < ED)
                vb = *(const float4*)(W + (size_t)(e0 + row) * DM + k0 + 4 * kq);
            blds[(4*kq+0)*68 + row] = vb.x;
            blds[(4*kq+1)*68 + row] = vb.y;
            blds[(4*kq+2)*68 + row] = vb.z;
            blds[(4*kq+3)*68 + row] = vb.w;
        }
        __syncthreads();
        #pragma unroll 8
        for (int k = 0; k < 32; ++k) {
            const float4 a = *(const float4*)&alds[k*68 + 4*ty];
            const float4 b = *(const float4*)&blds[k*68 + 4*tx];
            const float av[4] = {a.x, a.y, a.z, a.w};
            const float bv[4] = {b.x, b.y, b.z, b.w};
            #pragma unroll
            for (int i = 0; i < 4; ++i)
                #pragma unroll
                for (int j = 0; j < 4; ++j)
                    acc[i][j] = fmaf(av[i], bv[j], acc[i][j]);
        }
        __syncthreads();
    }
    const bool valid = (e0 + 4*tx + 4) <= ED;
    float4 bias = make_float4(0.f, 0.f, 0.f, 0.f);
    if (valid) bias = *(const float4*)(bproj + e0 + 4*tx);
    #pragma unroll
    for (int i = 0; i < 4; ++i) {
        if (valid) {
            float4 o;
            o.x = acc[i][0] + bias.x;
            o.y = acc[i][1] + bias.y;
            o.z = acc[i][2] + bias.z;
            o.w = acc[i][3] + bias.w;
            *(float4*)(Z + (size_t)(m0 + 4*ty + i) * ED + e0 + 4*tx) = o;
        }
    }
}

__global__ __launch_bounds__(64)
void k_zsq(const float* __restrict__ Z, float* __restrict__ zsq) {
    const int r = blockIdx.x;
    const float4* row4 = (const float4*)(Z + (size_t)r * ED);
    double s = 0.0;
    for (int q = threadIdx.x; q < ED / 4; q += 64) {
        const float4 v = row4[q];
        s += (double)v.x * v.x + (double)v.y * v.y + (double)v.z * v.z + (double)v.w * v.w;
    }
    #pragma unroll
    for (int off = 32; off > 0; off >>= 1) s += __shfl_down(s, off);
    if (threadIdx.x == 0) zsq[r] = (float)s;
}

__global__ __launch_bounds__(512, 2)
void k_dist(const float* __restrict__ Z, const float* __restrict__ basis,
            const float* __restrict__ bsq, const float* __restrict__ zsq,
            float* __restrict__ A, float* __restrict__ wgpart,
            int* __restrict__ idxws, float* __restrict__ out) {
    const int bid = blockIdx.x;
    const int wr0 = bid * 32;
    const int t   = threadIdx.x;
    const int cg  = t & 127;
    const int rq  = t >> 7;
    const int r0  = rq * 8;
    const int c0  = cg * 4;
    const int c1  = 512 + cg * 4;
    __shared__ float blds[16 * 1024];
    __shared__ float zlds[16 * 36];
    float acc[8][8];
    #pragma unroll
    for (int i = 0; i < 8; ++i)
        #pragma unroll
        for (int j = 0; j < 8; ++j) acc[i][j] = 0.f;
    for (int k0 = 0; k0 < ED; k0 += 16) {
        const bool full = (k0 + 16) <= ED;
        #pragma unroll
        for (int rep = 0; rep < 2; ++rep) {
            const int c = t + rep * 512;
            const float* bp = basis + (size_t)c * ED + k0;
            if (full) {
                const float4 v0 = *(const float4*)(bp + 0);
                const float4 v1 = *(const float4*)(bp + 4);
                const float4 v2 = *(const float4*)(bp + 8);
                const float4 v3 = *(const float4*)(bp + 12);
                blds[ 0*1024+c]=v0.x; blds[ 1*1024+c]=v0.y; blds[ 2*1024+c]=v0.z; blds[ 3*1024+c]=v0.w;
                blds[ 4*1024+c]=v1.x; blds[ 5*1024+c]=v1.y; blds[ 6*1024+c]=v1.z; blds[ 7*1024+c]=v1.w;
                blds[ 8*1024+c]=v2.x; blds[ 9*1024+c]=v2.y; blds[10*1024+c]=v2.z; blds[11*1024+c]=v2.w;
                blds[12*1024+c]=v3.x; blds[13*1024+c]=v3.y; blds[14*1024+c]=v3.z; blds[15*1024+c]=v3.w;
            } else {
                for (int kk = 0; kk < 16; ++kk)
                    blds[kk*1024 + c] = (k0 + kk < ED) ? bp[kk] : 0.f;
            }
        }
        if (t < 128) {
            const int row = t >> 2, kq = t & 3;
            const float* zp = Z + (size_t)(wr0 + row) * ED + k0 + 4 * kq;
            if (full) {
                const float4 v = *(const float4*)zp;
                zlds[(4*kq+0)*36 + row] = v.x;
                zlds[(4*kq+1)*36 + row] = v.y;
                zlds[(4*kq+2)*36 + row] = v.z;
                zlds[(4*kq+3)*36 + row] = v.w;
            } else {
                for (int j = 0; j < 4; ++j) {
                    const int k = k0 + 4*kq + j;
                    zlds[(4*kq+j)*36 + row] = (k < ED) ? zp[j] : 0.f;
                }
            }
        }
        __syncthreads();
        #pragma unroll
        for (int k = 0; k < 16; ++k) {
            const float4 z0 = *(const float4*)&zlds[k*36 + r0];
            const float4 z1 = *(const float4*)&zlds[k*36 + r0 + 4];
            const float4 b0 = *(const float4*)&blds[k*1024 + c0];
            const float4 b1 = *(const float4*)&blds[k*1024 + c1];
            const float zz[8] = {z0.x, z0.y, z0.z, z0.w, z1.x, z1.y, z1.z, z1.w};
            const float bb[8] = {b0.x, b0.y, b0.z, b0.w, b1.x, b1.y, b1.z, b1.w};
            #pragma unroll
            for (int i = 0; i < 8; ++i)
                #pragma unroll
                for (int j = 0; j < 8; ++j)
                    acc[i][j] = fmaf(zz[i], bb[j], acc[i][j]);
        }
        __syncthreads();
    }
    float* red_v    = blds;
    int*   red_i    = (int*)(blds + 4096);
    float* row_dmin = blds + 8192;
    float* row_s    = blds + 8224;
    float* pc       = blds + 8256;
    float bsqv[8], zsqv[8];
    #pragma unroll
    for (int j = 0; j < 4; ++j) { bsqv[j] = bsq[c0 + j]; bsqv[4 + j] = bsq[c1 + j]; }
    #pragma unroll
    for (int i = 0; i < 8; ++i) zsqv[i] = zsq[wr0 + r0 + i];
    #pragma unroll
    for (int i = 0; i < 8; ++i)
        #pragma unroll
        for (int j = 0; j < 8; ++j) {
            const float tv = zsqv[i] - 2.f * acc[i][j];
            acc[i][j] = tv + bsqv[j];
        }
    #pragma unroll
    for (int i = 0; i < 8; ++i) {
        float bv = acc[i][0]; int bi = c0;
        #pragma unroll
        for (int j = 1; j < 8; ++j) {
            const int c = (j < 4) ? (c0 + j) : (c1 + (j - 4));
            if (acc[i][j] < bv || (acc[i][j] == bv && c < bi)) { bv = acc[i][j]; bi = c; }
        }
        red_v[(r0 + i) * 128 + cg] = bv;
        red_i[(r0 + i) * 128 + cg] = bi;
    }
    __syncthreads();
    if (t < 32) {
        float bv = red_v[t * 128]; int bi = red_i[t * 128];
        for (int x = 1; x < 128; ++x) {
            const float v = red_v[t * 128 + x];
            const int  iv = red_i[t * 128 + x];
            if (v < bv || (v == bv && iv < bi)) { bv = v; bi = iv; }
        }
        row_dmin[t] = bv;
        idxws[wr0 + t] = bi;
        out[IDX_OFF + wr0 + t] = (float)bi;
    }
    __syncthreads();
    float su[8];
    #pragma unroll
    for (int i = 0; i < 8; ++i) {
        const float dm = row_dmin[r0 + i];
        float s = 0.f;
        #pragma unroll
        for (int j = 0; j < 8; ++j) {
            const float u = expf(dm - acc[i][j]);
            acc[i][j] = u;
            s += u;
        }
        su[i] = s;
    }
    #pragma unroll
    for (int i = 0; i < 8; ++i) red_v[(r0 + i) * 128 + cg] = su[i];
    __syncthreads();
    if (t < 32) {
        float s = 0.f;
        for (int x = 0; x < 128; ++x) s += red_v[t * 128 + x];
        row_s[t] = s;
    }
    __syncthreads();
    float rcp[8];
    #pragma unroll
    for (int i = 0; i < 8; ++i) rcp[i] = 1.f / row_s[r0 + i];
    pc[t] = 0.f; pc[t + 512] = 0.f;
    __syncthreads();
    #pragma unroll
    for (int j = 0; j < 8; ++j) {
        const int c = (j < 4) ? (c0 + j) : (c1 + (j - 4));
        float s = 0.f;
        #pragma unroll
        for (int i = 0; i < 8; ++i) s += acc[i][j] * rcp[i];
        atomicAdd(&pc[c], s);
    }
    __syncthreads();
    atomicAdd(&A[t],       pc[t]);
    atomicAdd(&A[t + 512], pc[t + 512]);
    if (t == 0) {
        float s = 0.f;
        for (int r = 0; r < 32; ++r) s += row_dmin[r];
        wgpart[bid] = s;
    }
}

__global__ void k_final(const float* __restrict__ wgpart, const float* __restrict__ A,
                        float* __restrict__ out) {
    __shared__ double sd[1024];
    const int t = threadIdx.x;
    sd[t] = (double)wgpart[t];
    __syncthreads();
    for (int off = 512; off > 0; off >>= 1) {
        if (t < off) sd[t] += sd[t + off];
        __syncthreads();
    }
    if (t == 0) out[VQ_OFF] = (float)(0.25 * sd[0] / 88473600.0);
    __syncthreads();
    const double p = (double)A[t] * (1.0 / 32768.0);
    sd[t] = -p * log(p + 1e-8);
    __syncthreads();
    for (int off = 512; off > 0; off >>= 1) {
        if (t < off) sd[t] += sd[t + off];
        __syncthreads();
    }
    if (t == 0) out[ENT_OFF] = (float)sd[0];
}

// =====================================================================

extern "C" void kernel_launch(void* const* d_in, const int* in_sizes, int n_in,
                              void* d_out, int out_size, void* d_ws, size_t ws_size,
                              hipStream_t stream) {
    const float* S     = (const float*)d_in[0];  // [32768, 256]
    const float* W     = (const float*)d_in[1];  // [2700, 256]
    const float* bproj = (const float*)d_in[2];  // [2700]
    const float* basis = (const float*)d_in[3];  // [1024, 2700]
    float* out = (float*)d_out;
    float* ws  = (float*)d_ws;

    // ws floats: 396800 small/planes + G 33554432 = 33,951,232 (~135.8 MB)
    const size_t NEED = (size_t)33951232 * sizeof(float);
    if (ws_size >= NEED) {
        // -------- MFMA path --------
        float* A        = ws;                 // 1024
        float* bsq      = ws + 1024;          // 1024
        float* wgpart   = ws + 2048;          // 1024
        int*   idxws    = (int*)(ws + 3072);  // 32768
        float* uv       = ws + 35840;         // 257 (pad 384)
        float* ydotpart = ws + 36224;         // 128
        float* cspart   = ws + 36352;         // 128*256 = 32768
        unsigned short* Ph = (unsigned short*)(ws + 69120);   // 1024*256 ush
        unsigned short* Pm = (unsigned short*)(ws + 200192);
        unsigned short* Mh = (unsigned short*)(ws + 331264);  // 256*256 ush
        unsigned short* Mm = (unsigned short*)(ws + 364032);
        float* G        = ws + 396800;        // 32768*1024
        // transients aliased into G (dead before k_gemm2 writes G)
        float* basisP = G;                    // 1024*2720 = 2785280
        float* WT     = G + 2785280;          // 256*2720  = 696320
        float* Pp     = G + 3481600;          // 5*262144  = 1310720
        float* Mp     = G + 4792320;          // 5*65536   = 327680
        // S planes live in q_st output region (dead before k_gather)
        unsigned short* Sh = (unsigned short*)out;            // 32768*256 ush
        unsigned short* Sm = Sh + (size_t)BKROWS * DM;

        hipMemsetAsync(A, 0, (size_t)NC * sizeof(float), stream);
        k_packS <<<BKROWS * DM / 1024, 256, 0, stream>>>(S, Sh, Sm);
        k_prepB <<<NC, 256, 0, stream>>>(basis, bproj, basisP, bsq);
        k_padWT <<<dim3(43, 4), 256, 0, stream>>>(W, WT);
        k_uv2   <<<257, 256, 0, stream>>>(WT, bproj, uv);
        k_colsum<<<128, 256, 0, stream>>>(S, cspart);
        k_gsplit<<<dim3(4, 16, 5), 256, 0, stream>>>(basisP, WT, Pp, 256);  // P partials
        k_gsplit<<<dim3(4, 4, 5),  256, 0, stream>>>(WT, WT, Mp, 256);      // M partials
        k_redP  <<<1024, 256, 0, stream>>>(Pp, Ph, Pm);
        k_redM2 <<<256, 256, 0, stream>>>(Mp, Mh, Mm);
        k_gemm2 <<<512, 512, 0, stream>>>(Sh, Sm, Ph, Pm, G);
        k_ydot  <<<128, 512, 0, stream>>>(Sh, Sm, Mh, Mm, S, ydotpart);
        k_post  <<<BKROWS / 32, 512, 0, stream>>>(G, bsq, A, wgpart, idxws, out);
        k_final2<<<1, 1024, 0, stream>>>(wgpart, A, ydotpart, cspart, uv, out);
        k_gather<<<BKROWS, 256, 0, stream>>>(basis, idxws, out);
    } else {
        // -------- fallback: round-2 f32 path --------
        float* zsqF    = ws;
        float* A       = ws + 32768;
        float* bsqF    = ws + 33792;
        float* wgpartF = ws + 34816;
        int*   idxwsF  = (int*)(ws + 35840);
        float* Z = out;
        hipMemsetAsync(A, 0, (size_t)NC * sizeof(float), stream);
        k_bsq   <<<NC, 256, 0, stream>>>(basis, bsqF);
        k_gemm1 <<<dim3(43, 512), 256, 0, stream>>>(S, W, bproj, Z);
        k_zsq   <<<BKROWS, 64, 0, stream>>>(Z, zsqF);
        k_dist  <<<BKROWS / 32, 512, 0, stream>>>(Z, basis, bsqF, zsqF, A, wgpartF, idxwsF, out);
        k_final <<<1, 1024, 0, stream>>>(wgpartF, A, out);
        k_gather<<<BKROWS, 256, 0, stream>>>(basis, idxwsF, out);
    }
}

// Round 14
// 326.104 us; speedup vs baseline: 1.6018x; 1.1274x over previous
//
#include <hip/hip_runtime.h>
#include <math.h>

#define ED 2700     // basis_dim
#define NC 1024     // num_codes
#define DM 256      // d_model
#define BKROWS 32768

#define IDX_OFF 88473600
#define VQ_OFF  88506368
#define ENT_OFF 88506369

#define KPAD 2720     // padded K for P/M small GEMMs (5 x 544)
#define K2CH 8        // gemm chunks (K=256 / 32)

typedef float  f32x4  __attribute__((ext_vector_type(4)));
typedef short  bf16x8 __attribute__((ext_vector_type(8)));

__device__ inline unsigned short f2bf(float x) {
    unsigned int u = __float_as_uint(x);
    unsigned int r = (u + 0x7FFFu + ((u >> 16) & 1u)) >> 16;
    return (unsigned short)r;
}
__device__ inline float bf2f(unsigned short h) {
    return __uint_as_float(((unsigned int)h) << 16);
}

// =====================================================================
// ============================ MFMA PATH ==============================
// =====================================================================

// ---- S -> Sh/Sm bf16 planes ----
__global__ __launch_bounds__(256)
void k_packS(const float* __restrict__ S, unsigned short* __restrict__ Sh,
             unsigned short* __restrict__ Sm) {
    const size_t i4 = (size_t)blockIdx.x * 256 + threadIdx.x;
    const float4 v = *(const float4*)(S + i4 * 4);
    ushort4 hv, mv;
    unsigned short* hp = (unsigned short*)&hv;
    unsigned short* mp = (unsigned short*)&mv;
    const float xs[4] = {v.x, v.y, v.z, v.w};
    #pragma unroll
    for (int j = 0; j < 4; ++j) {
        const unsigned short h = f2bf(xs[j]);
        hp[j] = h;
        mp[j] = f2bf(xs[j] - bf2f(h));
    }
    *(ushort4*)(Sh + i4 * 4) = hv;
    *(ushort4*)(Sm + i4 * 4) = mv;
}

// ---- merged prep: blocks 0..1023 prepB | 1024..1195 padWT | 1196..1452 uvW | 1453..1580 colsum ----
__global__ __launch_bounds__(256)
void k_prep1(const float* __restrict__ basis, const float* __restrict__ bproj,
             const float* __restrict__ W, const float* __restrict__ S,
             float* __restrict__ bP, float* __restrict__ bsq,
             float* __restrict__ WT, float* __restrict__ uv,
             float* __restrict__ cspart) {
    __shared__ double sdbuf[2080];   // 16640 B union
    const int b = blockIdx.x;
    const int t = threadIdx.x;

    if (b < 1024) {
        // -------- prepB: basisP copy + bsq' --------
        const int c = b;
        const float* row = basis + (size_t)c * ED;
        float* dst = bP + (size_t)c * KPAD;
        double s2 = 0.0, sp = 0.0;
        for (int j = t; j < ED; j += 256) {
            const float x = row[j];
            dst[j] = x;
            s2 += (double)x * (double)x;
            sp += (double)x * (double)bproj[j];
        }
        if (t < KPAD - ED) dst[ED + t] = 0.f;
        double* sd = sdbuf;
        sd[t] = s2; sd[256 + t] = sp;
        __syncthreads();
        for (int off = 128; off > 0; off >>= 1) {
            if (t < off) { sd[t] += sd[t + off]; sd[256 + t] += sd[256 + t + off]; }
            __syncthreads();
        }
        if (t == 0) bsq[c] = (float)(sd[0] - 2.0 * sd[256]);
    } else if (b < 1196) {
        // -------- padWT --------
        const int i  = b - 1024;
        const int e0 = (i >> 2) * 64;
        const int d0 = (i & 3) * 64;
        float (*tbuf)[65] = (float(*)[65])sdbuf;
        const int r  = t >> 2;
        const int q4 = t & 3;
        #pragma unroll
        for (int j = 0; j < 4; ++j) {
            const int col = q4 * 16 + j * 4;
            const int e = e0 + r;
            float4 v = make_float4(0.f, 0.f, 0.f, 0.f);
            if (e < ED) v = *(const float4*)(W + (size_t)e * DM + d0 + col);
            tbuf[r][col + 0] = v.x; tbuf[r][col + 1] = v.y;
            tbuf[r][col + 2] = v.z; tbuf[r][col + 3] = v.w;
        }
        __syncthreads();
        #pragma unroll
        for (int j = 0; j < 4; ++j) {
            const int col = q4 * 16 + j * 4;
            if (e0 + col < KPAD) {
                float4 o;
                o.x = tbuf[col + 0][r]; o.y = tbuf[col + 1][r];
                o.z = tbuf[col + 2][r]; o.w = tbuf[col + 3][r];
                *(float4*)(WT + (size_t)(d0 + r) * KPAD + e0 + col) = o;
            }
        }
    } else if (b < 1453) {
        // -------- uv: u[d] = W[:,d].bproj (direct, L2); block 256 = ||bproj||^2 --------
        const int bb = b - 1196;
        double s = 0.0;
        if (bb < 256) {
            for (int e = t; e < ED; e += 256)
                s += (double)W[(size_t)e * DM + bb] * (double)bproj[e];
        } else {
            for (int j = t; j < ED; j += 256) { const double x = bproj[j]; s += x * x; }
        }
        double* sd = sdbuf;
        sd[t] = s;
        __syncthreads();
        for (int off = 128; off > 0; off >>= 1) {
            if (t < off) sd[t] += sd[t + off];
            __syncthreads();
        }
        if (t == 0) uv[bb] = (float)sd[0];
    } else {
        // -------- colsum of S --------
        const int m0 = (b - 1453) * 256;
        double s = 0.0;
        for (int r = 0; r < 256; ++r) s += (double)S[(size_t)(m0 + r) * DM + t];
        cspart[(b - 1453) * 256 + t] = (float)s;
    }
}

// ---- merged gsplit: blocks 0..319 P-partials | 320..399 M-partials ----
__global__ __launch_bounds__(256)
void k_gsplitPM(const float* __restrict__ basisP, const float* __restrict__ WT,
                float* __restrict__ Pp, float* __restrict__ Mp) {
    const int b = blockIdx.x;
    const float* A;
    const float* B = WT;
    float* Cout;
    int n0, m0, k00, mtiles;
    if (b < 320) {
        const int kz = b / 64, rem = b % 64;
        A = basisP; mtiles = 16;
        m0 = (rem >> 2) * 64; n0 = (rem & 3) * 64; k00 = kz * 544;
        Cout = Pp + (size_t)kz * mtiles * 64 * 256;
    } else {
        const int j = b - 320;
        const int kz = j / 16, rem = j % 16;
        A = WT; mtiles = 4;
        m0 = (rem >> 2) * 64; n0 = (rem & 3) * 64; k00 = kz * 544;
        Cout = Mp + (size_t)kz * mtiles * 64 * 256;
    }
    const int t  = threadIdx.x;
    const int tx = t & 15, ty = t >> 4;

    __shared__ float alds[32 * 68];
    __shared__ float blds[32 * 68];

    float acc[4][4] = {};

    for (int k0 = k00; k0 < k00 + 544; k0 += 32) {
        #pragma unroll
        for (int rep = 0; rep < 2; ++rep) {
            const int id  = t + rep * 256;
            const int row = id >> 3, kq = id & 7;
            const float4 va = *(const float4*)(A + (size_t)(m0 + row) * KPAD + k0 + 4 * kq);
            alds[(4*kq+0)*68 + row] = va.x;
            alds[(4*kq+1)*68 + row] = va.y;
            alds[(4*kq+2)*68 + row] = va.z;
            alds[(4*kq+3)*68 + row] = va.w;
            const float4 vb = *(const float4*)(B + (size_t)(n0 + row) * KPAD + k0 + 4 * kq);
            blds[(4*kq+0)*68 + row] = vb.x;
            blds[(4*kq+1)*68 + row] = vb.y;
            blds[(4*kq+2)*68 + row] = vb.z;
            blds[(4*kq+3)*68 + row] = vb.w;
        }
        __syncthreads();
        #pragma unroll 8
        for (int k = 0; k < 32; ++k) {
            const float4 a = *(const float4*)&alds[k*68 + 4*ty];
            const float4 bb = *(const float4*)&blds[k*68 + 4*tx];
            const float av[4] = {a.x, a.y, a.z, a.w};
            const float bv[4] = {bb.x, bb.y, bb.z, bb.w};
            #pragma unroll
            for (int i = 0; i < 4; ++i)
                #pragma unroll
                for (int j = 0; j < 4; ++j)
                    acc[i][j] = fmaf(av[i], bv[j], acc[i][j]);
        }
        __syncthreads();
    }
    #pragma unroll
    for (int i = 0; i < 4; ++i) {
        float4 o; o.x = acc[i][0]; o.y = acc[i][1]; o.z = acc[i][2]; o.w = acc[i][3];
        *(float4*)(Cout + (size_t)(m0 + 4*ty + i) * 256 + n0 + 4*tx) = o;
    }
}

// ---- merged reduce: blocks 0..1023 P-planes | 1024..1279 M-planes ----
__global__ __launch_bounds__(256)
void k_redPM(const float* __restrict__ Pp, const float* __restrict__ Mp,
             unsigned short* __restrict__ Ph, unsigned short* __restrict__ Pm,
             unsigned short* __restrict__ Mh, unsigned short* __restrict__ Mm) {
    const int b = blockIdx.x;
    if (b < 1024) {
        const size_t idx = (size_t)b * 256 + threadIdx.x;
        float s = 0.f;
        #pragma unroll
        for (int k = 0; k < 5; ++k) s += Pp[(size_t)k * 262144 + idx];
        const unsigned short h = f2bf(s);
        Ph[idx] = h;
        Pm[idx] = f2bf(s - bf2f(h));
    } else {
        const size_t idx = (size_t)(b - 1024) * 256 + threadIdx.x;
        float s = 0.f;
        #pragma unroll
        for (int k = 0; k < 5; ++k) s += Mp[(size_t)k * 65536 + idx];
        const unsigned short h = f2bf(s);
        Mh[idx] = h;
        Mm[idx] = f2bf(s - bf2f(h));
    }
}

// ---- K2m: G = S.P^T, 256x256 tile, 8 waves, 4-phase counted-vmcnt, K=256 ----
__global__ __launch_bounds__(512, 2)
void k_gemm2(const unsigned short* __restrict__ Zh, const unsigned short* __restrict__ Zm,
             const unsigned short* __restrict__ Bh, const unsigned short* __restrict__ Bm,
             float* __restrict__ G) {
    __shared__ unsigned short lds[2 * 32768];

    const int bid  = blockIdx.x;
    const int xcd  = bid & 7, local = bid >> 3;
    const int mt   = xcd * 16 + (local >> 2);
    const int nt   = local & 3;
    const int m0   = mt * 256, n0 = nt * 256;
    const int tid  = threadIdx.x;
    const int w    = tid >> 6, l = tid & 63;
    const int wr   = (w >> 2) * 128;
    const int wc   = (w & 3) * 64;
    const int lrow = l & 15;
    const int lu   = l >> 4;

    const unsigned short* hsrc[4][2];
    int hlds[4][2];
    #pragma unroll
    for (int ht = 0; ht < 4; ++ht) {
        #pragma unroll
        for (int j = 0; j < 2; ++j) {
            const int slot = j * 512 + tid;
            const int rwh  = slot >> 3;
            const int unit = slot & 7;
            int row; bool isB;
            if (ht == 0)      { row = (rwh & 63) + (rwh >> 6) * 128;       isB = false; }
            else if (ht == 1) { row = 64 + (rwh & 63) + (rwh >> 6) * 128;  isB = false; }
            else if (ht == 2) { row = (rwh & 31) + (rwh >> 5) * 64;        isB = true;  }
            else              { row = 32 + (rwh & 31) + (rwh >> 5) * 64;   isB = true;  }
            const int sg   = unit ^ (row & 7);
            const int pl   = sg >> 2;
            const int koff = (sg & 3) * 8;
            if (!isB) hsrc[ht][j] = (pl ? Zm : Zh) + (size_t)(m0 + row) * DM + koff;
            else      hsrc[ht][j] = (pl ? Bm : Bh) + (size_t)(n0 + row) * DM + koff;
            hlds[ht][j] = (isB ? 16384 : 0) + row * 64 + unit * 8;
        }
    }

    f32x4 acc[8][4];
    #pragma unroll
    for (int i = 0; i < 8; ++i)
        #pragma unroll
        for (int j = 0; j < 4; ++j) acc[i][j] = (f32x4){0.f, 0.f, 0.f, 0.f};

    #define STAGE_HALF(ht, ck, db) { \
        _Pragma("unroll") \
        for (int j = 0; j < 2; ++j) \
            __builtin_amdgcn_global_load_lds( \
                (const __attribute__((address_space(1))) unsigned int*)(const void*)(hsrc[ht][j] + (ck) * 32), \
                (__attribute__((address_space(3))) unsigned int*)(void*)&lds[(db) * 32768 + hlds[ht][j]], \
                16, 0, 0); \
    }

    #define LOAD_A(db, qm) { \
        const unsigned short* At = &lds[(db) * 32768]; \
        _Pragma("unroll") \
        for (int f = 0; f < 4; ++f) { \
            const int row = wr + ((qm) * 4 + f) * 16 + lrow; \
            ah[f] = *(const bf16x8*)(At + row * 64 + (((0 + lu) ^ (row & 7))) * 8); \
            am[f] = *(const bf16x8*)(At + row * 64 + (((4 + lu) ^ (row & 7))) * 8); \
        } \
    }
    #define LOAD_B(db, qn) { \
        const unsigned short* Bt = &lds[(db) * 32768 + 16384]; \
        _Pragma("unroll") \
        for (int f = 0; f < 2; ++f) { \
            const int col = wc + ((qn) * 2 + f) * 16 + lrow; \
            bh[f] = *(const bf16x8*)(Bt + col * 64 + (((0 + lu) ^ (col & 7))) * 8); \
            bm[f] = *(const bf16x8*)(Bt + col * 64 + (((4 + lu) ^ (col & 7))) * 8); \
        } \
    }
    #define MFMA_Q(qm, qn) { \
        __builtin_amdgcn_s_setprio(1); \
        _Pragma("unroll") \
        for (int i = 0; i < 4; ++i) \
            _Pragma("unroll") \
            for (int j = 0; j < 2; ++j) { \
                f32x4 cc = acc[(qm) * 4 + i][(qn) * 2 + j]; \
                cc = __builtin_amdgcn_mfma_f32_16x16x32_bf16(ah[i], bh[j], cc, 0, 0, 0); \
                cc = __builtin_amdgcn_mfma_f32_16x16x32_bf16(ah[i], bm[j], cc, 0, 0, 0); \
                cc = __builtin_amdgcn_mfma_f32_16x16x32_bf16(am[i], bh[j], cc, 0, 0, 0); \
                acc[(qm) * 4 + i][(qn) * 2 + j] = cc; \
            } \
        __builtin_amdgcn_s_setprio(0); \
    }
    #define VM8  asm volatile("s_waitcnt vmcnt(8)" ::: "memory");
    #define BAR  __builtin_amdgcn_s_barrier();

    STAGE_HALF(0, 0, 0) STAGE_HALF(2, 0, 0) STAGE_HALF(3, 0, 0) STAGE_HALF(1, 0, 0)
    STAGE_HALF(0, 1, 1) STAGE_HALF(2, 1, 1)
    VM8
    BAR

    for (int c = 0; c < K2CH - 2; ++c) {
        const int cb = c & 1, ob = cb ^ 1;
        bf16x8 ah[4], am[4], bh[2], bm[2];
        LOAD_A(cb, 0) LOAD_B(cb, 0)
        STAGE_HALF(3, c + 1, ob)
        BAR
        MFMA_Q(0, 0)
        VM8
        BAR
        LOAD_B(cb, 1)
        STAGE_HALF(1, c + 1, ob)
        BAR
        MFMA_Q(0, 1)
        VM8
        BAR
        LOAD_A(cb, 1) LOAD_B(cb, 0)
        STAGE_HALF(0, c + 2, cb)
        BAR
        MFMA_Q(1, 0)
        BAR
        LOAD_B(cb, 1)
        STAGE_HALF(2, c + 2, cb)
        BAR
        MFMA_Q(1, 1)
        VM8
        BAR
    }

    STAGE_HALF(3, K2CH - 1, (K2CH - 1) & 1) STAGE_HALF(1, K2CH - 1, (K2CH - 1) & 1)
    asm volatile("s_waitcnt vmcnt(0)" ::: "memory");
    BAR
    #pragma unroll
    for (int e = 0; e < 2; ++e) {
        const int cb = (K2CH - 2 + e) & 1;
        bf16x8 ah[4], am[4], bh[2], bm[2];
        LOAD_A(cb, 0) LOAD_B(cb, 0)
        MFMA_Q(0, 0)
        LOAD_B(cb, 1)
        MFMA_Q(0, 1)
        LOAD_A(cb, 1) LOAD_B(cb, 0)
        MFMA_Q(1, 0)
        LOAD_B(cb, 1)
        MFMA_Q(1, 1)
    }

    // C layout: col = lane&15, row = (lane>>4)*4 + reg
    #pragma unroll
    for (int fm = 0; fm < 8; ++fm)
        #pragma unroll
        for (int fn = 0; fn < 4; ++fn) {
            const int col = n0 + wc + fn * 16 + lrow;
            #pragma unroll
            for (int r = 0; r < 4; ++r) {
                const int row = m0 + wr + fm * 16 + lu * 4 + r;
                G[(size_t)row * NC + col] = acc[fm][fn][r];
            }
        }
}

// ---- k_ydot: ydotpart[b] = <(S.M^T)_tile, S_tile> (same proven core; grid 128) ----
__global__ __launch_bounds__(512, 2)
void k_ydot(const unsigned short* __restrict__ Zh, const unsigned short* __restrict__ Zm,
            const unsigned short* __restrict__ Bh, const unsigned short* __restrict__ Bm,
            const float* __restrict__ S, float* __restrict__ ydotpart) {
    __shared__ unsigned short lds[2 * 32768];

    const int bid  = blockIdx.x;
    const int xcd  = bid & 7, local = bid >> 3;
    const int mt   = xcd * 16 + local;
    const int m0   = mt * 256, n0 = 0;
    const int tid  = threadIdx.x;
    const int w    = tid >> 6, l = tid & 63;
    const int wr   = (w >> 2) * 128;
    const int wc   = (w & 3) * 64;
    const int lrow = l & 15;
    const int lu   = l >> 4;

    const unsigned short* hsrc[4][2];
    int hlds[4][2];
    #pragma unroll
    for (int ht = 0; ht < 4; ++ht) {
        #pragma unroll
        for (int j = 0; j < 2; ++j) {
            const int slot = j * 512 + tid;
            const int rwh  = slot >> 3;
            const int unit = slot & 7;
            int row; bool isB;
            if (ht == 0)      { row = (rwh & 63) + (rwh >> 6) * 128;       isB = false; }
            else if (ht == 1) { row = 64 + (rwh & 63) + (rwh >> 6) * 128;  isB = false; }
            else if (ht == 2) { row = (rwh & 31) + (rwh >> 5) * 64;        isB = true;  }
            else              { row = 32 + (rwh & 31) + (rwh >> 5) * 64;   isB = true;  }
            const int sg   = unit ^ (row & 7);
            const int pl   = sg >> 2;
            const int koff = (sg & 3) * 8;
            if (!isB) hsrc[ht][j] = (pl ? Zm : Zh) + (size_t)(m0 + row) * DM + koff;
            else      hsrc[ht][j] = (pl ? Bm : Bh) + (size_t)(n0 + row) * DM + koff;
            hlds[ht][j] = (isB ? 16384 : 0) + row * 64 + unit * 8;
        }
    }

    f32x4 acc[8][4];
    #pragma unroll
    for (int i = 0; i < 8; ++i)
        #pragma unroll
        for (int j = 0; j < 4; ++j) acc[i][j] = (f32x4){0.f, 0.f, 0.f, 0.f};

    STAGE_HALF(0, 0, 0) STAGE_HALF(2, 0, 0) STAGE_HALF(3, 0, 0) STAGE_HALF(1, 0, 0)
    STAGE_HALF(0, 1, 1) STAGE_HALF(2, 1, 1)
    VM8
    BAR

    for (int c = 0; c < K2CH - 2; ++c) {
        const int cb = c & 1, ob = cb ^ 1;
        bf16x8 ah[4], am[4], bh[2], bm[2];
        LOAD_A(cb, 0) LOAD_B(cb, 0)
        STAGE_HALF(3, c + 1, ob)
        BAR
        MFMA_Q(0, 0)
        VM8
        BAR
        LOAD_B(cb, 1)
        STAGE_HALF(1, c + 1, ob)
        BAR
        MFMA_Q(0, 1)
        VM8
        BAR
        LOAD_A(cb, 1) LOAD_B(cb, 0)
        STAGE_HALF(0, c + 2, cb)
        BAR
        MFMA_Q(1, 0)
        BAR
        LOAD_B(cb, 1)
        STAGE_HALF(2, c + 2, cb)
        BAR
        MFMA_Q(1, 1)
        VM8
        BAR
    }

    STAGE_HALF(3, K2CH - 1, (K2CH - 1) & 1) STAGE_HALF(1, K2CH - 1, (K2CH - 1) & 1)
    asm volatile("s_waitcnt vmcnt(0)" ::: "memory");
    BAR
    #pragma unroll
    for (int e = 0; e < 2; ++e) {
        const int cb = (K2CH - 2 + e) & 1;
        bf16x8 ah[4], am[4], bh[2], bm[2];
        LOAD_A(cb, 0) LOAD_B(cb, 0)
        MFMA_Q(0, 0)
        LOAD_B(cb, 1)
        MFMA_Q(0, 1)
        LOAD_A(cb, 1) LOAD_B(cb, 0)
        MFMA_Q(1, 0)
        LOAD_B(cb, 1)
        MFMA_Q(1, 1)
    }
    #undef STAGE_HALF
    #undef LOAD_A
    #undef LOAD_B
    #undef MFMA_Q
    #undef VM8
    #undef BAR

    float part = 0.f;
    #pragma unroll
    for (int fm = 0; fm < 8; ++fm)
        #pragma unroll
        for (int fn = 0; fn < 4; ++fn) {
            const int col = wc + fn * 16 + lrow;
            #pragma unroll
            for (int r = 0; r < 4; ++r) {
                const int row = m0 + wr + fm * 16 + lu * 4 + r;
                part += acc[fm][fn][r] * S[(size_t)row * DM + col];
            }
        }
    __syncthreads();
    float* red = (float*)lds;
    red[tid] = part;
    __syncthreads();
    for (int off = 256; off > 0; off >>= 1) {
        if (tid < off) red[tid] += red[tid + off];
        __syncthreads();
    }
    if (tid == 0) ydotpart[bid] = red[0];
}

// ---- k_postg: dist' = bsq' - 2G + argmin/softmax/avg_prob + FUSED gather ----
__global__ __launch_bounds__(512)
void k_postg(const float* __restrict__ G, const float* __restrict__ bsq,
             const float* __restrict__ basis, float* __restrict__ A,
             float* __restrict__ wgpart, float* __restrict__ out) {
    const int bid = blockIdx.x;
    const int wr0 = bid * 32;
    const int t   = threadIdx.x;
    const int cg  = t & 127;
    const int rq  = t >> 7;
    const int r0  = rq * 8;
    const int c0  = cg * 4;
    const int c1  = 512 + cg * 4;

    __shared__ float sm[9312];
    float* red_v    = sm;                 // [32][128]
    int*   red_i    = (int*)(sm + 4096);  // [32][128]
    float* row_dmin = sm + 8192;          // [32]
    float* row_s    = sm + 8224;          // [32]
    int*   idxsh    = (int*)(sm + 8256);  // [32]
    float* pc       = sm + 8288;          // [1024]

    float acc[8][8];
    #pragma unroll
    for (int i = 0; i < 8; ++i) {
        const float4 g0 = *(const float4*)&G[(size_t)(wr0 + r0 + i) * NC + c0];
        const float4 g1 = *(const float4*)&G[(size_t)(wr0 + r0 + i) * NC + c1];
        acc[i][0] = g0.x; acc[i][1] = g0.y; acc[i][2] = g0.z; acc[i][3] = g0.w;
        acc[i][4] = g1.x; acc[i][5] = g1.y; acc[i][6] = g1.z; acc[i][7] = g1.w;
    }

    float bsqv[8];
    #pragma unroll
    for (int j = 0; j < 4; ++j) { bsqv[j] = bsq[c0 + j]; bsqv[4 + j] = bsq[c1 + j]; }

    #pragma unroll
    for (int i = 0; i < 8; ++i)
        #pragma unroll
        for (int j = 0; j < 8; ++j)
            acc[i][j] = bsqv[j] - 2.f * acc[i][j];

    #pragma unroll
    for (int i = 0; i < 8; ++i) {
        float bv = acc[i][0]; int bi = c0;
        #pragma unroll
        for (int j = 1; j < 8; ++j) {
            const int c = (j < 4) ? (c0 + j) : (c1 + (j - 4));
            if (acc[i][j] < bv || (acc[i][j] == bv && c < bi)) { bv = acc[i][j]; bi = c; }
        }
        red_v[(r0 + i) * 128 + cg] = bv;
        red_i[(r0 + i) * 128 + cg] = bi;
    }
    __syncthreads();
    if (t < 32) {
        float bv = red_v[t * 128]; int bi = red_i[t * 128];
        for (int x = 1; x < 128; ++x) {
            const float v = red_v[t * 128 + x];
            const int  iv = red_i[t * 128 + x];
            if (v < bv || (v == bv && iv < bi)) { bv = v; bi = iv; }
        }
        row_dmin[t] = bv;
        idxsh[t] = bi;
        out[IDX_OFF + wr0 + t] = (float)bi;
    }
    __syncthreads();

    float su[8];
    #pragma unroll
    for (int i = 0; i < 8; ++i) {
        const float dm = row_dmin[r0 + i];
        float s = 0.f;
        #pragma unroll
        for (int j = 0; j < 8; ++j) {
            const float u = expf(dm - acc[i][j]);
            acc[i][j] = u;
            s += u;
        }
        su[i] = s;
    }
    #pragma unroll
    for (int i = 0; i < 8; ++i) red_v[(r0 + i) * 128 + cg] = su[i];
    __syncthreads();
    if (t < 32) {
        float s = 0.f;
        for (int x = 0; x < 128; ++x) s += red_v[t * 128 + x];
        row_s[t] = s;
    }
    __syncthreads();

    float rcp[8];
    #pragma unroll
    for (int i = 0; i < 8; ++i) rcp[i] = 1.f / row_s[r0 + i];

    pc[t] = 0.f; pc[t + 512] = 0.f;
    __syncthreads();
    #pragma unroll
    for (int j = 0; j < 8; ++j) {
        const int c = (j < 4) ? (c0 + j) : (c1 + (j - 4));
        float s = 0.f;
        #pragma unroll
        for (int i = 0; i < 8; ++i) s += acc[i][j] * rcp[i];
        atomicAdd(&pc[c], s);
    }
    __syncthreads();
    atomicAdd(&A[t],       pc[t]);
    atomicAdd(&A[t + 512], pc[t + 512]);

    if (t == 0) {
        float s = 0.f;
        for (int r = 0; r < 32; ++r) s += row_dmin[r];
        wgpart[bid] = s;
    }

    // ---- fused gather: q_st rows (Sh/Sm in out are dead: gemm2/ydot done) ----
    for (int r = 0; r < 32; ++r) {
        const int idx = idxsh[r];
        const float4* src = (const float4*)(basis + (size_t)idx * ED);
        float4* dst = (float4*)(out + (size_t)(wr0 + r) * ED);
        for (int j = t; j < ED / 4; j += 512) dst[j] = src[j];
    }
}

// ---- finalize scalars ----
__global__ void k_final2(const float* __restrict__ wgpart, const float* __restrict__ Aq,
                         const float* __restrict__ ydotpart, const float* __restrict__ cspart,
                         const float* __restrict__ uv, float* __restrict__ out) {
    __shared__ double sd[1024];
    const int t = threadIdx.x;
    sd[t] = (double)wgpart[t];
    __syncthreads();
    for (int off = 512; off > 0; off >>= 1) {
        if (t < off) sd[t] += sd[t + off];
        __syncthreads();
    }
    const double smin = sd[0];
    __syncthreads();
    sd[t] = (t < 128) ? (double)ydotpart[t] : 0.0;
    __syncthreads();
    for (int off = 512; off > 0; off >>= 1) {
        if (t < off) sd[t] += sd[t + off];
        __syncthreads();
    }
    const double sy = sd[0];
    __syncthreads();
    double cu = 0.0;
    if (t < 256) {
        double cs = 0.0;
        for (int b = 0; b < 128; ++b) cs += (double)cspart[b * 256 + t];
        cu = cs * (double)uv[t];
    }
    sd[t] = cu;
    __syncthreads();
    for (int off = 512; off > 0; off >>= 1) {
        if (t < off) sd[t] += sd[t + off];
        __syncthreads();
    }
    if (t == 0) {
        const double szsq = sy + 2.0 * sd[0] + 32768.0 * (double)uv[256];
        out[VQ_OFF] = (float)(0.25 * (smin + szsq) / 88473600.0);
    }
    __syncthreads();
    const double p = (double)Aq[t] * (1.0 / 32768.0);
    sd[t] = -p * log(p + 1e-8);
    __syncthreads();
    for (int off = 512; off > 0; off >>= 1) {
        if (t < off) sd[t] += sd[t + off];
        __syncthreads();
    }
    if (t == 0) out[ENT_OFF] = (float)sd[0];
}

// ---- q_st = basis[indices] (fallback path only) ----
__global__ void k_gather(const float* __restrict__ basis, const int* __restrict__ idxws,
                         float* __restrict__ out) {
    const int r = blockIdx.x;
    const int idx = idxws[r];
    const float4* src = (const float4*)(basis + (size_t)idx * ED);
    float4* dst = (float4*)(out + (size_t)r * ED);
    for (int j = threadIdx.x; j < ED / 4; j += 256) dst[j] = src[j];
}

// =====================================================================
// ===================== FALLBACK (round-2, f32 VALU) ==================
// =====================================================================

__global__ void k_bsq(const float* __restrict__ basis, float* __restrict__ bsq) {
    int c = blockIdx.x;
    const float* row = basis + (size_t)c * ED;
    double s = 0.0;
    for (int j = threadIdx.x; j < ED; j += 256) { float v = row[j]; s += (double)v * (double)v; }
    __shared__ double sd[256];
    sd[threadIdx.x] = s;
    __syncthreads();
    for (int off = 128; off > 0; off >>= 1) {
        if (threadIdx.x < off) sd[threadIdx.x] += sd[threadIdx.x + off];
        __syncthreads();
    }
    if (threadIdx.x == 0) bsq[c] = (float)sd[0];
}

__global__ __launch_bounds__(256, 4)
void k_gemm1(const float* __restrict__ S, const float* __restrict__ W,
             const float* __restrict__ bproj, float* __restrict__ Z) {
    const int e0 = blockIdx.x * 64;
    const int m0 = blockIdx.y * 64;
    const int t  = threadIdx.x;
    const int tx = t & 15, ty = t >> 4;
    __shared__ float alds[32 * 68];
    __shared__ float blds[32 * 68];
    float acc[4][4] = {};
    for (int k0 = 0; k0 < DM; k0 += 32) {
        #pragma unroll
        for (int rep = 0; rep < 2; ++rep) {
            const int id  = t + rep * 256;
            const int row = id >> 3, kq = id & 7;
            const float4 va = *(const float4*)(S + (size_t)(m0 + row) * DM + k0 + 4 * kq);
            alds[(4*kq+0)*68 + row] = va.x;
            alds[(4*kq+1)*68 + row] = va.y;
            alds[(4*kq+2)*68 + row] = va.z;
            alds[(4*kq+3)*68 + row] = va.w;
            float4 vb = make_float4(0.f, 0.f, 0.f, 0.f);
            if (e0 + row < ED)
                vb = *(const float4*)(W + (size_t)(e0 + row) * DM + k0 + 4 * kq);
            blds[(4*kq+0)*68 + row] = vb.x;
            blds[(4*kq+1)*68 + row] = vb.y;
            blds[(4*kq+2)*68 + row] = vb.z;
            blds[(4*kq+3)*68 + row] = vb.w;
        }
        __syncthreads();
        #pragma unroll 8
        for (int k = 0; k < 32; ++k) {
            const float4 a = *(const float4*)&alds[k*68 + 4*ty];
            const float4 b = *(const float4*)&blds[k*68 + 4*tx];
            const float av[4] = {a.x, a.y, a.z, a.w};
            const float bv[4] = {b.x, b.y, b.z, b.w};
            #pragma unroll
            for (int i = 0; i < 4; ++i)
                #pragma unroll
                for (int j = 0; j < 4; ++j)
                    acc[i][j] = fmaf(av[i], bv[j], acc[i][j]);
        }
        __syncthreads();
    }
    const bool valid = (e0 + 4*tx + 4) <= ED;
    float4 bias = make_float4(0.f, 0.f, 0.f, 0.f);
    if (valid) bias = *(const float4*)(bproj + e0 + 4*tx);
    #pragma unroll
    for (int i = 0; i < 4; ++i) {
        if (valid) {
            float4 o;
            o.x = acc[i][0] + bias.x;
            o.y = acc[i][1] + bias.y;
            o.z = acc[i][2] + bias.z;
            o.w = acc[i][3] + bias.w;
            *(float4*)(Z + (size_t)(m0 + 4*ty + i) * ED + e0 + 4*tx) = o;
        }
    }
}

__global__ __launch_bounds__(64)
void k_zsq(const float* __restrict__ Z, float* __restrict__ zsq) {
    const int r = blockIdx.x;
    const float4* row4 = (const float4*)(Z + (size_t)r * ED);
    double s = 0.0;
    for (int q = threadIdx.x; q < ED / 4; q += 64) {
        const float4 v = row4[q];
        s += (double)v.x * v.x + (double)v.y * v.y + (double)v.z * v.z + (double)v.w * v.w;
    }
    #pragma unroll
    for (int off = 32; off > 0; off >>= 1) s += __shfl_down(s, off);
    if (threadIdx.x == 0) zsq[r] = (float)s;
}

__global__ __launch_bounds__(512, 2)
void k_dist(const float* __restrict__ Z, const float* __restrict__ basis,
            const float* __restrict__ bsq, const float* __restrict__ zsq,
            float* __restrict__ A, float* __restrict__ wgpart,
            int* __restrict__ idxws, float* __restrict__ out) {
    const int bid = blockIdx.x;
    const int wr0 = bid * 32;
    const int t   = threadIdx.x;
    const int cg  = t & 127;
    const int rq  = t >> 7;
    const int r0  = rq * 8;
    const int c0  = cg * 4;
    const int c1  = 512 + cg * 4;
    __shared__ float blds[16 * 1024];
    __shared__ float zlds[16 * 36];
    float acc[8][8];
    #pragma unroll
    for (int i = 0; i < 8; ++i)
        #pragma unroll
        for (int j = 0; j < 8; ++j) acc[i][j] = 0.f;
    for (int k0 = 0; k0 < ED; k0 += 16) {
        const bool full = (k0 + 16) <= ED;
        #pragma unroll
        for (int rep = 0; rep < 2; ++rep) {
            const int c = t + rep * 512;
            const float* bp = basis + (size_t)c * ED + k0;
            if (full) {
                const float4 v0 = *(const float4*)(bp + 0);
                const float4 v1 = *(const float4*)(bp + 4);
                const float4 v2 = *(const float4*)(bp + 8);
                const float4 v3 = *(const float4*)(bp + 12);
                blds[ 0*1024+c]=v0.x; blds[ 1*1024+c]=v0.y; blds[ 2*1024+c]=v0.z; blds[ 3*1024+c]=v0.w;
                blds[ 4*1024+c]=v1.x; blds[ 5*1024+c]=v1.y; blds[ 6*1024+c]=v1.z; blds[ 7*1024+c]=v1.w;
                blds[ 8*1024+c]=v2.x; blds[ 9*1024+c]=v2.y; blds[10*1024+c]=v2.z; blds[11*1024+c]=v2.w;
                blds[12*1024+c]=v3.x; blds[13*1024+c]=v3.y; blds[14*1024+c]=v3.z; blds[15*1024+c]=v3.w;
            } else {
                for (int kk = 0; kk < 16; ++kk)
                    blds[kk*1024 + c] = (k0 + kk < ED) ? bp[kk] : 0.f;
            }
        }
        if (t < 128) {
            const int row = t >> 2, kq = t & 3;
            const float* zp = Z + (size_t)(wr0 + row) * ED + k0 + 4 * kq;
            if (full) {
                const float4 v = *(const float4*)zp;
                zlds[(4*kq+0)*36 + row] = v.x;
                zlds[(4*kq+1)*36 + row] = v.y;
                zlds[(4*kq+2)*36 + row] = v.z;
                zlds[(4*kq+3)*36 + row] = v.w;
            } else {
                for (int j = 0; j < 4; ++j) {
                    const int k = k0 + 4*kq + j;
                    zlds[(4*kq+j)*36 + row] = (k < ED) ? zp[j] : 0.f;
                }
            }
        }
        __syncthreads();
        #pragma unroll
        for (int k = 0; k < 16; ++k) {
            const float4 z0 = *(const float4*)&zlds[k*36 + r0];
            const float4 z1 = *(const float4*)&zlds[k*36 + r0 + 4];
            const float4 b0 = *(const float4*)&blds[k*1024 + c0];
            const float4 b1 = *(const float4*)&blds[k*1024 + c1];
            const float zz[8] = {z0.x, z0.y, z0.z, z0.w, z1.x, z1.y, z1.z, z1.w};
            const float bb[8] = {b0.x, b0.y, b0.z, b0.w, b1.x, b1.y, b1.z, b1.w};
            #pragma unroll
            for (int i = 0; i < 8; ++i)
                #pragma unroll
                for (int j = 0; j < 8; ++j)
                    acc[i][j] = fmaf(zz[i], bb[j], acc[i][j]);
        }
        __syncthreads();
    }
    float* red_v    = blds;
    int*   red_i    = (int*)(blds + 4096);
    float* row_dmin = blds + 8192;
    float* row_s    = blds + 8224;
    float* pc       = blds + 8256;
    float bsqv[8], zsqv[8];
    #pragma unroll
    for (int j = 0; j < 4; ++j) { bsqv[j] = bsq[c0 + j]; bsqv[4 + j] = bsq[c1 + j]; }
    #pragma unroll
    for (int i = 0; i < 8; ++i) zsqv[i] = zsq[wr0 + r0 + i];
    #pragma unroll
    for (int i = 0; i < 8; ++i)
        #pragma unroll
        for (int j = 0; j < 8; ++j) {
            const float tv = zsqv[i] - 2.f * acc[i][j];
            acc[i][j] = tv + bsqv[j];
        }
    #pragma unroll
    for (int i = 0; i < 8; ++i) {
        float bv = acc[i][0]; int bi = c0;
        #pragma unroll
        for (int j = 1; j < 8; ++j) {
            const int c = (j < 4) ? (c0 + j) : (c1 + (j - 4));
            if (acc[i][j] < bv || (acc[i][j] == bv && c < bi)) { bv = acc[i][j]; bi = c; }
        }
        red_v[(r0 + i) * 128 + cg] = bv;
        red_i[(r0 + i) * 128 + cg] = bi;
    }
    __syncthreads();
    if (t < 32) {
        float bv = red_v[t * 128]; int bi = red_i[t * 128];
        for (int x = 1; x < 128; ++x) {
            const float v = red_v[t * 128 + x];
            const int  iv = red_i[t * 128 + x];
            if (v < bv || (v == bv && iv < bi)) { bv = v; bi = iv; }
        }
        row_dmin[t] = bv;
        idxws[wr0 + t] = bi;
        out[IDX_OFF + wr0 + t] = (float)bi;
    }
    __syncthreads();
    float su[8];
    #pragma unroll
    for (int i = 0; i < 8; ++i) {
        const float dm = row_dmin[r0 + i];
        float s = 0.f;
        #pragma unroll
        for (int j = 0; j < 8; ++j) {
            const float u = expf(dm - acc[i][j]);
            acc[i][j] = u;
            s += u;
        }
        su[i] = s;
    }
    #pragma unroll
    for (int i = 0; i < 8; ++i) red_v[(r0 + i) * 128 + cg] = su[i];
    __syncthreads();
    if (t < 32) {
        float s = 0.f;
        for (int x = 0; x < 128; ++x) s += red_v[t * 128 + x];
        row_s[t] = s;
    }
    __syncthreads();
    float rcp[8];
    #pragma unroll
    for (int i = 0; i < 8; ++i) rcp[i] = 1.f / row_s[r0 + i];
    pc[t] = 0.f; pc[t + 512] = 0.f;
    __syncthreads();
    #pragma unroll
    for (int j = 0; j < 8; ++j) {
        const int c = (j < 4) ? (c0 + j) : (c1 + (j - 4));
        float s = 0.f;
        #pragma unroll
        for (int i = 0; i < 8; ++i) s += acc[i][j] * rcp[i];
        atomicAdd(&pc[c], s);
    }
    __syncthreads();
    atomicAdd(&A[t],       pc[t]);
    atomicAdd(&A[t + 512], pc[t + 512]);
    if (t == 0) {
        float s = 0.f;
        for (int r = 0; r < 32; ++r) s += row_dmin[r];
        wgpart[bid] = s;
    }
}

__global__ void k_final(const float* __restrict__ wgpart, const float* __restrict__ A,
                        float* __restrict__ out) {
    __shared__ double sd[1024];
    const int t = threadIdx.x;
    sd[t] = (double)wgpart[t];
    __syncthreads();
    for (int off = 512; off > 0; off >>= 1) {
        if (t < off) sd[t] += sd[t + off];
        __syncthreads();
    }
    if (t == 0) out[VQ_OFF] = (float)(0.25 * sd[0] / 88473600.0);
    __syncthreads();
    const double p = (double)A[t] * (1.0 / 32768.0);
    sd[t] = -p * log(p + 1e-8);
    __syncthreads();
    for (int off = 512; off > 0; off >>= 1) {
        if (t < off) sd[t] += sd[t + off];
        __syncthreads();
    }
    if (t == 0) out[ENT_OFF] = (float)sd[0];
}

// =====================================================================

extern "C" void kernel_launch(void* const* d_in, const int* in_sizes, int n_in,
                              void* d_out, int out_size, void* d_ws, size_t ws_size,
                              hipStream_t stream) {
    const float* S     = (const float*)d_in[0];  // [32768, 256]
    const float* W     = (const float*)d_in[1];  // [2700, 256]
    const float* bproj = (const float*)d_in[2];  // [2700]
    const float* basis = (const float*)d_in[3];  // [1024, 2700]
    float* out = (float*)d_out;
    float* ws  = (float*)d_ws;

    const size_t NEED = (size_t)33951232 * sizeof(float);   // ~135.8 MB
    if (ws_size >= NEED) {
        // -------- MFMA path --------
        float* A        = ws;                 // 1024
        float* bsq      = ws + 1024;          // 1024
        float* wgpart   = ws + 2048;          // 1024
        float* uv       = ws + 35840;         // 257 (pad 384)
        float* ydotpart = ws + 36224;         // 128
        float* cspart   = ws + 36352;         // 128*256 = 32768
        unsigned short* Ph = (unsigned short*)(ws + 69120);   // 1024*256 ush
        unsigned short* Pm = (unsigned short*)(ws + 200192);
        unsigned short* Mh = (unsigned short*)(ws + 331264);  // 256*256 ush
        unsigned short* Mm = (unsigned short*)(ws + 364032);
        float* G        = ws + 396800;        // 32768*1024
        // transients aliased into G (dead before k_gemm2 writes G)
        float* basisP = G;                    // 1024*2720 = 2785280
        float* WT     = G + 2785280;          // 256*2720  = 696320
        float* Pp     = G + 3481600;          // 5*262144  = 1310720
        float* Mp     = G + 4792320;          // 5*65536   = 327680
        // S planes live in q_st output region (dead before k_postg gathers)
        unsigned short* Sh = (unsigned short*)out;            // 32768*256 ush
        unsigned short* Sm = Sh + (size_t)BKROWS * DM;

        hipMemsetAsync(A, 0, (size_t)NC * sizeof(float), stream);
        k_packS   <<<BKROWS * DM / 1024, 256, 0, stream>>>(S, Sh, Sm);
        k_prep1   <<<1581, 256, 0, stream>>>(basis, bproj, W, S, basisP, bsq, WT, uv, cspart);
        k_gsplitPM<<<400, 256, 0, stream>>>(basisP, WT, Pp, Mp);
        k_redPM   <<<1280, 256, 0, stream>>>(Pp, Mp, Ph, Pm, Mh, Mm);
        k_gemm2   <<<512, 512, 0, stream>>>(Sh, Sm, Ph, Pm, G);
        k_ydot    <<<128, 512, 0, stream>>>(Sh, Sm, Mh, Mm, S, ydotpart);
        k_postg   <<<BKROWS / 32, 512, 0, stream>>>(G, bsq, basis, A, wgpart, out);
        k_final2  <<<1, 1024, 0, stream>>>(wgpart, A, ydotpart, cspart, uv, out);
    } else {
        // -------- fallback: round-2 f32 path --------
        float* zsqF    = ws;
        float* A       = ws + 32768;
        float* bsqF    = ws + 33792;
        float* wgpartF = ws + 34816;
        int*   idxwsF  = (int*)(ws + 35840);
        float* Z = out;
        hipMemsetAsync(A, 0, (size_t)NC * sizeof(float), stream);
        k_bsq   <<<NC, 256, 0, stream>>>(basis, bsqF);
        k_gemm1 <<<dim3(43, 512), 256, 0, stream>>>(S, W, bproj, Z);
        k_zsq   <<<BKROWS, 64, 0, stream>>>(Z, zsqF);
        k_dist  <<<BKROWS / 32, 512, 0, stream>>>(Z, basis, bsqF, zsqF, A, wgpartF, idxwsF, out);
        k_final <<<1, 1024, 0, stream>>>(wgpartF, A, out);
        k_gather<<<BKROWS, 256, 0, stream>>>(basis, idxwsF, out);
    }
}

// Round 15
// 316.960 us; speedup vs baseline: 1.6480x; 1.0289x over previous
//
#include <hip/hip_runtime.h>
#include <math.h>

#define ED 2700     // basis_dim
#define NC 1024     // num_codes
#define DM 256      // d_model
#define BKROWS 32768

#define IDX_OFF 88473600
#define VQ_OFF  88506368
#define ENT_OFF 88506369

#define KPAD 2720     // padded K for P/M small GEMMs (5 x 544)
#define K2CH 8        // gemm chunks (K=256 / 32)

typedef float  f32x4  __attribute__((ext_vector_type(4)));
typedef short  bf16x8 __attribute__((ext_vector_type(8)));

__device__ inline unsigned short f2bf(float x) {
    unsigned int u = __float_as_uint(x);
    unsigned int r = (u + 0x7FFFu + ((u >> 16) & 1u)) >> 16;
    return (unsigned short)r;
}
__device__ inline float bf2f(unsigned short h) {
    return __uint_as_float(((unsigned int)h) << 16);
}

// =====================================================================
// ============================ MFMA PATH ==============================
// =====================================================================

// ---- merged prep: 0..8191 packS | 8192..9215 prepB | 9216..9387 padWT
//      | 9388..9644 uvW | 9645..9772 colsum | 9773 zeroA ----
__global__ __launch_bounds__(256)
void k_prep1(const float* __restrict__ S, const float* __restrict__ basis,
             const float* __restrict__ bproj, const float* __restrict__ W,
             unsigned short* __restrict__ Sh, unsigned short* __restrict__ Sm,
             float* __restrict__ bP, float* __restrict__ bsq,
             float* __restrict__ WT, float* __restrict__ uv,
             float* __restrict__ cspart, float* __restrict__ A) {
    __shared__ double sdbuf[2080];
    const int b = blockIdx.x;
    const int t = threadIdx.x;

    if (b < 8192) {
        // -------- packS --------
        const size_t i4 = (size_t)b * 256 + t;
        const float4 v = *(const float4*)(S + i4 * 4);
        ushort4 hv, mv;
        unsigned short* hp = (unsigned short*)&hv;
        unsigned short* mp = (unsigned short*)&mv;
        const float xs[4] = {v.x, v.y, v.z, v.w};
        #pragma unroll
        for (int j = 0; j < 4; ++j) {
            const unsigned short h = f2bf(xs[j]);
            hp[j] = h;
            mp[j] = f2bf(xs[j] - bf2f(h));
        }
        *(ushort4*)(Sh + i4 * 4) = hv;
        *(ushort4*)(Sm + i4 * 4) = mv;
    } else if (b < 9216) {
        // -------- prepB: basisP copy + bsq' --------
        const int c = b - 8192;
        const float* row = basis + (size_t)c * ED;
        float* dst = bP + (size_t)c * KPAD;
        double s2 = 0.0, sp = 0.0;
        for (int j = t; j < ED; j += 256) {
            const float x = row[j];
            dst[j] = x;
            s2 += (double)x * (double)x;
            sp += (double)x * (double)bproj[j];
        }
        if (t < KPAD - ED) dst[ED + t] = 0.f;
        double* sd = sdbuf;
        sd[t] = s2; sd[256 + t] = sp;
        __syncthreads();
        for (int off = 128; off > 0; off >>= 1) {
            if (t < off) { sd[t] += sd[t + off]; sd[256 + t] += sd[256 + t + off]; }
            __syncthreads();
        }
        if (t == 0) bsq[c] = (float)(sd[0] - 2.0 * sd[256]);
    } else if (b < 9388) {
        // -------- padWT --------
        const int i  = b - 9216;
        const int e0 = (i >> 2) * 64;
        const int d0 = (i & 3) * 64;
        float (*tbuf)[65] = (float(*)[65])sdbuf;
        const int r  = t >> 2;
        const int q4 = t & 3;
        #pragma unroll
        for (int j = 0; j < 4; ++j) {
            const int col = q4 * 16 + j * 4;
            const int e = e0 + r;
            float4 v = make_float4(0.f, 0.f, 0.f, 0.f);
            if (e < ED) v = *(const float4*)(W + (size_t)e * DM + d0 + col);
            tbuf[r][col + 0] = v.x; tbuf[r][col + 1] = v.y;
            tbuf[r][col + 2] = v.z; tbuf[r][col + 3] = v.w;
        }
        __syncthreads();
        #pragma unroll
        for (int j = 0; j < 4; ++j) {
            const int col = q4 * 16 + j * 4;
            if (e0 + col < KPAD) {
                float4 o;
                o.x = tbuf[col + 0][r]; o.y = tbuf[col + 1][r];
                o.z = tbuf[col + 2][r]; o.w = tbuf[col + 3][r];
                *(float4*)(WT + (size_t)(d0 + r) * KPAD + e0 + col) = o;
            }
        }
    } else if (b < 9645) {
        // -------- uv: u[d] = W[:,d].bproj; block 256 = ||bproj||^2 --------
        const int bb = b - 9388;
        double s = 0.0;
        if (bb < 256) {
            for (int e = t; e < ED; e += 256)
                s += (double)W[(size_t)e * DM + bb] * (double)bproj[e];
        } else {
            for (int j = t; j < ED; j += 256) { const double x = bproj[j]; s += x * x; }
        }
        double* sd = sdbuf;
        sd[t] = s;
        __syncthreads();
        for (int off = 128; off > 0; off >>= 1) {
            if (t < off) sd[t] += sd[t + off];
            __syncthreads();
        }
        if (t == 0) uv[bb] = (float)sd[0];
    } else if (b < 9773) {
        // -------- colsum of S --------
        const int blk = b - 9645;
        const int m0 = blk * 256;
        double s = 0.0;
        for (int r = 0; r < 256; ++r) s += (double)S[(size_t)(m0 + r) * DM + t];
        cspart[blk * 256 + t] = (float)s;
    } else {
        // -------- zero A --------
        #pragma unroll
        for (int j = 0; j < 4; ++j) A[t * 4 + j] = 0.f;
    }
}

// ---- merged gsplit: blocks 0..319 P-partials | 320..399 M-partials ----
__global__ __launch_bounds__(256)
void k_gsplitPM(const float* __restrict__ basisP, const float* __restrict__ WT,
                float* __restrict__ Pp, float* __restrict__ Mp) {
    const int b = blockIdx.x;
    const float* A;
    const float* B = WT;
    float* Cout;
    int n0, m0, k00, mtiles;
    if (b < 320) {
        const int kz = b / 64, rem = b % 64;
        A = basisP; mtiles = 16;
        m0 = (rem >> 2) * 64; n0 = (rem & 3) * 64; k00 = kz * 544;
        Cout = Pp + (size_t)kz * mtiles * 64 * 256;
    } else {
        const int j = b - 320;
        const int kz = j / 16, rem = j % 16;
        A = WT; mtiles = 4;
        m0 = (rem >> 2) * 64; n0 = (rem & 3) * 64; k00 = kz * 544;
        Cout = Mp + (size_t)kz * mtiles * 64 * 256;
    }
    const int t  = threadIdx.x;
    const int tx = t & 15, ty = t >> 4;

    __shared__ float alds[32 * 68];
    __shared__ float blds[32 * 68];

    float acc[4][4] = {};

    for (int k0 = k00; k0 < k00 + 544; k0 += 32) {
        #pragma unroll
        for (int rep = 0; rep < 2; ++rep) {
            const int id  = t + rep * 256;
            const int row = id >> 3, kq = id & 7;
            const float4 va = *(const float4*)(A + (size_t)(m0 + row) * KPAD + k0 + 4 * kq);
            alds[(4*kq+0)*68 + row] = va.x;
            alds[(4*kq+1)*68 + row] = va.y;
            alds[(4*kq+2)*68 + row] = va.z;
            alds[(4*kq+3)*68 + row] = va.w;
            const float4 vb = *(const float4*)(B + (size_t)(n0 + row) * KPAD + k0 + 4 * kq);
            blds[(4*kq+0)*68 + row] = vb.x;
            blds[(4*kq+1)*68 + row] = vb.y;
            blds[(4*kq+2)*68 + row] = vb.z;
            blds[(4*kq+3)*68 + row] = vb.w;
        }
        __syncthreads();
        #pragma unroll 8
        for (int k = 0; k < 32; ++k) {
            const float4 a = *(const float4*)&alds[k*68 + 4*ty];
            const float4 bb = *(const float4*)&blds[k*68 + 4*tx];
            const float av[4] = {a.x, a.y, a.z, a.w};
            const float bv[4] = {bb.x, bb.y, bb.z, bb.w};
            #pragma unroll
            for (int i = 0; i < 4; ++i)
                #pragma unroll
                for (int j = 0; j < 4; ++j)
                    acc[i][j] = fmaf(av[i], bv[j], acc[i][j]);
        }
        __syncthreads();
    }
    #pragma unroll
    for (int i = 0; i < 4; ++i) {
        float4 o; o.x = acc[i][0]; o.y = acc[i][1]; o.z = acc[i][2]; o.w = acc[i][3];
        *(float4*)(Cout + (size_t)(m0 + 4*ty + i) * 256 + n0 + 4*tx) = o;
    }
}

// ---- merged reduce: blocks 0..1023 P-planes | 1024..1279 M-planes ----
__global__ __launch_bounds__(256)
void k_redPM(const float* __restrict__ Pp, const float* __restrict__ Mp,
             unsigned short* __restrict__ Ph, unsigned short* __restrict__ Pm,
             unsigned short* __restrict__ Mh, unsigned short* __restrict__ Mm) {
    const int b = blockIdx.x;
    if (b < 1024) {
        const size_t idx = (size_t)b * 256 + threadIdx.x;
        float s = 0.f;
        #pragma unroll
        for (int k = 0; k < 5; ++k) s += Pp[(size_t)k * 262144 + idx];
        const unsigned short h = f2bf(s);
        Ph[idx] = h;
        Pm[idx] = f2bf(s - bf2f(h));
    } else {
        const size_t idx = (size_t)(b - 1024) * 256 + threadIdx.x;
        float s = 0.f;
        #pragma unroll
        for (int k = 0; k < 5; ++k) s += Mp[(size_t)k * 65536 + idx];
        const unsigned short h = f2bf(s);
        Mh[idx] = h;
        Mm[idx] = f2bf(s - bf2f(h));
    }
}

// ---- k_gemm2y: blocks 0..511 -> G tiles (S.P^T); blocks 512..639 -> ydot (S.M^T dot S) ----
__global__ __launch_bounds__(512, 2)
void k_gemm2y(const unsigned short* __restrict__ Zh, const unsigned short* __restrict__ Zm,
              const unsigned short* __restrict__ Ph, const unsigned short* __restrict__ Pm,
              const unsigned short* __restrict__ Mh, const unsigned short* __restrict__ Mm,
              const float* __restrict__ S, float* __restrict__ G,
              float* __restrict__ ydotpart) {
    __shared__ unsigned short lds[2 * 32768];

    const int bid  = blockIdx.x;
    const bool isY = (bid >= 512);
    int m0, n0;
    const unsigned short *Bh, *Bm;
    if (!isY) {
        const int xcd = bid & 7, local = bid >> 3;
        m0 = (xcd * 16 + (local >> 2)) * 256;
        n0 = (local & 3) * 256;
        Bh = Ph; Bm = Pm;
    } else {
        const int b2 = bid - 512;
        const int xcd = b2 & 7, local = b2 >> 3;
        m0 = (xcd * 16 + local) * 256;
        n0 = 0;
        Bh = Mh; Bm = Mm;
    }
    const int tid  = threadIdx.x;
    const int w    = tid >> 6, l = tid & 63;
    const int wr   = (w >> 2) * 128;
    const int wc   = (w & 3) * 64;
    const int lrow = l & 15;
    const int lu   = l >> 4;

    const unsigned short* hsrc[4][2];
    int hlds[4][2];
    #pragma unroll
    for (int ht = 0; ht < 4; ++ht) {
        #pragma unroll
        for (int j = 0; j < 2; ++j) {
            const int slot = j * 512 + tid;
            const int rwh  = slot >> 3;
            const int unit = slot & 7;
            int row; bool isB;
            if (ht == 0)      { row = (rwh & 63) + (rwh >> 6) * 128;       isB = false; }
            else if (ht == 1) { row = 64 + (rwh & 63) + (rwh >> 6) * 128;  isB = false; }
            else if (ht == 2) { row = (rwh & 31) + (rwh >> 5) * 64;        isB = true;  }
            else              { row = 32 + (rwh & 31) + (rwh >> 5) * 64;   isB = true;  }
            const int sg   = unit ^ (row & 7);
            const int pl   = sg >> 2;
            const int koff = (sg & 3) * 8;
            if (!isB) hsrc[ht][j] = (pl ? Zm : Zh) + (size_t)(m0 + row) * DM + koff;
            else      hsrc[ht][j] = (pl ? Bm : Bh) + (size_t)(n0 + row) * DM + koff;
            hlds[ht][j] = (isB ? 16384 : 0) + row * 64 + unit * 8;
        }
    }

    f32x4 acc[8][4];
    #pragma unroll
    for (int i = 0; i < 8; ++i)
        #pragma unroll
        for (int j = 0; j < 4; ++j) acc[i][j] = (f32x4){0.f, 0.f, 0.f, 0.f};

    #define STAGE_HALF(ht, ck, db) { \
        _Pragma("unroll") \
        for (int j = 0; j < 2; ++j) \
            __builtin_amdgcn_global_load_lds( \
                (const __attribute__((address_space(1))) unsigned int*)(const void*)(hsrc[ht][j] + (ck) * 32), \
                (__attribute__((address_space(3))) unsigned int*)(void*)&lds[(db) * 32768 + hlds[ht][j]], \
                16, 0, 0); \
    }

    #define LOAD_A(db, qm) { \
        const unsigned short* At = &lds[(db) * 32768]; \
        _Pragma("unroll") \
        for (int f = 0; f < 4; ++f) { \
            const int row = wr + ((qm) * 4 + f) * 16 + lrow; \
            ah[f] = *(const bf16x8*)(At + row * 64 + (((0 + lu) ^ (row & 7))) * 8); \
            am[f] = *(const bf16x8*)(At + row * 64 + (((4 + lu) ^ (row & 7))) * 8); \
        } \
    }
    #define LOAD_B(db, qn) { \
        const unsigned short* Bt = &lds[(db) * 32768 + 16384]; \
        _Pragma("unroll") \
        for (int f = 0; f < 2; ++f) { \
            const int col = wc + ((qn) * 2 + f) * 16 + lrow; \
            bh[f] = *(const bf16x8*)(Bt + col * 64 + (((0 + lu) ^ (col & 7))) * 8); \
            bm[f] = *(const bf16x8*)(Bt + col * 64 + (((4 + lu) ^ (col & 7))) * 8); \
        } \
    }
    #define MFMA_Q(qm, qn) { \
        __builtin_amdgcn_s_setprio(1); \
        _Pragma("unroll") \
        for (int i = 0; i < 4; ++i) \
            _Pragma("unroll") \
            for (int j = 0; j < 2; ++j) { \
                f32x4 cc = acc[(qm) * 4 + i][(qn) * 2 + j]; \
                cc = __builtin_amdgcn_mfma_f32_16x16x32_bf16(ah[i], bh[j], cc, 0, 0, 0); \
                cc = __builtin_amdgcn_mfma_f32_16x16x32_bf16(ah[i], bm[j], cc, 0, 0, 0); \
                cc = __builtin_amdgcn_mfma_f32_16x16x32_bf16(am[i], bh[j], cc, 0, 0, 0); \
                acc[(qm) * 4 + i][(qn) * 2 + j] = cc; \
            } \
        __builtin_amdgcn_s_setprio(0); \
    }
    #define VM8  asm volatile("s_waitcnt vmcnt(8)" ::: "memory");
    #define BAR  __builtin_amdgcn_s_barrier();

    STAGE_HALF(0, 0, 0) STAGE_HALF(2, 0, 0) STAGE_HALF(3, 0, 0) STAGE_HALF(1, 0, 0)
    STAGE_HALF(0, 1, 1) STAGE_HALF(2, 1, 1)
    VM8
    BAR

    for (int c = 0; c < K2CH - 2; ++c) {
        const int cb = c & 1, ob = cb ^ 1;
        bf16x8 ah[4], am[4], bh[2], bm[2];
        LOAD_A(cb, 0) LOAD_B(cb, 0)
        STAGE_HALF(3, c + 1, ob)
        BAR
        MFMA_Q(0, 0)
        VM8
        BAR
        LOAD_B(cb, 1)
        STAGE_HALF(1, c + 1, ob)
        BAR
        MFMA_Q(0, 1)
        VM8
        BAR
        LOAD_A(cb, 1) LOAD_B(cb, 0)
        STAGE_HALF(0, c + 2, cb)
        BAR
        MFMA_Q(1, 0)
        BAR
        LOAD_B(cb, 1)
        STAGE_HALF(2, c + 2, cb)
        BAR
        MFMA_Q(1, 1)
        VM8
        BAR
    }

    STAGE_HALF(3, K2CH - 1, (K2CH - 1) & 1) STAGE_HALF(1, K2CH - 1, (K2CH - 1) & 1)
    asm volatile("s_waitcnt vmcnt(0)" ::: "memory");
    BAR
    #pragma unroll
    for (int e = 0; e < 2; ++e) {
        const int cb = (K2CH - 2 + e) & 1;
        bf16x8 ah[4], am[4], bh[2], bm[2];
        LOAD_A(cb, 0) LOAD_B(cb, 0)
        MFMA_Q(0, 0)
        LOAD_B(cb, 1)
        MFMA_Q(0, 1)
        LOAD_A(cb, 1) LOAD_B(cb, 0)
        MFMA_Q(1, 0)
        LOAD_B(cb, 1)
        MFMA_Q(1, 1)
    }
    #undef STAGE_HALF
    #undef LOAD_A
    #undef LOAD_B
    #undef MFMA_Q
    #undef VM8
    #undef BAR

    if (!isY) {
        // C layout: col = lane&15, row = (lane>>4)*4 + reg
        #pragma unroll
        for (int fm = 0; fm < 8; ++fm)
            #pragma unroll
            for (int fn = 0; fn < 4; ++fn) {
                const int col = n0 + wc + fn * 16 + lrow;
                #pragma unroll
                for (int r = 0; r < 4; ++r) {
                    const int row = m0 + wr + fm * 16 + lu * 4 + r;
                    G[(size_t)row * NC + col] = acc[fm][fn][r];
                }
            }
    } else {
        float part = 0.f;
        #pragma unroll
        for (int fm = 0; fm < 8; ++fm)
            #pragma unroll
            for (int fn = 0; fn < 4; ++fn) {
                const int col = wc + fn * 16 + lrow;
                #pragma unroll
                for (int r = 0; r < 4; ++r) {
                    const int row = m0 + wr + fm * 16 + lu * 4 + r;
                    part += acc[fm][fn][r] * S[(size_t)row * DM + col];
                }
            }
        __syncthreads();
        float* red = (float*)lds;
        red[tid] = part;
        __syncthreads();
        for (int off = 256; off > 0; off >>= 1) {
            if (tid < off) red[tid] += red[tid + off];
            __syncthreads();
        }
        if (tid == 0) ydotpart[bid - 512] = red[0];
    }
}

// ---- k_postg: dist' = bsq' - 2G + argmin/softmax/avg_prob + FUSED gather ----
__global__ __launch_bounds__(512)
void k_postg(const float* __restrict__ G, const float* __restrict__ bsq,
             const float* __restrict__ basis, float* __restrict__ A,
             float* __restrict__ wgpart, float* __restrict__ out) {
    const int bid = blockIdx.x;
    const int wr0 = bid * 32;
    const int t   = threadIdx.x;
    const int cg  = t & 127;
    const int rq  = t >> 7;
    const int r0  = rq * 8;
    const int c0  = cg * 4;
    const int c1  = 512 + cg * 4;

    __shared__ float sm[9312];
    float* red_v    = sm;                 // [32][128]
    int*   red_i    = (int*)(sm + 4096);  // [32][128]
    float* row_dmin = sm + 8192;          // [32]
    float* row_s    = sm + 8224;          // [32]
    int*   idxsh    = (int*)(sm + 8256);  // [32]
    float* pc       = sm + 8288;          // [1024]

    float acc[8][8];
    #pragma unroll
    for (int i = 0; i < 8; ++i) {
        const float4 g0 = *(const float4*)&G[(size_t)(wr0 + r0 + i) * NC + c0];
        const float4 g1 = *(const float4*)&G[(size_t)(wr0 + r0 + i) * NC + c1];
        acc[i][0] = g0.x; acc[i][1] = g0.y; acc[i][2] = g0.z; acc[i][3] = g0.w;
        acc[i][4] = g1.x; acc[i][5] = g1.y; acc[i][6] = g1.z; acc[i][7] = g1.w;
    }

    float bsqv[8];
    #pragma unroll
    for (int j = 0; j < 4; ++j) { bsqv[j] = bsq[c0 + j]; bsqv[4 + j] = bsq[c1 + j]; }

    #pragma unroll
    for (int i = 0; i < 8; ++i)
        #pragma unroll
        for (int j = 0; j < 8; ++j)
            acc[i][j] = bsqv[j] - 2.f * acc[i][j];

    #pragma unroll
    for (int i = 0; i < 8; ++i) {
        float bv = acc[i][0]; int bi = c0;
        #pragma unroll
        for (int j = 1; j < 8; ++j) {
            const int c = (j < 4) ? (c0 + j) : (c1 + (j - 4));
            if (acc[i][j] < bv || (acc[i][j] == bv && c < bi)) { bv = acc[i][j]; bi = c; }
        }
        red_v[(r0 + i) * 128 + cg] = bv;
        red_i[(r0 + i) * 128 + cg] = bi;
    }
    __syncthreads();
    if (t < 32) {
        float bv = red_v[t * 128]; int bi = red_i[t * 128];
        for (int x = 1; x < 128; ++x) {
            const float v = red_v[t * 128 + x];
            const int  iv = red_i[t * 128 + x];
            if (v < bv || (v == bv && iv < bi)) { bv = v; bi = iv; }
        }
        row_dmin[t] = bv;
        idxsh[t] = bi;
        out[IDX_OFF + wr0 + t] = (float)bi;
    }
    __syncthreads();

    float su[8];
    #pragma unroll
    for (int i = 0; i < 8; ++i) {
        const float dm = row_dmin[r0 + i];
        float s = 0.f;
        #pragma unroll
        for (int j = 0; j < 8; ++j) {
            const float u = expf(dm - acc[i][j]);
            acc[i][j] = u;
            s += u;
        }
        su[i] = s;
    }
    #pragma unroll
    for (int i = 0; i < 8; ++i) red_v[(r0 + i) * 128 + cg] = su[i];
    __syncthreads();
    if (t < 32) {
        float s = 0.f;
        for (int x = 0; x < 128; ++x) s += red_v[t * 128 + x];
        row_s[t] = s;
    }
    __syncthreads();

    float rcp[8];
    #pragma unroll
    for (int i = 0; i < 8; ++i) rcp[i] = 1.f / row_s[r0 + i];

    pc[t] = 0.f; pc[t + 512] = 0.f;
    __syncthreads();
    #pragma unroll
    for (int j = 0; j < 8; ++j) {
        const int c = (j < 4) ? (c0 + j) : (c1 + (j - 4));
        float s = 0.f;
        #pragma unroll
        for (int i = 0; i < 8; ++i) s += acc[i][j] * rcp[i];
        atomicAdd(&pc[c], s);
    }
    __syncthreads();
    atomicAdd(&A[t],       pc[t]);
    atomicAdd(&A[t + 512], pc[t + 512]);

    if (t == 0) {
        float s = 0.f;
        for (int r = 0; r < 32; ++r) s += row_dmin[r];
        wgpart[bid] = s;
    }

    // ---- fused gather: q_st rows (Sh/Sm in out are dead: gemm2y done) ----
    for (int r = 0; r < 32; ++r) {
        const int idx = idxsh[r];
        const float4* src = (const float4*)(basis + (size_t)idx * ED);
        float4* dst = (float4*)(out + (size_t)(wr0 + r) * ED);
        for (int j = t; j < ED / 4; j += 512) dst[j] = src[j];
    }
}

// ---- finalize scalars ----
__global__ void k_final2(const float* __restrict__ wgpart, const float* __restrict__ Aq,
                         const float* __restrict__ ydotpart, const float* __restrict__ cspart,
                         const float* __restrict__ uv, float* __restrict__ out) {
    __shared__ double sd[1024];
    const int t = threadIdx.x;
    sd[t] = (double)wgpart[t];
    __syncthreads();
    for (int off = 512; off > 0; off >>= 1) {
        if (t < off) sd[t] += sd[t + off];
        __syncthreads();
    }
    const double smin = sd[0];
    __syncthreads();
    sd[t] = (t < 128) ? (double)ydotpart[t] : 0.0;
    __syncthreads();
    for (int off = 512; off > 0; off >>= 1) {
        if (t < off) sd[t] += sd[t + off];
        __syncthreads();
    }
    const double sy = sd[0];
    __syncthreads();
    double cu = 0.0;
    if (t < 256) {
        double cs = 0.0;
        for (int b = 0; b < 128; ++b) cs += (double)cspart[b * 256 + t];
        cu = cs * (double)uv[t];
    }
    sd[t] = cu;
    __syncthreads();
    for (int off = 512; off > 0; off >>= 1) {
        if (t < off) sd[t] += sd[t + off];
        __syncthreads();
    }
    if (t == 0) {
        const double szsq = sy + 2.0 * sd[0] + 32768.0 * (double)uv[256];
        out[VQ_OFF] = (float)(0.25 * (smin + szsq) / 88473600.0);
    }
    __syncthreads();
    const double p = (double)Aq[t] * (1.0 / 32768.0);
    sd[t] = -p * log(p + 1e-8);
    __syncthreads();
    for (int off = 512; off > 0; off >>= 1) {
        if (t < off) sd[t] += sd[t + off];
        __syncthreads();
    }
    if (t == 0) out[ENT_OFF] = (float)sd[0];
}

// ---- q_st = basis[indices] (fallback path only) ----
__global__ void k_gather(const float* __restrict__ basis, const int* __restrict__ idxws,
                         float* __restrict__ out) {
    const int r = blockIdx.x;
    const int idx = idxws[r];
    const float4* src = (const float4*)(basis + (size_t)idx * ED);
    float4* dst = (float4*)(out + (size_t)r * ED);
    for (int j = threadIdx.x; j < ED / 4; j += 256) dst[j] = src[j];
}

// =====================================================================
// ===================== FALLBACK (round-2, f32 VALU) ==================
// =====================================================================

__global__ void k_bsq(const float* __restrict__ basis, float* __restrict__ bsq) {
    int c = blockIdx.x;
    const float* row = basis + (size_t)c * ED;
    double s = 0.0;
    for (int j = threadIdx.x; j < ED; j += 256) { float v = row[j]; s += (double)v * (double)v; }
    __shared__ double sd[256];
    sd[threadIdx.x] = s;
    __syncthreads();
    for (int off = 128; off > 0; off >>= 1) {
        if (threadIdx.x < off) sd[threadIdx.x] += sd[threadIdx.x + off];
        __syncthreads();
    }
    if (threadIdx.x == 0) bsq[c] = (float)sd[0];
}

__global__ __launch_bounds__(256, 4)
void k_gemm1(const float* __restrict__ S, const float* __restrict__ W,
             const float* __restrict__ bproj, float* __restrict__ Z) {
    const int e0 = blockIdx.x * 64;
    const int m0 = blockIdx.y * 64;
    const int t  = threadIdx.x;
    const int tx = t & 15, ty = t >> 4;
    __shared__ float alds[32 * 68];
    __shared__ float blds[32 * 68];
    float acc[4][4] = {};
    for (int k0 = 0; k0 < DM; k0 += 32) {
        #pragma unroll
        for (int rep = 0; rep < 2; ++rep) {
            const int id  = t + rep * 256;
            const int row = id >> 3, kq = id & 7;
            const float4 va = *(const float4*)(S + (size_t)(m0 + row) * DM + k0 + 4 * kq);
            alds[(4*kq+0)*68 + row] = va.x;
            alds[(4*kq+1)*68 + row] = va.y;
            alds[(4*kq+2)*68 + row] = va.z;
            alds[(4*kq+3)*68 + row] = va.w;
            float4 vb = make_float4(0.f, 0.f, 0.f, 0.f);
            if (e0 + row < ED)
                vb = *(const float4*)(W + (size_t)(e0 + row) * DM + k0 + 4 * kq);
            blds[(4*kq+0)*68 + row] = vb.x;
            blds[(4*kq+1)*68 + row] = vb.y;
            blds[(4*kq+2)*68 + row] = vb.z;
            blds[(4*kq+3)*68 + row] = vb.w;
        }
        __syncthreads();
        #pragma unroll 8
        for (int k = 0; k < 32; ++k) {
            const float4 a = *(const float4*)&alds[k*68 + 4*ty];
            const float4 b = *(const float4*)&blds[k*68 + 4*tx];
            const float av[4] = {a.x, a.y, a.z, a.w};
            const float bv[4] = {b.x, b.y, b.z, b.w};
            #pragma unroll
            for (int i = 0; i < 4; ++i)
                #pragma unroll
                for (int j = 0; j < 4; ++j)
                    acc[i][j] = fmaf(av[i], bv[j], acc[i][j]);
        }
        __syncthreads();
    }
    const bool valid = (e0 + 4*tx + 4) <= ED;
    float4 bias = make_float4(0.f, 0.f, 0.f, 0.f);
    if (valid) bias = *(const float4*)(bproj + e0 + 4*tx);
    #pragma unroll
    for (int i = 0; i < 4; ++i) {
        if (valid) {
            float4 o;
            o.x = acc[i][0] + bias.x;
            o.y = acc[i][1] + bias.y;
            o.z = acc[i][2] + bias.z;
            o.w = acc[i][3] + bias.w;
            *(float4*)(Z + (size_t)(m0 + 4*ty + i) * ED + e0 + 4*tx) = o;
        }
    }
}

__global__ __launch_bounds__(64)
void k_zsq(const float* __restrict__ Z, float* __restrict__ zsq) {
    const int r = blockIdx.x;
    const float4* row4 = (const float4*)(Z + (size_t)r * ED);
    double s = 0.0;
    for (int q = threadIdx.x; q < ED / 4; q += 64) {
        const float4 v = row4[q];
        s += (double)v.x * v.x + (double)v.y * v.y + (double)v.z * v.z + (double)v.w * v.w;
    }
    #pragma unroll
    for (int off = 32; off > 0; off >>= 1) s += __shfl_down(s, off);
    if (threadIdx.x == 0) zsq[r] = (float)s;
}

__global__ __launch_bounds__(512, 2)
void k_dist(const float* __restrict__ Z, const float* __restrict__ basis,
            const float* __restrict__ bsq, const float* __restrict__ zsq,
            float* __restrict__ A, float* __restrict__ wgpart,
            int* __restrict__ idxws, float* __restrict__ out) {
    const int bid = blockIdx.x;
    const int wr0 = bid * 32;
    const int t   = threadIdx.x;
    const int cg  = t & 127;
    const int rq  = t >> 7;
    const int r0  = rq * 8;
    const int c0  = cg * 4;
    const int c1  = 512 + cg * 4;
    __shared__ float blds[16 * 1024];
    __shared__ float zlds[16 * 36];
    float acc[8][8];
    #pragma unroll
    for (int i = 0; i < 8; ++i)
        #pragma unroll
        for (int j = 0; j < 8; ++j) acc[i][j] = 0.f;
    for (int k0 = 0; k0 < ED; k0 += 16) {
        const bool full = (k0 + 16) <= ED;
        #pragma unroll
        for (int rep = 0; rep < 2; ++rep) {
            const int c = t + rep * 512;
            const float* bp = basis + (size_t)c * ED + k0;
            if (full) {
                const float4 v0 = *(const float4*)(bp + 0);
                const float4 v1 = *(const float4*)(bp + 4);
                const float4 v2 = *(const float4*)(bp + 8);
                const float4 v3 = *(const float4*)(bp + 12);
                blds[ 0*1024+c]=v0.x; blds[ 1*1024+c]=v0.y; blds[ 2*1024+c]=v0.z; blds[ 3*1024+c]=v0.w;
                blds[ 4*1024+c]=v1.x; blds[ 5*1024+c]=v1.y; blds[ 6*1024+c]=v1.z; blds[ 7*1024+c]=v1.w;
                blds[ 8*1024+c]=v2.x; blds[ 9*1024+c]=v2.y; blds[10*1024+c]=v2.z; blds[11*1024+c]=v2.w;
                blds[12*1024+c]=v3.x; blds[13*1024+c]=v3.y; blds[14*1024+c]=v3.z; blds[15*1024+c]=v3.w;
            } else {
                for (int kk = 0; kk < 16; ++kk)
                    blds[kk*1024 + c] = (k0 + kk < ED) ? bp[kk] : 0.f;
            }
        }
        if (t < 128) {
            const int row = t >> 2, kq = t & 3;
            const float* zp = Z + (size_t)(wr0 + row) * ED + k0 + 4 * kq;
            if (full) {
                const float4 v = *(const float4*)zp;
                zlds[(4*kq+0)*36 + row] = v.x;
                zlds[(4*kq+1)*36 + row] = v.y;
                zlds[(4*kq+2)*36 + row] = v.z;
                zlds[(4*kq+3)*36 + row] = v.w;
            } else {
                for (int j = 0; j < 4; ++j) {
                    const int k = k0 + 4*kq + j;
                    zlds[(4*kq+j)*36 + row] = (k < ED) ? zp[j] : 0.f;
                }
            }
        }
        __syncthreads();
        #pragma unroll
        for (int k = 0; k < 16; ++k) {
            const float4 z0 = *(const float4*)&zlds[k*36 + r0];
            const float4 z1 = *(const float4*)&zlds[k*36 + r0 + 4];
            const float4 b0 = *(const float4*)&blds[k*1024 + c0];
            const float4 b1 = *(const float4*)&blds[k*1024 + c1];
            const float zz[8] = {z0.x, z0.y, z0.z, z0.w, z1.x, z1.y, z1.z, z1.w};
            const float bb[8] = {b0.x, b0.y, b0.z, b0.w, b1.x, b1.y, b1.z, b1.w};
            #pragma unroll
            for (int i = 0; i < 8; ++i)
                #pragma unroll
                for (int j = 0; j < 8; ++j)
                    acc[i][j] = fmaf(zz[i], bb[j], acc[i][j]);
        }
        __syncthreads();
    }
    float* red_v    = blds;
    int*   red_i    = (int*)(blds + 4096);
    float* row_dmin = blds + 8192;
    float* row_s    = blds + 8224;
    float* pc       = blds + 8256;
    float bsqv[8], zsqv[8];
    #pragma unroll
    for (int j = 0; j < 4; ++j) { bsqv[j] = bsq[c0 + j]; bsqv[4 + j] = bsq[c1 + j]; }
    #pragma unroll
    for (int i = 0; i < 8; ++i) zsqv[i] = zsq[wr0 + r0 + i];
    #pragma unroll
    for (int i = 0; i < 8; ++i)
        #pragma unroll
        for (int j = 0; j < 8; ++j) {
            const float tv = zsqv[i] - 2.f * acc[i][j];
            acc[i][j] = tv + bsqv[j];
        }
    #pragma unroll
    for (int i = 0; i < 8; ++i) {
        float bv = acc[i][0]; int bi = c0;
        #pragma unroll
        for (int j = 1; j < 8; ++j) {
            const int c = (j < 4) ? (c0 + j) : (c1 + (j - 4));
            if (acc[i][j] < bv || (acc[i][j] == bv && c < bi)) { bv = acc[i][j]; bi = c; }
        }
        red_v[(r0 + i) * 128 + cg] = bv;
        red_i[(r0 + i) * 128 + cg] = bi;
    }
    __syncthreads();
    if (t < 32) {
        float bv = red_v[t * 128]; int bi = red_i[t * 128];
        for (int x = 1; x < 128; ++x) {
            const float v = red_v[t * 128 + x];
            const int  iv = red_i[t * 128 + x];
            if (v < bv || (v == bv && iv < bi)) { bv = v; bi = iv; }
        }
        row_dmin[t] = bv;
        idxws[wr0 + t] = bi;
        out[IDX_OFF + wr0 + t] = (float)bi;
    }
    __syncthreads();
    float su[8];
    #pragma unroll
    for (int i = 0; i < 8; ++i) {
        const float dm = row_dmin[r0 + i];
        float s = 0.f;
        #pragma unroll
        for (int j = 0; j < 8; ++j) {
            const float u = expf(dm - acc[i][j]);
            acc[i][j] = u;
            s += u;
        }
        su[i] = s;
    }
    #pragma unroll
    for (int i = 0; i < 8; ++i) red_v[(r0 + i) * 128 + cg] = su[i];
    __syncthreads();
    if (t < 32) {
        float s = 0.f;
        for (int x = 0; x < 128; ++x) s += red_v[t * 128 + x];
        row_s[t] = s;
    }
    __syncthreads();
    float rcp[8];
    #pragma unroll
    for (int i = 0; i < 8; ++i) rcp[i] = 1.f / row_s[r0 + i];
    pc[t] = 0.f; pc[t + 512] = 0.f;
    __syncthreads();
    #pragma unroll
    for (int j = 0; j < 8; ++j) {
        const int c = (j < 4) ? (c0 + j) : (c1 + (j - 4));
        float s = 0.f;
        #pragma unroll
        for (int i = 0; i < 8; ++i) s += acc[i][j] * rcp[i];
        atomicAdd(&pc[c], s);
    }
    __syncthreads();
    atomicAdd(&A[t],       pc[t]);
    atomicAdd(&A[t + 512], pc[t + 512]);
    if (t == 0) {
        float s = 0.f;
        for (int r = 0; r < 32; ++r) s += row_dmin[r];
        wgpart[bid] = s;
    }
}

__global__ void k_final(const float* __restrict__ wgpart, const float* __restrict__ A,
                        float* __restrict__ out) {
    __shared__ double sd[1024];
    const int t = threadIdx.x;
    sd[t] = (double)wgpart[t];
    __syncthreads();
    for (int off = 512; off > 0; off >>= 1) {
        if (t < off) sd[t] += sd[t + off];
        __syncthreads();
    }
    if (t == 0) out[VQ_OFF] = (float)(0.25 * sd[0] / 88473600.0);
    __syncthreads();
    const double p = (double)A[t] * (1.0 / 32768.0);
    sd[t] = -p * log(p + 1e-8);
    __syncthreads();
    for (int off = 512; off > 0; off >>= 1) {
        if (t < off) sd[t] += sd[t + off];
        __syncthreads();
    }
    if (t == 0) out[ENT_OFF] = (float)sd[0];
}

// =====================================================================

extern "C" void kernel_launch(void* const* d_in, const int* in_sizes, int n_in,
                              void* d_out, int out_size, void* d_ws, size_t ws_size,
                              hipStream_t stream) {
    const float* S     = (const float*)d_in[0];  // [32768, 256]
    const float* W     = (const float*)d_in[1];  // [2700, 256]
    const float* bproj = (const float*)d_in[2];  // [2700]
    const float* basis = (const float*)d_in[3];  // [1024, 2700]
    float* out = (float*)d_out;
    float* ws  = (float*)d_ws;

    const size_t NEED = (size_t)33951232 * sizeof(float);   // ~135.8 MB
    if (ws_size >= NEED) {
        // -------- MFMA path --------
        float* A        = ws;                 // 1024
        float* bsq      = ws + 1024;          // 1024
        float* wgpart   = ws + 2048;          // 1024
        float* uv       = ws + 35840;         // 257 (pad 384)
        float* ydotpart = ws + 36224;         // 128
        float* cspart   = ws + 36352;         // 128*256 = 32768
        unsigned short* Ph = (unsigned short*)(ws + 69120);   // 1024*256 ush
        unsigned short* Pm = (unsigned short*)(ws + 200192);
        unsigned short* Mh = (unsigned short*)(ws + 331264);  // 256*256 ush
        unsigned short* Mm = (unsigned short*)(ws + 364032);
        float* G        = ws + 396800;        // 32768*1024
        // transients aliased into G (dead before k_gemm2y writes G)
        float* basisP = G;                    // 1024*2720 = 2785280
        float* WT     = G + 2785280;          // 256*2720  = 696320
        float* Pp     = G + 3481600;          // 5*262144  = 1310720
        float* Mp     = G + 4792320;          // 5*65536   = 327680
        // S planes live in q_st output region (dead before k_postg gathers)
        unsigned short* Sh = (unsigned short*)out;            // 32768*256 ush
        unsigned short* Sm = Sh + (size_t)BKROWS * DM;

        k_prep1   <<<9774, 256, 0, stream>>>(S, basis, bproj, W, Sh, Sm, basisP, bsq, WT, uv, cspart, A);
        k_gsplitPM<<<400, 256, 0, stream>>>(basisP, WT, Pp, Mp);
        k_redPM   <<<1280, 256, 0, stream>>>(Pp, Mp, Ph, Pm, Mh, Mm);
        k_gemm2y  <<<640, 512, 0, stream>>>(Sh, Sm, Ph, Pm, Mh, Mm, S, G, ydotpart);
        k_postg   <<<BKROWS / 32, 512, 0, stream>>>(G, bsq, basis, A, wgpart, out);
        k_final2  <<<1, 1024, 0, stream>>>(wgpart, A, ydotpart, cspart, uv, out);
    } else {
        // -------- fallback: round-2 f32 path --------
        float* zsqF    = ws;
        float* A       = ws + 32768;
        float* bsqF    = ws + 33792;
        float* wgpartF = ws + 34816;
        int*   idxwsF  = (int*)(ws + 35840);
        float* Z = out;
        hipMemsetAsync(A, 0, (size_t)NC * sizeof(float), stream);
        k_bsq   <<<NC, 256, 0, stream>>>(basis, bsqF);
        k_gemm1 <<<dim3(43, 512), 256, 0, stream>>>(S, W, bproj, Z);
        k_zsq   <<<BKROWS, 64, 0, stream>>>(Z, zsqF);
        k_dist  <<<BKROWS / 32, 512, 0, stream>>>(Z, basis, bsqF, zsqF, A, wgpartF, idxwsF, out);
        k_final <<<1, 1024, 0, stream>>>(wgpartF, A, out);
        k_gather<<<BKROWS, 256, 0, stream>>>(basis, idxwsF, out);
    }
}